// Round 9
// baseline (44402.887 us; speedup 1.0000x reference)
//
#include <hip/hip_runtime.h>
#include <hip/hip_bf16.h>
#include <cstdint>

#define B_    8
#define C_    3
#define H_    32
#define W_    32
#define HID   512
#define HEADS 8
#define FILT  2048
#define L_    6
#define BLEN  256
#define NPIX  256
#define S_    (H_*W_*C_)   /* 3072 */

// ---------------------------------------------------------------------------
// Embedding gather + token shift + positional encoding, ONE BATCH.
// ---------------------------------------------------------------------------
__global__ __launch_bounds__(256) void k_embed(const float* __restrict__ Xb,
                                               const float* __restrict__ emb,
                                               float* __restrict__ xo) {
    int s = blockIdx.x;              // 0..3071
    int h = s / (W_ * C_);
    int j = s - h * (W_ * C_);
    int tid = threadIdx.x;           // dims tid and tid+256

    float e0 = 0.f, e1 = 0.f;
    if (s > 0) {
        int sp = s - 1;
        int hp = sp / (W_ * C_);
        int jp = sp - hp * (W_ * C_);
        int cp = jp % C_;
        int wp = jp / C_;
        float xv = Xb[((size_t)cp * H_ + hp) * W_ + wp];
        int iv = (int)(xv * 255.0f) + cp * NPIX;
        const float* er = emb + (size_t)iv * HID;
        e0 = er[tid]       * 22.627416997969522f;   // sqrt(512)
        e1 = er[tid + 256] * 22.627416997969522f;
    }
    float invd = expf((float)(tid & 127) * -0.07252236513366287f);
    float p0 = (tid < 128) ? sinf((float)h * invd) : cosf((float)h * invd);
    float p1 = (tid < 128) ? sinf((float)j * invd) : cosf((float)j * invd);

    xo[(size_t)s * HID + tid]       = e0 + p0;
    xo[(size_t)s * HID + tid + 256] = e1 + p1;
}

// ---------------------------------------------------------------------------
// fp32 tiled GEMM: C = A(M,K) @ W(K,N) [+bias] [relu].  64x64 tile, 256 thr.
// ---------------------------------------------------------------------------
template<int BIAS, int RELU>
__global__ __launch_bounds__(256) void k_gemm(const float* __restrict__ A,
                                              const float* __restrict__ Bw,
                                              const float* __restrict__ bias,
                                              float* __restrict__ Cc,
                                              int N, int K) {
    __shared__ float As[16][64];   // [k][m]
    __shared__ float Bs[16][64];   // [k][n]
    int tid = threadIdx.x;
    int tx = tid & 15, ty = tid >> 4;
    int row0 = blockIdx.y * 64, col0 = blockIdx.x * 64;

    int am = tid >> 2;
    int ak = (tid & 3) * 4;
    int bk = tid >> 4;
    int bn = (tid & 15) * 4;

    float acc[4][4] = {{0.f}};

    for (int k0 = 0; k0 < K; k0 += 16) {
        float4 av = *(const float4*)(A  + (size_t)(row0 + am) * K + k0 + ak);
        float4 bv = *(const float4*)(Bw + (size_t)(k0 + bk) * N + col0 + bn);
        As[ak + 0][am] = av.x;
        As[ak + 1][am] = av.y;
        As[ak + 2][am] = av.z;
        As[ak + 3][am] = av.w;
        *(float4*)&Bs[bk][bn] = bv;
        __syncthreads();
#pragma unroll
        for (int kk = 0; kk < 16; ++kk) {
            float4 a4 = *(const float4*)&As[kk][ty * 4];
            float4 b4 = *(const float4*)&Bs[kk][tx * 4];
            float ar[4] = {a4.x, a4.y, a4.z, a4.w};
            float br[4] = {b4.x, b4.y, b4.z, b4.w};
#pragma unroll
            for (int i = 0; i < 4; ++i)
#pragma unroll
                for (int jj = 0; jj < 4; ++jj)
                    acc[i][jj] += ar[i] * br[jj];
        }
        __syncthreads();
    }

#pragma unroll
    for (int i = 0; i < 4; ++i) {
        int row = row0 + ty * 4 + i;
        float o[4];
#pragma unroll
        for (int jj = 0; jj < 4; ++jj) {
            o[jj] = acc[i][jj];
            if (BIAS) o[jj] += bias[col0 + tx * 4 + jj];
            if (RELU) o[jj] = fmaxf(o[jj], 0.f);
        }
        float4 ov = {o[0], o[1], o[2], o[3]};
        *(float4*)(Cc + (size_t)row * N + col0 + tx * 4) = ov;
    }
}

// ---------------------------------------------------------------------------
// Block-local causal attention, ONE BATCH. grid=(12, HEADS), block=256.
// ---------------------------------------------------------------------------
__global__ __launch_bounds__(256) void k_attn(const float* __restrict__ Qm,
                                              const float* __restrict__ Km,
                                              const float* __restrict__ Vm,
                                              float* __restrict__ Om) {
    __shared__ float Ks[64][64];
    __shared__ float Vs[64][64];
    int qb  = blockIdx.x;
    int h   = blockIdx.y;
    int tid = threadIdx.x;
    int sq  = qb * BLEN + tid;

    size_t qoff = (size_t)sq * HID + h * 64;
    float q[64];
#pragma unroll
    for (int d = 0; d < 64; d += 4) {
        float4 v = *(const float4*)(Qm + qoff + d);
        q[d]   = v.x * 0.125f; q[d+1] = v.y * 0.125f;
        q[d+2] = v.z * 0.125f; q[d+3] = v.w * 0.125f;
    }

    float acc[64];
#pragma unroll
    for (int d = 0; d < 64; ++d) acc[d] = 0.f;
    float l = 0.f;

    int kstart  = (qb == 0) ? 0 : (qb - 1) * BLEN;
    int nchunks = (qb == 0) ? 4 : 8;

    for (int ck = 0; ck < nchunks; ++ck) {
        int ka = kstart + ck * 64;
        __syncthreads();
        int li = tid;
#pragma unroll
        for (int it = 0; it < 4; ++it, li += 256) {
            int key = li >> 4;
            int seg = (li & 15) * 4;
            size_t goff = (size_t)(ka + key) * HID + h * 64 + seg;
            *(float4*)&Ks[key][seg] = *(const float4*)(Km + goff);
            *(float4*)&Vs[key][seg] = *(const float4*)(Vm + goff);
        }
        __syncthreads();

        int nk = sq - ka + 1;
        if (nk > 64) nk = 64;
        for (int kk = 0; kk < nk; ++kk) {
            float dot = 0.f;
#pragma unroll
            for (int d = 0; d < 64; ++d) dot += q[d] * Ks[kk][d];
            float p = expf(dot);
            l += p;
#pragma unroll
            for (int d = 0; d < 64; ++d) acc[d] += p * Vs[kk][d];
        }
    }

    float rl = 1.0f / l;
    size_t ooff = (size_t)sq * HID + h * 64;
#pragma unroll
    for (int d = 0; d < 64; ++d) Om[ooff + d] = acc[d] * rl;
}

// ---------------------------------------------------------------------------
// x = LayerNorm(T + x) * g + b
// ---------------------------------------------------------------------------
__global__ __launch_bounds__(256) void k_addln(const float* __restrict__ T,
                                               float* __restrict__ X,
                                               const float* __restrict__ g,
                                               const float* __restrict__ bb) {
    __shared__ float red[8];
    int r = blockIdx.x;
    size_t off = (size_t)r * HID;
    int tid = threadIdx.x;
    float v0 = T[off + tid]       + X[off + tid];
    float v1 = T[off + tid + 256] + X[off + tid + 256];
    float s  = v0 + v1;
    float sq = v0 * v0 + v1 * v1;
#pragma unroll
    for (int o = 32; o > 0; o >>= 1) {
        s  += __shfl_down(s,  o, 64);
        sq += __shfl_down(sq, o, 64);
    }
    int wid = tid >> 6;
    if ((tid & 63) == 0) { red[wid] = s; red[4 + wid] = sq; }
    __syncthreads();
    if (tid == 0) {
        red[0] = red[0] + red[1] + red[2] + red[3];
        red[4] = red[4] + red[5] + red[6] + red[7];
    }
    __syncthreads();
    float mean = red[0] * (1.0f / 512.0f);
    float var  = red[4] * (1.0f / 512.0f) - mean * mean;
    float rs   = rsqrtf(var + 1e-6f);
    X[off + tid]       = (v0 - mean) * rs * g[tid]       + bb[tid];
    X[off + tid + 256] = (v1 - mean) * rs * g[tid + 256] + bb[tid + 256];
}

// ---------------------------------------------------------------------------
// (S_,NPIX) fp32 logits of ONE batch -> (C,H,W,NPIX) **fp32** output slab.
// d_out hypothesis B: float32 (matches reference return dtype).
// ---------------------------------------------------------------------------
__global__ __launch_bounds__(256) void k_permute(const float* __restrict__ T,
                                                 float* __restrict__ Ob) {
    int s = blockIdx.x;
    int p = threadIdx.x;
    int h = s / (W_ * C_);
    int j = s - h * (W_ * C_);
    int w = j / C_;
    int c = j - w * C_;
    Ob[(((size_t)c * H_ + h) * W_ + w) * NPIX + p] = T[(size_t)s * NPIX + p];
}

// ---------------------------------------------------------------------------
extern "C" void kernel_launch(void* const* d_in, const int* in_sizes, int n_in,
                              void* d_out, int out_size, void* d_ws, size_t ws_size,
                              hipStream_t stream) {
    const float* X    = (const float*)d_in[0];
    const float* emb  = (const float*)d_in[1];
    const float* Wq   = (const float*)d_in[2];
    const float* Wk   = (const float*)d_in[3];
    const float* Wv   = (const float*)d_in[4];
    const float* Wo   = (const float*)d_in[5];
    const float* g1   = (const float*)d_in[6];
    const float* b1l  = (const float*)d_in[7];
    const float* W1   = (const float*)d_in[8];
    const float* bb1  = (const float*)d_in[9];
    const float* W2   = (const float*)d_in[10];
    const float* bb2  = (const float*)d_in[11];
    const float* g2   = (const float*)d_in[12];
    const float* b2l  = (const float*)d_in[13];
    const float* Wout = (const float*)d_in[14];
    const float* bout = (const float*)d_in[15];
    float* out = (float*)d_out;
    (void)ws_size; (void)in_sizes; (void)n_in; (void)out_size;

    // Per-batch workspace: 6 x S_*HID fp32 = 36 MiB (proven-safe footprint).
    const size_t SH = (size_t)S_ * HID;
    float* xb  = (float*)d_ws;
    float* q32 = xb  + SH;
    float* k32 = q32 + SH;
    float* v32 = k32 + SH;
    float* a32 = v32 + SH;
    float* f32 = a32 + SH;
    float* hid32  = q32;                    // FFN hidden = q..a span (exact)
    float* logits = q32;

    dim3 gB(HID / 64, S_ / 64);

    for (int b = 0; b < B_; ++b) {
        k_embed<<<S_, 256, 0, stream>>>(X + (size_t)b * C_ * H_ * W_, emb, xb);

        for (int i = 0; i < L_; ++i) {
            const float* wq = Wq + (size_t)i * HID * HID;
            const float* wk = Wk + (size_t)i * HID * HID;
            const float* wv = Wv + (size_t)i * HID * HID;
            const float* wo = Wo + (size_t)i * HID * HID;

            k_gemm<0,0><<<gB, 256, 0, stream>>>(xb, wq, nullptr, q32, HID, HID);
            k_gemm<0,0><<<gB, 256, 0, stream>>>(xb, wk, nullptr, k32, HID, HID);
            k_gemm<0,0><<<gB, 256, 0, stream>>>(xb, wv, nullptr, v32, HID, HID);

            k_attn<<<dim3(S_ / BLEN, HEADS), 256, 0, stream>>>(q32, k32, v32, a32);

            k_gemm<0,0><<<gB, 256, 0, stream>>>(a32, wo, nullptr, f32, HID, HID);
            k_addln<<<S_, 256, 0, stream>>>(f32, xb, g1 + i * HID, b1l + i * HID);

            k_gemm<1,1><<<dim3(FILT / 64, S_ / 64), 256, 0, stream>>>(
                xb, W1 + (size_t)i * HID * FILT, bb1 + i * FILT, hid32, FILT, HID);
            k_gemm<1,0><<<dim3(HID / 64, S_ / 64), 256, 0, stream>>>(
                hid32, W2 + (size_t)i * FILT * HID, bb2 + i * HID, f32, HID, FILT);
            k_addln<<<S_, 256, 0, stream>>>(f32, xb, g2 + i * HID, b2l + i * HID);
        }

        k_gemm<1,0><<<dim3(NPIX / 64, S_ / 64), 256, 0, stream>>>(
            xb, Wout, bout, logits, NPIX, HID);
        k_permute<<<S_, 256, 0, stream>>>(
            logits, out + (size_t)b * C_ * H_ * W_ * NPIX);
    }
}

// Round 10
// 8492.661 us; speedup vs baseline: 5.2284x; 5.2284x over previous
//
#include <hip/hip_runtime.h>
#include <hip/hip_bf16.h>
#include <cstdint>

#define B_    8
#define C_    3
#define H_    32
#define W_    32
#define HID   512
#define HEADS 8
#define FILT  2048
#define L_    6
#define BLEN  256
#define NPIX  256
#define S_    (H_*W_*C_)   /* 3072 */
#define MROWS (B_*S_)      /* 24576 */

typedef unsigned short u16;
typedef short bf16x8 __attribute__((ext_vector_type(8)));
typedef float f32x4  __attribute__((ext_vector_type(4)));

__device__ __forceinline__ float bf2f(u16 u) {
    union { unsigned int i; float f; } x; x.i = ((unsigned int)u) << 16; return x.f;
}
__device__ __forceinline__ u16 f2bf(float f) {
    __hip_bfloat16 h = __float2bfloat16(f);
    return *reinterpret_cast<u16*>(&h);
}

// ---------------------------------------------------------------------------
// Embedding gather + token shift + positional encoding -> x (MROWS, HID) fp32
// ---------------------------------------------------------------------------
__global__ __launch_bounds__(256) void k_embed(const float* __restrict__ X,
                                               const float* __restrict__ emb,
                                               float* __restrict__ xo) {
    int r = blockIdx.x;              // b*S + s
    int b = r / S_, s = r - b * S_;
    int h = s / (W_ * C_);
    int j = s - h * (W_ * C_);
    int tid = threadIdx.x;

    float e0 = 0.f, e1 = 0.f;
    if (s > 0) {
        int sp = s - 1;
        int hp = sp / (W_ * C_);
        int jp = sp - hp * (W_ * C_);
        int cp = jp % C_;
        int wp = jp / C_;
        float xv = X[(((size_t)b * C_ + cp) * H_ + hp) * W_ + wp];
        int iv = (int)(xv * 255.0f) + cp * NPIX;
        const float* er = emb + (size_t)iv * HID;
        e0 = er[tid]       * 22.627416997969522f;   // sqrt(512)
        e1 = er[tid + 256] * 22.627416997969522f;
    }
    float invd = expf((float)(tid & 127) * -0.07252236513366287f);
    float p0 = (tid < 128) ? sinf((float)h * invd) : cosf((float)h * invd);
    float p1 = (tid < 128) ? sinf((float)j * invd) : cosf((float)j * invd);

    xo[(size_t)r * HID + tid]       = e0 + p0;
    xo[(size_t)r * HID + tid + 256] = e1 + p1;
}

// ---------------------------------------------------------------------------
// bf16 MFMA GEMM: C = A(M,K) @ W(K,N) [+bias] [relu]
// A: fp32 or bf16 (A_BF). W,bias: fp32 (converted in staging). C: fp32/bf16.
// 128x128 tile, 4 waves (64x64 each), BK=32, mfma_f32_16x16x32_bf16.
// M,N mult of 128; K mult of 32. Grid: (N/128, M/128).
// ---------------------------------------------------------------------------
template<int A_BF, int C_BF, int BIAS, int RELU>
__global__ __launch_bounds__(256) void g_mfma(const void* __restrict__ Ap,
                                              const float* __restrict__ Bw,
                                              const float* __restrict__ bias,
                                              void* __restrict__ Cp,
                                              int N, int K) {
    __shared__ __align__(16) u16 As[128][40];   // [m][k], pad->b128-friendly
    __shared__ __align__(16) u16 Bs[128][40];   // [n][k] (transposed W tile)
    int tid  = threadIdx.x;
    int row0 = blockIdx.y * 128, col0 = blockIdx.x * 128;

    int ar  = tid >> 1;              // 0..127 (A row)
    int akq = (tid & 1) << 4;        // 0/16   (A k-seg)
    int bkk = tid >> 5;              // 0..7   (B k-base)
    int bnn = (tid & 31) << 2;       // 0..124 (B n-base)

    int lane = tid & 63;
    int wv   = tid >> 6;
    int wr   = (wv >> 1) << 6;       // wave row offset (0/64)
    int wc   = (wv & 1) << 6;        // wave col offset (0/64)
    int lr   = lane & 15;
    int kb   = lane >> 4;            // 0..3

    f32x4 acc[4][4];
#pragma unroll
    for (int mi = 0; mi < 4; ++mi)
#pragma unroll
        for (int nj = 0; nj < 4; ++nj)
            acc[mi][nj] = (f32x4){0.f, 0.f, 0.f, 0.f};

    for (int k0 = 0; k0 < K; k0 += 32) {
        // ---- stage A tile (128x32) ----
        if (A_BF) {
            const u16* ap = (const u16*)Ap + (size_t)(row0 + ar) * K + k0 + akq;
#pragma unroll
            for (int p = 0; p < 4; ++p)
                *(ushort4*)&As[ar][akq + (p << 2)] = *(const ushort4*)(ap + (p << 2));
        } else {
            const float* ap = (const float*)Ap + (size_t)(row0 + ar) * K + k0 + akq;
#pragma unroll
            for (int p = 0; p < 4; ++p) {
                float4 v = *(const float4*)(ap + (p << 2));
                ushort4 w = {f2bf(v.x), f2bf(v.y), f2bf(v.z), f2bf(v.w)};
                *(ushort4*)&As[ar][akq + (p << 2)] = w;
            }
        }
        // ---- stage B tile transposed: Bs[n][k] = W[k0+k][col0+n] ----
#pragma unroll
        for (int p = 0; p < 4; ++p) {
            int kl = bkk + (p << 3);
            float4 w = *(const float4*)(Bw + (size_t)(k0 + kl) * N + col0 + bnn);
            Bs[bnn + 0][kl] = f2bf(w.x);
            Bs[bnn + 1][kl] = f2bf(w.y);
            Bs[bnn + 2][kl] = f2bf(w.z);
            Bs[bnn + 3][kl] = f2bf(w.w);
        }
        __syncthreads();

        // ---- 16 MFMA ----
        bf16x8 af[4], bfr[4];
#pragma unroll
        for (int mi = 0; mi < 4; ++mi)
            af[mi] = *(const bf16x8*)&As[wr + (mi << 4) + lr][kb << 3];
#pragma unroll
        for (int nj = 0; nj < 4; ++nj)
            bfr[nj] = *(const bf16x8*)&Bs[wc + (nj << 4) + lr][kb << 3];
#pragma unroll
        for (int mi = 0; mi < 4; ++mi)
#pragma unroll
            for (int nj = 0; nj < 4; ++nj)
                acc[mi][nj] = __builtin_amdgcn_mfma_f32_16x16x32_bf16(
                    af[mi], bfr[nj], acc[mi][nj], 0, 0, 0);
        __syncthreads();
    }

    // ---- epilogue: D col=lane&15, row=(lane>>4)*4+reg ----
#pragma unroll
    for (int mi = 0; mi < 4; ++mi)
#pragma unroll
        for (int nj = 0; nj < 4; ++nj) {
            int col = col0 + wc + (nj << 4) + lr;
            float bsv = BIAS ? bias[col] : 0.f;
#pragma unroll
            for (int reg = 0; reg < 4; ++reg) {
                int row = row0 + wr + (mi << 4) + (kb << 2) + reg;
                float v = acc[mi][nj][reg] + bsv;
                if (RELU) v = fmaxf(v, 0.f);
                if (C_BF)
                    ((u16*)Cp)[(size_t)row * N + col] = f2bf(v);
                else
                    ((float*)Cp)[(size_t)row * N + col] = v;
            }
        }
}

// ---------------------------------------------------------------------------
// Block-local causal attention (bf16 QKV/O), batched. grid=(12, B*HEADS).
// O aliases Q: each thread fully reads its q before any O write, and
// (row, head-slice) ownership is disjoint across threads/blocks.
// ---------------------------------------------------------------------------
__global__ __launch_bounds__(256) void k_attn(const u16* Qm,
                                              const u16* __restrict__ Km,
                                              const u16* __restrict__ Vm,
                                              u16* Om) {
    __shared__ float Ks[64][64];
    __shared__ float Vs[64][64];
    int qb  = blockIdx.x;            // 0..11
    int bh  = blockIdx.y;            // b*HEADS+h
    int b   = bh >> 3, h = bh & 7;
    int tid = threadIdx.x;
    int sq  = qb * BLEN + tid;

    size_t qoff = ((size_t)b * S_ + sq) * HID + h * 64;
    float q[64];
#pragma unroll
    for (int d = 0; d < 64; d += 4) {
        ushort4 u = *(const ushort4*)(Qm + qoff + d);
        q[d]   = bf2f(u.x) * 0.125f;
        q[d+1] = bf2f(u.y) * 0.125f;
        q[d+2] = bf2f(u.z) * 0.125f;
        q[d+3] = bf2f(u.w) * 0.125f;
    }

    float acc[64];
#pragma unroll
    for (int d = 0; d < 64; ++d) acc[d] = 0.f;
    float l = 0.f;

    int kstart  = (qb == 0) ? 0 : (qb - 1) * BLEN;
    int nchunks = (qb == 0) ? 4 : 8;

    for (int ck = 0; ck < nchunks; ++ck) {
        int ka = kstart + ck * 64;
        __syncthreads();
        int li = tid;
#pragma unroll
        for (int it = 0; it < 4; ++it, li += 256) {
            int key = li >> 4;
            int seg = (li & 15) * 4;
            size_t goff = ((size_t)b * S_ + ka + key) * HID + h * 64 + seg;
            ushort4 ku = *(const ushort4*)(Km + goff);
            ushort4 vu = *(const ushort4*)(Vm + goff);
            Ks[key][seg+0] = bf2f(ku.x); Ks[key][seg+1] = bf2f(ku.y);
            Ks[key][seg+2] = bf2f(ku.z); Ks[key][seg+3] = bf2f(ku.w);
            Vs[key][seg+0] = bf2f(vu.x); Vs[key][seg+1] = bf2f(vu.y);
            Vs[key][seg+2] = bf2f(vu.z); Vs[key][seg+3] = bf2f(vu.w);
        }
        __syncthreads();

        int nk = sq - ka + 1;          // causal: keys [ka, sq]
        if (nk > 64) nk = 64;
        for (int kk = 0; kk < nk; ++kk) {
            float dot = 0.f;
#pragma unroll
            for (int d = 0; d < 64; ++d) dot += q[d] * Ks[kk][d];
            float p = expf(dot);
            l += p;
#pragma unroll
            for (int d = 0; d < 64; ++d) acc[d] += p * Vs[kk][d];
        }
    }

    float rl = 1.0f / l;
    size_t ooff = ((size_t)b * S_ + sq) * HID + h * 64;
#pragma unroll
    for (int d = 0; d < 64; d += 4) {
        ushort4 s;
        s.x = f2bf(acc[d]   * rl); s.y = f2bf(acc[d+1] * rl);
        s.z = f2bf(acc[d+2] * rl); s.w = f2bf(acc[d+3] * rl);
        *(ushort4*)(Om + ooff + d) = s;
    }
}

// ---------------------------------------------------------------------------
// x32 = LayerNorm(T16 + x32) * g + b
// ---------------------------------------------------------------------------
__global__ __launch_bounds__(256) void k_addln(const u16* __restrict__ T,
                                               float* __restrict__ X,
                                               const float* __restrict__ g,
                                               const float* __restrict__ bb) {
    __shared__ float red[8];
    int r = blockIdx.x;
    size_t off = (size_t)r * HID;
    int tid = threadIdx.x;
    float v0 = bf2f(T[off + tid])       + X[off + tid];
    float v1 = bf2f(T[off + tid + 256]) + X[off + tid + 256];
    float s  = v0 + v1;
    float sq = v0 * v0 + v1 * v1;
#pragma unroll
    for (int o = 32; o > 0; o >>= 1) {
        s  += __shfl_down(s,  o, 64);
        sq += __shfl_down(sq, o, 64);
    }
    int wid = tid >> 6;
    if ((tid & 63) == 0) { red[wid] = s; red[4 + wid] = sq; }
    __syncthreads();
    if (tid == 0) {
        red[0] = red[0] + red[1] + red[2] + red[3];
        red[4] = red[4] + red[5] + red[6] + red[7];
    }
    __syncthreads();
    float mean = red[0] * (1.0f / 512.0f);
    float var  = red[4] * (1.0f / 512.0f) - mean * mean;
    float rs   = rsqrtf(var + 1e-6f);
    X[off + tid]       = (v0 - mean) * rs * g[tid]       + bb[tid];
    X[off + tid + 256] = (v1 - mean) * rs * g[tid + 256] + bb[tid + 256];
}

// ---------------------------------------------------------------------------
// (B,S,NPIX) fp32 logits -> (B,C,H,W,NPIX) fp32 output
// ---------------------------------------------------------------------------
__global__ __launch_bounds__(256) void k_permute(const float* __restrict__ T,
                                                 float* __restrict__ O) {
    int r = blockIdx.x;          // b*S + s
    int p = threadIdx.x;
    int b = r / S_, s = r - b * S_;
    int h = s / (W_ * C_);
    int j = s - h * (W_ * C_);
    int w = j / C_;
    int c = j - w * C_;
    O[((((size_t)b * C_ + c) * H_ + h) * W_ + w) * NPIX + p] =
        T[(size_t)r * NPIX + p];
}

// ---------------------------------------------------------------------------
extern "C" void kernel_launch(void* const* d_in, const int* in_sizes, int n_in,
                              void* d_out, int out_size, void* d_ws, size_t ws_size,
                              hipStream_t stream) {
    const float* X    = (const float*)d_in[0];
    const float* emb  = (const float*)d_in[1];
    const float* Wq   = (const float*)d_in[2];
    const float* Wk   = (const float*)d_in[3];
    const float* Wv   = (const float*)d_in[4];
    const float* Wo   = (const float*)d_in[5];
    const float* g1   = (const float*)d_in[6];
    const float* b1l  = (const float*)d_in[7];
    const float* W1   = (const float*)d_in[8];
    const float* bb1  = (const float*)d_in[9];
    const float* W2   = (const float*)d_in[10];
    const float* bb2  = (const float*)d_in[11];
    const float* g2   = (const float*)d_in[12];
    const float* b2l  = (const float*)d_in[13];
    const float* Wout = (const float*)d_in[14];
    const float* bout = (const float*)d_in[15];
    float* out = (float*)d_out;
    (void)ws_size; (void)in_sizes; (void)n_in; (void)out_size;

    // Workspace (125.8 MB, = round-3 footprint that ran fault-free):
    //   x32 (fp32 residual, 50.3MB) | q16 | k16 | v16 (bf16, 25.2MB each)
    //   FFN hidden chunk (12288x2048 bf16 = 50.3MB) = q16..k16 span
    //   fp32 logits (24576x256 = 25.2MB) = q16 span
    const size_t NB = (size_t)MROWS * HID;
    float* x32 = (float*)d_ws;
    u16*   q16 = (u16*)(x32 + NB);
    u16*   k16 = q16 + NB;
    u16*   v16 = k16 + NB;
    u16*   hid16  = q16;
    float* logits = (float*)q16;

    k_embed<<<MROWS, 256, 0, stream>>>(X, emb, x32);

    dim3 gQKV(HID / 128, MROWS / 128);          // (4, 192)
    dim3 gW1(FILT / 128, (MROWS / 2) / 128);    // (16, 96)
    dim3 gW2(HID / 128, (MROWS / 2) / 128);     // (4, 96)
    dim3 gOut(NPIX / 128, MROWS / 128);         // (2, 192)

    for (int i = 0; i < L_; ++i) {
        const float* wq = Wq + (size_t)i * HID * HID;
        const float* wk = Wk + (size_t)i * HID * HID;
        const float* wv = Wv + (size_t)i * HID * HID;
        const float* wo = Wo + (size_t)i * HID * HID;

        g_mfma<0,1,0,0><<<gQKV, 256, 0, stream>>>(x32, wq, nullptr, q16, HID, HID);
        g_mfma<0,1,0,0><<<gQKV, 256, 0, stream>>>(x32, wk, nullptr, k16, HID, HID);
        g_mfma<0,1,0,0><<<gQKV, 256, 0, stream>>>(x32, wv, nullptr, v16, HID, HID);

        k_attn<<<dim3(S_ / BLEN, B_ * HEADS), 256, 0, stream>>>(q16, k16, v16, q16);

        g_mfma<1,1,0,0><<<gQKV, 256, 0, stream>>>(q16, wo, nullptr, k16, HID, HID);
        k_addln<<<MROWS, 256, 0, stream>>>(k16, x32, g1 + i * HID, b1l + i * HID);

        // FFN in 2 row-chunks of 12288 (hidden chunk fits q16+k16 span)
        for (int c = 0; c < 2; ++c) {
            const size_t r0 = (size_t)c * (MROWS / 2);
            g_mfma<0,1,1,1><<<gW1, 256, 0, stream>>>(
                x32 + r0 * HID, W1 + (size_t)i * HID * FILT,
                bb1 + i * FILT, hid16, FILT, HID);
            g_mfma<1,1,1,0><<<gW2, 256, 0, stream>>>(
                hid16, W2 + (size_t)i * FILT * HID,
                bb2 + i * HID, v16 + r0 * HID, HID, FILT);
        }
        k_addln<<<MROWS, 256, 0, stream>>>(v16, x32, g2 + i * HID, b2l + i * HID);
    }

    g_mfma<0,0,1,0><<<gOut, 256, 0, stream>>>(x32, Wout, bout, logits, NPIX, HID);
    k_permute<<<MROWS, 256, 0, stream>>>(logits, out);
}

// Round 11
// 5398.940 us; speedup vs baseline: 8.2244x; 1.5730x over previous
//
#include <hip/hip_runtime.h>
#include <hip/hip_bf16.h>
#include <cstdint>

#define B_    8
#define C_    3
#define H_    32
#define W_    32
#define HID   512
#define HEADS 8
#define FILT  2048
#define L_    6
#define BLEN  256
#define NPIX  256
#define S_    (H_*W_*C_)   /* 3072 */
#define MROWS (B_*S_)      /* 24576 */

typedef unsigned short u16;
typedef short bf16x8 __attribute__((ext_vector_type(8)));
typedef float f32x4  __attribute__((ext_vector_type(4)));

__device__ __forceinline__ float bf2f(u16 u) {
    union { unsigned int i; float f; } x; x.i = ((unsigned int)u) << 16; return x.f;
}
__device__ __forceinline__ u16 f2bf(float f) {
    __hip_bfloat16 h = __float2bfloat16(f);
    return *reinterpret_cast<u16*>(&h);
}

#define GLP(p) ((const __attribute__((address_space(1))) void*)(p))
#define LLP(p) ((__attribute__((address_space(3))) void*)(p))

// ---------------------------------------------------------------------------
// Embedding gather + shift + positional -> x32 (fp32) and optional x16 (bf16)
// ---------------------------------------------------------------------------
__global__ __launch_bounds__(256) void k_embed(const float* __restrict__ X,
                                               const float* __restrict__ emb,
                                               float* __restrict__ xo,
                                               u16* __restrict__ xo16) {
    int r = blockIdx.x;              // b*S + s
    int b = r / S_, s = r - b * S_;
    int h = s / (W_ * C_);
    int j = s - h * (W_ * C_);
    int tid = threadIdx.x;

    float e0 = 0.f, e1 = 0.f;
    if (s > 0) {
        int sp = s - 1;
        int hp = sp / (W_ * C_);
        int jp = sp - hp * (W_ * C_);
        int cp = jp % C_;
        int wp = jp / C_;
        float xv = X[(((size_t)b * C_ + cp) * H_ + hp) * W_ + wp];
        int iv = (int)(xv * 255.0f) + cp * NPIX;
        const float* er = emb + (size_t)iv * HID;
        e0 = er[tid]       * 22.627416997969522f;   // sqrt(512)
        e1 = er[tid + 256] * 22.627416997969522f;
    }
    float invd = expf((float)(tid & 127) * -0.07252236513366287f);
    float p0 = (tid < 128) ? sinf((float)h * invd) : cosf((float)h * invd);
    float p1 = (tid < 128) ? sinf((float)j * invd) : cosf((float)j * invd);

    float v0 = e0 + p0, v1 = e1 + p1;
    xo[(size_t)r * HID + tid]       = v0;
    xo[(size_t)r * HID + tid + 256] = v1;
    if (xo16) {
        xo16[(size_t)r * HID + tid]       = f2bf(v0);
        xo16[(size_t)r * HID + tid + 256] = f2bf(v1);
    }
}

// ---------------------------------------------------------------------------
// 64x64 tile transpose+convert: out[N][K] (bf16) = in[K][N] (fp32).
// grid (N/64, K/64, nz); in += z*inStride, out += z*outStride.
// ---------------------------------------------------------------------------
__global__ __launch_bounds__(256) void k_trans_g(const float* __restrict__ in,
                                                 u16* __restrict__ out,
                                                 int N, int K,
                                                 size_t inStride, size_t outStride) {
    __shared__ u16 T[64][72];
    in  += (size_t)blockIdx.z * inStride;
    out += (size_t)blockIdx.z * outStride;
    int n0 = blockIdx.x * 64, k0 = blockIdx.y * 64;
    int t = threadIdx.x;
    int r4 = t >> 4;            // 0..15
    int c4 = (t & 15) << 2;     // 0..60
#pragma unroll
    for (int pass = 0; pass < 4; ++pass) {
        int kr = pass * 16 + r4;
        float4 v = *(const float4*)(in + (size_t)(k0 + kr) * N + n0 + c4);
        T[c4 + 0][kr] = f2bf(v.x);
        T[c4 + 1][kr] = f2bf(v.y);
        T[c4 + 2][kr] = f2bf(v.z);
        T[c4 + 3][kr] = f2bf(v.w);
    }
    __syncthreads();
#pragma unroll
    for (int pass = 0; pass < 4; ++pass) {
        int n = pass * 16 + r4;
        ushort4 s = {T[n][c4], T[n][c4 + 1], T[n][c4 + 2], T[n][c4 + 3]};
        *(ushort4*)(out + (size_t)(n0 + n) * K + k0 + c4) = s;
    }
}

// ---------------------------------------------------------------------------
// Pure-bf16 MFMA GEMM (m97-style): C = A(M,K) @ Bt(N,K)^T  [+bias][relu]
// A [M][K] bf16, Bt [N][K] bf16 (pre-transposed weights).
// 128x128 tile, 4 waves (64x64 quadrants), BK=64, global_load_lds w16,
// XOR-swizzled LDS (source-preswizzle + swizzled ds_read, involution).
// QKV=1: cols 0..1535 routed to C0/C1/C2 by col>>9, C stride Nc=512.
// ---------------------------------------------------------------------------
template<int QKV, int C_BF, int BIAS, int RELU>
__global__ __launch_bounds__(256) void g_bf16(const u16* __restrict__ A,
                                              const u16* __restrict__ Bt,
                                              const float* __restrict__ bias,
                                              void* __restrict__ C0,
                                              void* __restrict__ C1,
                                              void* __restrict__ C2,
                                              int Nc, int K) {
    __shared__ __align__(16) u16 As[128 * 64];   // linear [row][64k], swizzled
    __shared__ __align__(16) u16 Bs[128 * 64];
    int tid  = threadIdx.x;
    int lane = tid & 63;
    int w    = tid >> 6;
    int row0 = blockIdx.y * 128, col0 = blockIdx.x * 128;

    // --- staging geometry (per lane) ---
    int l8 = lane >> 3;                   // 0..7
    int l7 = lane & 7;                    // 0..7
    int scol = (l7 ^ l8) << 3;            // pre-swizzled source col (elems)
    const u16* aP = A  + (size_t)(row0 + w * 32 + l8) * K + scol;
    const u16* bP = Bt + (size_t)(col0 + w * 32 + l8) * K + scol;
    u16* asBase = As + w * 2048;          // wave-uniform LDS bases
    u16* bsBase = Bs + w * 2048;

    // --- fragment geometry ---
    int wr = (w >> 1) << 6;               // wave row quadrant (0/64)
    int wc = (w & 1) << 6;                // wave col quadrant (0/64)
    int lr = lane & 15;
    int kb = lane >> 4;                   // 0..3

    f32x4 acc[4][4];
#pragma unroll
    for (int mi = 0; mi < 4; ++mi)
#pragma unroll
        for (int nj = 0; nj < 4; ++nj)
            acc[mi][nj] = (f32x4){0.f, 0.f, 0.f, 0.f};

    for (int k0 = 0; k0 < K; k0 += 64) {
#pragma unroll
        for (int p = 0; p < 4; ++p) {
            __builtin_amdgcn_global_load_lds(GLP(aP + (size_t)p * 8 * K),
                                             LLP(asBase + p * 512), 16, 0, 0);
            __builtin_amdgcn_global_load_lds(GLP(bP + (size_t)p * 8 * K),
                                             LLP(bsBase + p * 512), 16, 0, 0);
        }
        aP += 64; bP += 64;
        __syncthreads();

#pragma unroll
        for (int kh = 0; kh < 2; ++kh) {
            int s = ((kh << 2) + kb) ^ (lr & 7);      // swizzled 16B slot
            bf16x8 af[4], bv[4];
#pragma unroll
            for (int mi = 0; mi < 4; ++mi)
                af[mi] = *(const bf16x8*)&As[(wr + lr) * 64 + mi * 1024 + s * 8];
#pragma unroll
            for (int nj = 0; nj < 4; ++nj)
                bv[nj] = *(const bf16x8*)&Bs[(wc + lr) * 64 + nj * 1024 + s * 8];
#pragma unroll
            for (int mi = 0; mi < 4; ++mi)
#pragma unroll
                for (int nj = 0; nj < 4; ++nj)
                    acc[mi][nj] = __builtin_amdgcn_mfma_f32_16x16x32_bf16(
                        af[mi], bv[nj], acc[mi][nj], 0, 0, 0);
        }
        __syncthreads();
    }

    // --- epilogue (validated D map: col=lane&15, row=(lane>>4)*4+reg) ---
#pragma unroll
    for (int nj = 0; nj < 4; ++nj) {
        int colg = col0 + wc + (nj << 4) + lr;        // col in Bt-space
        void* Cp; int ccol;
        if (QKV) {
            int sel = colg >> 9;
            Cp = (sel == 0) ? C0 : (sel == 1) ? C1 : C2;
            ccol = colg & 511;
        } else { Cp = C0; ccol = colg; }
        float bsv = BIAS ? bias[colg] : 0.f;
#pragma unroll
        for (int mi = 0; mi < 4; ++mi) {
#pragma unroll
            for (int reg = 0; reg < 4; ++reg) {
                int row = row0 + wr + (mi << 4) + (kb << 2) + reg;
                float v = acc[mi][nj][reg] + bsv;
                if (RELU) v = fmaxf(v, 0.f);
                if (C_BF)
                    ((u16*)Cp)[(size_t)row * Nc + ccol] = f2bf(v);
                else
                    ((float*)Cp)[(size_t)row * Nc + ccol] = v;
            }
        }
    }
}

// ---------------------------------------------------------------------------
// LEGACY fp32-staged MFMA GEMM (round-10, proven) — fallback path only.
// ---------------------------------------------------------------------------
template<int A_BF, int C_BF, int BIAS, int RELU>
__global__ __launch_bounds__(256) void g_mfma(const void* __restrict__ Ap,
                                              const float* __restrict__ Bw,
                                              const float* __restrict__ bias,
                                              void* __restrict__ Cp,
                                              int N, int K) {
    __shared__ __align__(16) u16 As[128][40];
    __shared__ __align__(16) u16 Bs[128][40];
    int tid  = threadIdx.x;
    int row0 = blockIdx.y * 128, col0 = blockIdx.x * 128;

    int ar  = tid >> 1;
    int akq = (tid & 1) << 4;
    int bkk = tid >> 5;
    int bnn = (tid & 31) << 2;

    int lane = tid & 63;
    int wv   = tid >> 6;
    int wr   = (wv >> 1) << 6;
    int wc   = (wv & 1) << 6;
    int lr   = lane & 15;
    int kb   = lane >> 4;

    f32x4 acc[4][4];
#pragma unroll
    for (int mi = 0; mi < 4; ++mi)
#pragma unroll
        for (int nj = 0; nj < 4; ++nj)
            acc[mi][nj] = (f32x4){0.f, 0.f, 0.f, 0.f};

    for (int k0 = 0; k0 < K; k0 += 32) {
        if (A_BF) {
            const u16* ap = (const u16*)Ap + (size_t)(row0 + ar) * K + k0 + akq;
#pragma unroll
            for (int p = 0; p < 4; ++p)
                *(ushort4*)&As[ar][akq + (p << 2)] = *(const ushort4*)(ap + (p << 2));
        } else {
            const float* ap = (const float*)Ap + (size_t)(row0 + ar) * K + k0 + akq;
#pragma unroll
            for (int p = 0; p < 4; ++p) {
                float4 v = *(const float4*)(ap + (p << 2));
                ushort4 wq = {f2bf(v.x), f2bf(v.y), f2bf(v.z), f2bf(v.w)};
                *(ushort4*)&As[ar][akq + (p << 2)] = wq;
            }
        }
#pragma unroll
        for (int p = 0; p < 4; ++p) {
            int kl = bkk + (p << 3);
            float4 wv4 = *(const float4*)(Bw + (size_t)(k0 + kl) * N + col0 + bnn);
            Bs[bnn + 0][kl] = f2bf(wv4.x);
            Bs[bnn + 1][kl] = f2bf(wv4.y);
            Bs[bnn + 2][kl] = f2bf(wv4.z);
            Bs[bnn + 3][kl] = f2bf(wv4.w);
        }
        __syncthreads();

        bf16x8 af[4], bfr[4];
#pragma unroll
        for (int mi = 0; mi < 4; ++mi)
            af[mi] = *(const bf16x8*)&As[wr + (mi << 4) + lr][kb << 3];
#pragma unroll
        for (int nj = 0; nj < 4; ++nj)
            bfr[nj] = *(const bf16x8*)&Bs[wc + (nj << 4) + lr][kb << 3];
#pragma unroll
        for (int mi = 0; mi < 4; ++mi)
#pragma unroll
            for (int nj = 0; nj < 4; ++nj)
                acc[mi][nj] = __builtin_amdgcn_mfma_f32_16x16x32_bf16(
                    af[mi], bfr[nj], acc[mi][nj], 0, 0, 0);
        __syncthreads();
    }

#pragma unroll
    for (int mi = 0; mi < 4; ++mi)
#pragma unroll
        for (int nj = 0; nj < 4; ++nj) {
            int col = col0 + wc + (nj << 4) + lr;
            float bsv = BIAS ? bias[col] : 0.f;
#pragma unroll
            for (int reg = 0; reg < 4; ++reg) {
                int row = row0 + wr + (mi << 4) + (kb << 2) + reg;
                float v = acc[mi][nj][reg] + bsv;
                if (RELU) v = fmaxf(v, 0.f);
                if (C_BF)
                    ((u16*)Cp)[(size_t)row * N + col] = f2bf(v);
                else
                    ((float*)Cp)[(size_t)row * N + col] = v;
            }
        }
}

// ---------------------------------------------------------------------------
// Block-local causal attention (bf16 QKV/O), batched. grid=(12, B*HEADS).
// ---------------------------------------------------------------------------
__global__ __launch_bounds__(256) void k_attn(const u16* Qm,
                                              const u16* __restrict__ Km,
                                              const u16* __restrict__ Vm,
                                              u16* Om) {
    __shared__ float Ks[64][64];
    __shared__ float Vs[64][64];
    int qb  = blockIdx.x;
    int bh  = blockIdx.y;
    int b   = bh >> 3, h = bh & 7;
    int tid = threadIdx.x;
    int sq  = qb * BLEN + tid;

    size_t qoff = ((size_t)b * S_ + sq) * HID + h * 64;
    float q[64];
#pragma unroll
    for (int d = 0; d < 64; d += 4) {
        ushort4 u = *(const ushort4*)(Qm + qoff + d);
        q[d]   = bf2f(u.x) * 0.125f;
        q[d+1] = bf2f(u.y) * 0.125f;
        q[d+2] = bf2f(u.z) * 0.125f;
        q[d+3] = bf2f(u.w) * 0.125f;
    }

    float acc[64];
#pragma unroll
    for (int d = 0; d < 64; ++d) acc[d] = 0.f;
    float l = 0.f;

    int kstart  = (qb == 0) ? 0 : (qb - 1) * BLEN;
    int nchunks = (qb == 0) ? 4 : 8;

    for (int ck = 0; ck < nchunks; ++ck) {
        int ka = kstart + ck * 64;
        __syncthreads();
        int li = tid;
#pragma unroll
        for (int it = 0; it < 4; ++it, li += 256) {
            int key = li >> 4;
            int seg = (li & 15) * 4;
            size_t goff = ((size_t)b * S_ + ka + key) * HID + h * 64 + seg;
            ushort4 ku = *(const ushort4*)(Km + goff);
            ushort4 vu = *(const ushort4*)(Vm + goff);
            Ks[key][seg+0] = bf2f(ku.x); Ks[key][seg+1] = bf2f(ku.y);
            Ks[key][seg+2] = bf2f(ku.z); Ks[key][seg+3] = bf2f(ku.w);
            Vs[key][seg+0] = bf2f(vu.x); Vs[key][seg+1] = bf2f(vu.y);
            Vs[key][seg+2] = bf2f(vu.z); Vs[key][seg+3] = bf2f(vu.w);
        }
        __syncthreads();

        int nk = sq - ka + 1;
        if (nk > 64) nk = 64;
        for (int kk = 0; kk < nk; ++kk) {
            float dot = 0.f;
#pragma unroll
            for (int d = 0; d < 64; ++d) dot += q[d] * Ks[kk][d];
            float p = expf(dot);
            l += p;
#pragma unroll
            for (int d = 0; d < 64; ++d) acc[d] += p * Vs[kk][d];
        }
    }

    float rl = 1.0f / l;
    size_t ooff = ((size_t)b * S_ + sq) * HID + h * 64;
#pragma unroll
    for (int d = 0; d < 64; d += 4) {
        ushort4 s;
        s.x = f2bf(acc[d]   * rl); s.y = f2bf(acc[d+1] * rl);
        s.z = f2bf(acc[d+2] * rl); s.w = f2bf(acc[d+3] * rl);
        *(ushort4*)(Om + ooff + d) = s;
    }
}

// ---------------------------------------------------------------------------
// x32 = LayerNorm(T16 + x32) * g + b ; optional bf16 mirror store
// ---------------------------------------------------------------------------
__global__ __launch_bounds__(256) void k_addln(const u16* __restrict__ T,
                                               float* __restrict__ X,
                                               u16* __restrict__ X16,
                                               const float* __restrict__ g,
                                               const float* __restrict__ bb) {
    __shared__ float red[8];
    int r = blockIdx.x;
    size_t off = (size_t)r * HID;
    int tid = threadIdx.x;
    float v0 = bf2f(T[off + tid])       + X[off + tid];
    float v1 = bf2f(T[off + tid + 256]) + X[off + tid + 256];
    float s  = v0 + v1;
    float sq = v0 * v0 + v1 * v1;
#pragma unroll
    for (int o = 32; o > 0; o >>= 1) {
        s  += __shfl_down(s,  o, 64);
        sq += __shfl_down(sq, o, 64);
    }
    int wid = tid >> 6;
    if ((tid & 63) == 0) { red[wid] = s; red[4 + wid] = sq; }
    __syncthreads();
    if (tid == 0) {
        red[0] = red[0] + red[1] + red[2] + red[3];
        red[4] = red[4] + red[5] + red[6] + red[7];
    }
    __syncthreads();
    float mean = red[0] * (1.0f / 512.0f);
    float var  = red[4] * (1.0f / 512.0f) - mean * mean;
    float rs   = rsqrtf(var + 1e-6f);
    float o0 = (v0 - mean) * rs * g[tid]       + bb[tid];
    float o1 = (v1 - mean) * rs * g[tid + 256] + bb[tid + 256];
    X[off + tid]       = o0;
    X[off + tid + 256] = o1;
    if (X16) {
        X16[off + tid]       = f2bf(o0);
        X16[off + tid + 256] = f2bf(o1);
    }
}

// ---------------------------------------------------------------------------
// (B,S,NPIX) fp32 logits -> (B,C,H,W,NPIX) fp32 output
// ---------------------------------------------------------------------------
__global__ __launch_bounds__(256) void k_permute(const float* __restrict__ T,
                                                 float* __restrict__ O) {
    int r = blockIdx.x;
    int p = threadIdx.x;
    int b = r / S_, s = r - b * S_;
    int h = s / (W_ * C_);
    int j = s - h * (W_ * C_);
    int w = j / C_;
    int c = j - w * C_;
    O[((((size_t)b * C_ + c) * H_ + h) * W_ + w) * NPIX + p] =
        T[(size_t)r * NPIX + p];
}

// ---------------------------------------------------------------------------
extern "C" void kernel_launch(void* const* d_in, const int* in_sizes, int n_in,
                              void* d_out, int out_size, void* d_ws, size_t ws_size,
                              hipStream_t stream) {
    const float* X    = (const float*)d_in[0];
    const float* emb  = (const float*)d_in[1];
    const float* Wq   = (const float*)d_in[2];
    const float* Wk   = (const float*)d_in[3];
    const float* Wv   = (const float*)d_in[4];
    const float* Wo   = (const float*)d_in[5];
    const float* g1   = (const float*)d_in[6];
    const float* b1l  = (const float*)d_in[7];
    const float* W1   = (const float*)d_in[8];
    const float* bb1  = (const float*)d_in[9];
    const float* W2   = (const float*)d_in[10];
    const float* bb2  = (const float*)d_in[11];
    const float* g2   = (const float*)d_in[12];
    const float* b2l  = (const float*)d_in[13];
    const float* Wout = (const float*)d_in[14];
    const float* bout = (const float*)d_in[15];
    float* out = (float*)d_out;
    (void)in_sizes; (void)n_in; (void)out_size;

    const size_t NB = (size_t)MROWS * HID;      // 12,582,912 elems
    const size_t BIG_NEED = 189005824ull;        // bytes (layout below)

    if (ws_size >= BIG_NEED) {
        // ===== BIG PATH: all-bf16 GEMMs with pre-transposed bf16 weights =====
        float* x32  = (float*)d_ws;              // 50.33 MB
        u16* x16    = (u16*)(x32 + NB);          // 25.17 MB
        u16* q16    = x16 + NB;                  // 25.17 MB
        u16* k16    = q16 + NB;                  // 25.17 MB
        u16* v16    = k16 + NB;                  // 25.17 MB
        u16* wqkvT  = v16 + NB;                  // 6*1536*512
        u16* woT    = wqkvT + (size_t)6 * 1536 * 512;
        u16* w1T    = woT   + (size_t)6 * 512 * 512;
        u16* w2T    = w1T   + (size_t)6 * 2048 * 512;
        u16* woutT  = w2T   + (size_t)6 * 512 * 2048;
        u16* h16    = q16;                       // FFN hidden chunk = q16..k16
        float* logits = (float*)q16;             // final logits = q16 span

        // one-time (per launch) weight transpose+convert
        k_trans_g<<<dim3(8, 8, 6),  256, 0, stream>>>(Wq, wqkvT,          512, 512,  262144, 786432);
        k_trans_g<<<dim3(8, 8, 6),  256, 0, stream>>>(Wk, wqkvT + 262144, 512, 512,  262144, 786432);
        k_trans_g<<<dim3(8, 8, 6),  256, 0, stream>>>(Wv, wqkvT + 524288, 512, 512,  262144, 786432);
        k_trans_g<<<dim3(8, 8, 6),  256, 0, stream>>>(Wo, woT,            512, 512,  262144, 262144);
        k_trans_g<<<dim3(32, 8, 6), 256, 0, stream>>>(W1, w1T,  2048, 512, 1048576, 1048576);
        k_trans_g<<<dim3(8, 32, 6), 256, 0, stream>>>(W2, w2T,  512, 2048, 1048576, 1048576);
        k_trans_g<<<dim3(4, 8, 1),  256, 0, stream>>>(Wout, woutT, 256, 512, 131072, 131072);

        k_embed<<<MROWS, 256, 0, stream>>>(X, emb, x32, x16);

        for (int i = 0; i < L_; ++i) {
            g_bf16<1,1,0,0><<<dim3(12, 192), 256, 0, stream>>>(
                x16, wqkvT + (size_t)i * 1536 * 512, nullptr,
                q16, k16, v16, HID, HID);

            k_attn<<<dim3(S_ / BLEN, B_ * HEADS), 256, 0, stream>>>(q16, k16, v16, q16);

            g_bf16<0,1,0,0><<<dim3(4, 192), 256, 0, stream>>>(
                q16, woT + (size_t)i * 512 * 512, nullptr,
                k16, nullptr, nullptr, HID, HID);
            k_addln<<<MROWS, 256, 0, stream>>>(k16, x32, x16,
                                               g1 + i * HID, b1l + i * HID);

            for (int c = 0; c < 2; ++c) {
                const size_t r0 = (size_t)c * (MROWS / 2);
                g_bf16<0,1,1,1><<<dim3(16, 96), 256, 0, stream>>>(
                    x16 + r0 * HID, w1T + (size_t)i * 2048 * 512,
                    bb1 + i * FILT, h16, nullptr, nullptr, FILT, HID);
                g_bf16<0,1,1,0><<<dim3(4, 96), 256, 0, stream>>>(
                    h16, w2T + (size_t)i * 512 * 2048,
                    bb2 + i * HID, v16 + r0 * HID, nullptr, nullptr, HID, FILT);
            }
            k_addln<<<MROWS, 256, 0, stream>>>(v16, x32, x16,
                                               g2 + i * HID, b2l + i * HID);
        }

        g_bf16<0,0,1,0><<<dim3(2, 192), 256, 0, stream>>>(
            x16, woutT, bout, logits, nullptr, nullptr, NPIX, HID);
        k_permute<<<MROWS, 256, 0, stream>>>(logits, out);

    } else {
        // ===== FALLBACK: round-10 proven path (125.8 MB ws) =====
        float* x32 = (float*)d_ws;
        u16*   q16 = (u16*)(x32 + NB);
        u16*   k16 = q16 + NB;
        u16*   v16 = k16 + NB;
        u16*   hid16  = q16;
        float* logits = (float*)q16;

        k_embed<<<MROWS, 256, 0, stream>>>(X, emb, x32, nullptr);

        dim3 gQKV(HID / 128, MROWS / 128);
        dim3 gW1(FILT / 128, (MROWS / 2) / 128);
        dim3 gW2(HID / 128, (MROWS / 2) / 128);
        dim3 gOut(NPIX / 128, MROWS / 128);

        for (int i = 0; i < L_; ++i) {
            const float* wq = Wq + (size_t)i * HID * HID;
            const float* wk = Wk + (size_t)i * HID * HID;
            const float* wv = Wv + (size_t)i * HID * HID;
            const float* wo = Wo + (size_t)i * HID * HID;

            g_mfma<0,1,0,0><<<gQKV, 256, 0, stream>>>(x32, wq, nullptr, q16, HID, HID);
            g_mfma<0,1,0,0><<<gQKV, 256, 0, stream>>>(x32, wk, nullptr, k16, HID, HID);
            g_mfma<0,1,0,0><<<gQKV, 256, 0, stream>>>(x32, wv, nullptr, v16, HID, HID);

            k_attn<<<dim3(S_ / BLEN, B_ * HEADS), 256, 0, stream>>>(q16, k16, v16, q16);

            g_mfma<1,1,0,0><<<gQKV, 256, 0, stream>>>(q16, wo, nullptr, k16, HID, HID);
            k_addln<<<MROWS, 256, 0, stream>>>(k16, x32, nullptr,
                                               g1 + i * HID, b1l + i * HID);

            for (int c = 0; c < 2; ++c) {
                const size_t r0 = (size_t)c * (MROWS / 2);
                g_mfma<0,1,1,1><<<gW1, 256, 0, stream>>>(
                    x32 + r0 * HID, W1 + (size_t)i * HID * FILT,
                    bb1 + i * FILT, hid16, FILT, HID);
                g_mfma<1,1,1,0><<<gW2, 256, 0, stream>>>(
                    hid16, W2 + (size_t)i * FILT * HID,
                    bb2 + i * HID, v16 + r0 * HID, HID, FILT);
            }
            k_addln<<<MROWS, 256, 0, stream>>>(v16, x32, nullptr,
                                               g2 + i * HID, b2l + i * HID);
        }

        g_mfma<0,0,1,0><<<gOut, 256, 0, stream>>>(x32, Wout, bout, logits, NPIX, HID);
        k_permute<<<MROWS, 256, 0, stream>>>(logits, out);
    }
}

// Round 12
// 2558.067 us; speedup vs baseline: 17.3580x; 2.1106x over previous
//
#include <hip/hip_runtime.h>
#include <hip/hip_bf16.h>
#include <cstdint>

#define B_    8
#define C_    3
#define H_    32
#define W_    32
#define HID   512
#define HEADS 8
#define FILT  2048
#define L_    6
#define BLEN  256
#define NPIX  256
#define S_    (H_*W_*C_)   /* 3072 */
#define MROWS (B_*S_)      /* 24576 */

typedef unsigned short u16;
typedef short bf16x8 __attribute__((ext_vector_type(8)));
typedef float f32x4  __attribute__((ext_vector_type(4)));

__device__ __forceinline__ float bf2f(u16 u) {
    union { unsigned int i; float f; } x; x.i = ((unsigned int)u) << 16; return x.f;
}
__device__ __forceinline__ u16 f2bf(float f) {
    __hip_bfloat16 h = __float2bfloat16(f);
    return *reinterpret_cast<u16*>(&h);
}

#define GLP(p) ((const __attribute__((address_space(1))) void*)(p))
#define LLP(p) ((__attribute__((address_space(3))) void*)(p))

// ---------------------------------------------------------------------------
// Embedding gather + shift + positional -> x32 (fp32) and optional x16 (bf16)
// ---------------------------------------------------------------------------
__global__ __launch_bounds__(256) void k_embed(const float* __restrict__ X,
                                               const float* __restrict__ emb,
                                               float* __restrict__ xo,
                                               u16* __restrict__ xo16) {
    int r = blockIdx.x;              // b*S + s
    int b = r / S_, s = r - b * S_;
    int h = s / (W_ * C_);
    int j = s - h * (W_ * C_);
    int tid = threadIdx.x;

    float e0 = 0.f, e1 = 0.f;
    if (s > 0) {
        int sp = s - 1;
        int hp = sp / (W_ * C_);
        int jp = sp - hp * (W_ * C_);
        int cp = jp % C_;
        int wp = jp / C_;
        float xv = X[(((size_t)b * C_ + cp) * H_ + hp) * W_ + wp];
        int iv = (int)(xv * 255.0f) + cp * NPIX;
        const float* er = emb + (size_t)iv * HID;
        e0 = er[tid]       * 22.627416997969522f;   // sqrt(512)
        e1 = er[tid + 256] * 22.627416997969522f;
    }
    float invd = expf((float)(tid & 127) * -0.07252236513366287f);
    float p0 = (tid < 128) ? sinf((float)h * invd) : cosf((float)h * invd);
    float p1 = (tid < 128) ? sinf((float)j * invd) : cosf((float)j * invd);

    float v0 = e0 + p0, v1 = e1 + p1;
    xo[(size_t)r * HID + tid]       = v0;
    xo[(size_t)r * HID + tid + 256] = v1;
    if (xo16) {
        xo16[(size_t)r * HID + tid]       = f2bf(v0);
        xo16[(size_t)r * HID + tid + 256] = f2bf(v1);
    }
}

// ---------------------------------------------------------------------------
// 64x64 tile transpose+convert: out[N][K] (bf16) = in[K][N] (fp32).
// ---------------------------------------------------------------------------
__global__ __launch_bounds__(256) void k_trans_g(const float* __restrict__ in,
                                                 u16* __restrict__ out,
                                                 int N, int K,
                                                 size_t inStride, size_t outStride) {
    __shared__ u16 T[64][72];
    in  += (size_t)blockIdx.z * inStride;
    out += (size_t)blockIdx.z * outStride;
    int n0 = blockIdx.x * 64, k0 = blockIdx.y * 64;
    int t = threadIdx.x;
    int r4 = t >> 4;            // 0..15
    int c4 = (t & 15) << 2;     // 0..60
#pragma unroll
    for (int pass = 0; pass < 4; ++pass) {
        int kr = pass * 16 + r4;
        float4 v = *(const float4*)(in + (size_t)(k0 + kr) * N + n0 + c4);
        T[c4 + 0][kr] = f2bf(v.x);
        T[c4 + 1][kr] = f2bf(v.y);
        T[c4 + 2][kr] = f2bf(v.z);
        T[c4 + 3][kr] = f2bf(v.w);
    }
    __syncthreads();
#pragma unroll
    for (int pass = 0; pass < 4; ++pass) {
        int n = pass * 16 + r4;
        ushort4 s = {T[n][c4], T[n][c4 + 1], T[n][c4 + 2], T[n][c4 + 3]};
        *(ushort4*)(out + (size_t)(n0 + n) * K + k0 + c4) = s;
    }
}

// ---------------------------------------------------------------------------
// Pure-bf16 MFMA GEMM (m97-style): C = A(M,K) @ Bt(N,K)^T  [+bias][relu]
// ---------------------------------------------------------------------------
template<int QKV, int C_BF, int BIAS, int RELU>
__global__ __launch_bounds__(256) void g_bf16(const u16* __restrict__ A,
                                              const u16* __restrict__ Bt,
                                              const float* __restrict__ bias,
                                              void* __restrict__ C0,
                                              void* __restrict__ C1,
                                              void* __restrict__ C2,
                                              int Nc, int K) {
    __shared__ __align__(16) u16 As[128 * 64];   // linear [row][64k], swizzled
    __shared__ __align__(16) u16 Bs[128 * 64];
    int tid  = threadIdx.x;
    int lane = tid & 63;
    int w    = tid >> 6;
    int row0 = blockIdx.y * 128, col0 = blockIdx.x * 128;

    int l8 = lane >> 3;                   // 0..7
    int l7 = lane & 7;                    // 0..7
    int scol = (l7 ^ l8) << 3;            // pre-swizzled source col (elems)
    const u16* aP = A  + (size_t)(row0 + w * 32 + l8) * K + scol;
    const u16* bP = Bt + (size_t)(col0 + w * 32 + l8) * K + scol;
    u16* asBase = As + w * 2048;
    u16* bsBase = Bs + w * 2048;

    int wr = (w >> 1) << 6;
    int wc = (w & 1) << 6;
    int lr = lane & 15;
    int kb = lane >> 4;

    f32x4 acc[4][4];
#pragma unroll
    for (int mi = 0; mi < 4; ++mi)
#pragma unroll
        for (int nj = 0; nj < 4; ++nj)
            acc[mi][nj] = (f32x4){0.f, 0.f, 0.f, 0.f};

    for (int k0 = 0; k0 < K; k0 += 64) {
#pragma unroll
        for (int p = 0; p < 4; ++p) {
            __builtin_amdgcn_global_load_lds(GLP(aP + (size_t)p * 8 * K),
                                             LLP(asBase + p * 512), 16, 0, 0);
            __builtin_amdgcn_global_load_lds(GLP(bP + (size_t)p * 8 * K),
                                             LLP(bsBase + p * 512), 16, 0, 0);
        }
        aP += 64; bP += 64;
        __syncthreads();

#pragma unroll
        for (int kh = 0; kh < 2; ++kh) {
            int s = ((kh << 2) + kb) ^ (lr & 7);
            bf16x8 af[4], bv[4];
#pragma unroll
            for (int mi = 0; mi < 4; ++mi)
                af[mi] = *(const bf16x8*)&As[(wr + lr) * 64 + mi * 1024 + s * 8];
#pragma unroll
            for (int nj = 0; nj < 4; ++nj)
                bv[nj] = *(const bf16x8*)&Bs[(wc + lr) * 64 + nj * 1024 + s * 8];
#pragma unroll
            for (int mi = 0; mi < 4; ++mi)
#pragma unroll
                for (int nj = 0; nj < 4; ++nj)
                    acc[mi][nj] = __builtin_amdgcn_mfma_f32_16x16x32_bf16(
                        af[mi], bv[nj], acc[mi][nj], 0, 0, 0);
        }
        __syncthreads();
    }

#pragma unroll
    for (int nj = 0; nj < 4; ++nj) {
        int colg = col0 + wc + (nj << 4) + lr;
        void* Cp; int ccol;
        if (QKV) {
            int sel = colg >> 9;
            Cp = (sel == 0) ? C0 : (sel == 1) ? C1 : C2;
            ccol = colg & 511;
        } else { Cp = C0; ccol = colg; }
        float bsv = BIAS ? bias[colg] : 0.f;
#pragma unroll
        for (int mi = 0; mi < 4; ++mi) {
#pragma unroll
            for (int reg = 0; reg < 4; ++reg) {
                int row = row0 + wr + (mi << 4) + (kb << 2) + reg;
                float v = acc[mi][nj][reg] + bsv;
                if (RELU) v = fmaxf(v, 0.f);
                if (C_BF)
                    ((u16*)Cp)[(size_t)row * Nc + ccol] = f2bf(v);
                else
                    ((float*)Cp)[(size_t)row * Nc + ccol] = v;
            }
        }
    }
}

// ---------------------------------------------------------------------------
// LEGACY fp32-staged MFMA GEMM — fallback path only.
// ---------------------------------------------------------------------------
template<int A_BF, int C_BF, int BIAS, int RELU>
__global__ __launch_bounds__(256) void g_mfma(const void* __restrict__ Ap,
                                              const float* __restrict__ Bw,
                                              const float* __restrict__ bias,
                                              void* __restrict__ Cp,
                                              int N, int K) {
    __shared__ __align__(16) u16 As[128][40];
    __shared__ __align__(16) u16 Bs[128][40];
    int tid  = threadIdx.x;
    int row0 = blockIdx.y * 128, col0 = blockIdx.x * 128;

    int ar  = tid >> 1;
    int akq = (tid & 1) << 4;
    int bkk = tid >> 5;
    int bnn = (tid & 31) << 2;

    int lane = tid & 63;
    int wv   = tid >> 6;
    int wr   = (wv >> 1) << 6;
    int wc   = (wv & 1) << 6;
    int lr   = lane & 15;
    int kb   = lane >> 4;

    f32x4 acc[4][4];
#pragma unroll
    for (int mi = 0; mi < 4; ++mi)
#pragma unroll
        for (int nj = 0; nj < 4; ++nj)
            acc[mi][nj] = (f32x4){0.f, 0.f, 0.f, 0.f};

    for (int k0 = 0; k0 < K; k0 += 32) {
        if (A_BF) {
            const u16* ap = (const u16*)Ap + (size_t)(row0 + ar) * K + k0 + akq;
#pragma unroll
            for (int p = 0; p < 4; ++p)
                *(ushort4*)&As[ar][akq + (p << 2)] = *(const ushort4*)(ap + (p << 2));
        } else {
            const float* ap = (const float*)Ap + (size_t)(row0 + ar) * K + k0 + akq;
#pragma unroll
            for (int p = 0; p < 4; ++p) {
                float4 v = *(const float4*)(ap + (p << 2));
                ushort4 wq = {f2bf(v.x), f2bf(v.y), f2bf(v.z), f2bf(v.w)};
                *(ushort4*)&As[ar][akq + (p << 2)] = wq;
            }
        }
#pragma unroll
        for (int p = 0; p < 4; ++p) {
            int kl = bkk + (p << 3);
            float4 wv4 = *(const float4*)(Bw + (size_t)(k0 + kl) * N + col0 + bnn);
            Bs[bnn + 0][kl] = f2bf(wv4.x);
            Bs[bnn + 1][kl] = f2bf(wv4.y);
            Bs[bnn + 2][kl] = f2bf(wv4.z);
            Bs[bnn + 3][kl] = f2bf(wv4.w);
        }
        __syncthreads();

        bf16x8 af[4], bfr[4];
#pragma unroll
        for (int mi = 0; mi < 4; ++mi)
            af[mi] = *(const bf16x8*)&As[wr + (mi << 4) + lr][kb << 3];
#pragma unroll
        for (int nj = 0; nj < 4; ++nj)
            bfr[nj] = *(const bf16x8*)&Bs[wc + (nj << 4) + lr][kb << 3];
#pragma unroll
        for (int mi = 0; mi < 4; ++mi)
#pragma unroll
            for (int nj = 0; nj < 4; ++nj)
                acc[mi][nj] = __builtin_amdgcn_mfma_f32_16x16x32_bf16(
                    af[mi], bfr[nj], acc[mi][nj], 0, 0, 0);
        __syncthreads();
    }

#pragma unroll
    for (int mi = 0; mi < 4; ++mi)
#pragma unroll
        for (int nj = 0; nj < 4; ++nj) {
            int col = col0 + wc + (nj << 4) + lr;
            float bsv = BIAS ? bias[col] : 0.f;
#pragma unroll
            for (int reg = 0; reg < 4; ++reg) {
                int row = row0 + wr + (mi << 4) + (kb << 2) + reg;
                float v = acc[mi][nj][reg] + bsv;
                if (RELU) v = fmaxf(v, 0.f);
                if (C_BF)
                    ((u16*)Cp)[(size_t)row * N + col] = f2bf(v);
                else
                    ((float*)Cp)[(size_t)row * N + col] = v;
            }
        }
}

// ---------------------------------------------------------------------------
// MFMA flash-style block-local causal attention (bf16).
// grid=(12, B*HEADS), 256 thr = 4 waves; wave owns 64 queries.
// S = Q.K^T via mfma_16x16x32_bf16 (no-max softmax, exact here);
// P round-trips LDS; PV via MFMA with V^T staged in LDS.
// O aliases Q safely (own rows/head only, Q consumed into regs first).
// ---------------------------------------------------------------------------
__global__ __launch_bounds__(256) void k_attn_mfma(const u16* Qm,
                                                   const u16* __restrict__ Km,
                                                   const u16* __restrict__ Vm,
                                                   u16* Om) {
    __shared__ __align__(16) u16 Kl[64][72];      // [key][d]
    __shared__ __align__(16) u16 VT[64][72];      // [d][key]
    __shared__ __align__(16) u16 Pl[4][64][72];   // per-wave [q][key]

    int qb  = blockIdx.x;            // 0..11
    int bh  = blockIdx.y;
    int b   = bh >> 3, h = bh & 7;
    int tid = threadIdx.x;
    int lane = tid & 63;
    int w    = tid >> 6;
    int lr   = lane & 15;
    int kb   = lane >> 4;            // 0..3 (k-slot AND row-group)
    int qw   = qb * BLEN + w * 64;   // wave query base

    // Q fragments: qf[mi][ks] = Q[qw+mi*16+lr][ks*32+kb*8 ..+7]
    bf16x8 qf[4][2];
#pragma unroll
    for (int mi = 0; mi < 4; ++mi)
#pragma unroll
        for (int ks = 0; ks < 2; ++ks)
            qf[mi][ks] = *(const bf16x8*)(Qm +
                ((size_t)b * S_ + qw + mi * 16 + lr) * HID + h * 64 + ks * 32 + kb * 8);

    f32x4 oacc[4][4];
    float lacc[4][4];
#pragma unroll
    for (int mi = 0; mi < 4; ++mi)
#pragma unroll
        for (int x = 0; x < 4; ++x) {
            oacc[mi][x] = (f32x4){0.f, 0.f, 0.f, 0.f};
            lacc[mi][x] = 0.f;
        }

    int kstart = (qb == 0) ? 0 : (qb - 1) * BLEN;
    int nch    = (qb == 0) ? 4 : 8;

    for (int ck = 0; ck < nch; ++ck) {
        int ka = kstart + ck * 64;
        __syncthreads();
        // stage K [key][d] and V^T [d][key]: 512 jobs of 8 dims, 2/thread
#pragma unroll
        for (int it = 0; it < 2; ++it) {
            int job = tid + it * 256;
            int key = job >> 3;
            int d8  = (job & 7) << 3;
            size_t goff = ((size_t)b * S_ + ka + key) * HID + h * 64 + d8;
            bf16x8 kv = *(const bf16x8*)(Km + goff);
            bf16x8 vv = *(const bf16x8*)(Vm + goff);
            *(bf16x8*)&Kl[key][d8] = kv;
            const u16* vu = (const u16*)&vv;
#pragma unroll
            for (int e = 0; e < 8; ++e) VT[d8 + e][key] = vu[e];
        }
        __syncthreads();

        if (ka <= qw + 63) {                      // wave has unmasked keys
            // ---- S = Q K^T ----
            f32x4 sa[4][4];
#pragma unroll
            for (int mi = 0; mi < 4; ++mi)
#pragma unroll
                for (int nj = 0; nj < 4; ++nj)
                    sa[mi][nj] = (f32x4){0.f, 0.f, 0.f, 0.f};
#pragma unroll
            for (int ks = 0; ks < 2; ++ks) {
                bf16x8 kf[4];
#pragma unroll
                for (int nj = 0; nj < 4; ++nj)
                    kf[nj] = *(const bf16x8*)&Kl[nj * 16 + lr][ks * 32 + kb * 8];
#pragma unroll
                for (int mi = 0; mi < 4; ++mi)
#pragma unroll
                    for (int nj = 0; nj < 4; ++nj)
                        sa[mi][nj] = __builtin_amdgcn_mfma_f32_16x16x32_bf16(
                            qf[mi][ks], kf[nj], sa[mi][nj], 0, 0, 0);
            }
            // ---- mask + exp + l-sum + P -> LDS ----
            bool diag = (ka + 63 > qw);
#pragma unroll
            for (int mi = 0; mi < 4; ++mi) {
#pragma unroll
                for (int reg = 0; reg < 4; ++reg) {
                    int qg = qw + mi * 16 + kb * 4 + reg;
                    float t = 0.f;
#pragma unroll
                    for (int nj = 0; nj < 4; ++nj) {
                        float s = sa[mi][nj][reg] * 0.125f;
                        float p = __expf(s);
                        if (diag && (ka + nj * 16 + lr > qg)) p = 0.f;
                        t += p;
                        Pl[w][mi * 16 + kb * 4 + reg][nj * 16 + lr] = f2bf(p);
                    }
                    t += __shfl_xor(t, 1);
                    t += __shfl_xor(t, 2);
                    t += __shfl_xor(t, 4);
                    t += __shfl_xor(t, 8);
                    lacc[mi][reg] += t;
                }
            }
            // ---- PV (P from LDS as A-frag, V^T as B-frag) ----
#pragma unroll
            for (int ks = 0; ks < 2; ++ks) {
                bf16x8 pf[4], vf[4];
#pragma unroll
                for (int mi = 0; mi < 4; ++mi)
                    pf[mi] = *(const bf16x8*)&Pl[w][mi * 16 + lr][ks * 32 + kb * 8];
#pragma unroll
                for (int dj = 0; dj < 4; ++dj)
                    vf[dj] = *(const bf16x8*)&VT[dj * 16 + lr][ks * 32 + kb * 8];
#pragma unroll
                for (int mi = 0; mi < 4; ++mi)
#pragma unroll
                    for (int dj = 0; dj < 4; ++dj)
                        oacc[mi][dj] = __builtin_amdgcn_mfma_f32_16x16x32_bf16(
                            pf[mi], vf[dj], oacc[mi][dj], 0, 0, 0);
            }
        }
    }

    // ---- epilogue: O = oacc / l ----
#pragma unroll
    for (int mi = 0; mi < 4; ++mi)
#pragma unroll
        for (int reg = 0; reg < 4; ++reg) {
            float rl = 1.0f / lacc[mi][reg];
            size_t orow = ((size_t)b * S_ + qw + mi * 16 + kb * 4 + reg) * HID + h * 64;
#pragma unroll
            for (int dj = 0; dj < 4; ++dj)
                Om[orow + dj * 16 + lr] = f2bf(oacc[mi][dj][reg] * rl);
        }
}

// ---------------------------------------------------------------------------
// LEGACY scalar attention — fallback path only.
// ---------------------------------------------------------------------------
__global__ __launch_bounds__(256) void k_attn(const u16* Qm,
                                              const u16* __restrict__ Km,
                                              const u16* __restrict__ Vm,
                                              u16* Om) {
    __shared__ float Ks[64][64];
    __shared__ float Vs[64][64];
    int qb  = blockIdx.x;
    int bh  = blockIdx.y;
    int b   = bh >> 3, h = bh & 7;
    int tid = threadIdx.x;
    int sq  = qb * BLEN + tid;

    size_t qoff = ((size_t)b * S_ + sq) * HID + h * 64;
    float q[64];
#pragma unroll
    for (int d = 0; d < 64; d += 4) {
        ushort4 u = *(const ushort4*)(Qm + qoff + d);
        q[d]   = bf2f(u.x) * 0.125f;
        q[d+1] = bf2f(u.y) * 0.125f;
        q[d+2] = bf2f(u.z) * 0.125f;
        q[d+3] = bf2f(u.w) * 0.125f;
    }

    float acc[64];
#pragma unroll
    for (int d = 0; d < 64; ++d) acc[d] = 0.f;
    float l = 0.f;

    int kstart  = (qb == 0) ? 0 : (qb - 1) * BLEN;
    int nchunks = (qb == 0) ? 4 : 8;

    for (int ck = 0; ck < nchunks; ++ck) {
        int ka = kstart + ck * 64;
        __syncthreads();
        int li = tid;
#pragma unroll
        for (int it = 0; it < 4; ++it, li += 256) {
            int key = li >> 4;
            int seg = (li & 15) * 4;
            size_t goff = ((size_t)b * S_ + ka + key) * HID + h * 64 + seg;
            ushort4 ku = *(const ushort4*)(Km + goff);
            ushort4 vu = *(const ushort4*)(Vm + goff);
            Ks[key][seg+0] = bf2f(ku.x); Ks[key][seg+1] = bf2f(ku.y);
            Ks[key][seg+2] = bf2f(ku.z); Ks[key][seg+3] = bf2f(ku.w);
            Vs[key][seg+0] = bf2f(vu.x); Vs[key][seg+1] = bf2f(vu.y);
            Vs[key][seg+2] = bf2f(vu.z); Vs[key][seg+3] = bf2f(vu.w);
        }
        __syncthreads();

        int nk = sq - ka + 1;
        if (nk > 64) nk = 64;
        for (int kk = 0; kk < nk; ++kk) {
            float dot = 0.f;
#pragma unroll
            for (int d = 0; d < 64; ++d) dot += q[d] * Ks[kk][d];
            float p = expf(dot);
            l += p;
#pragma unroll
            for (int d = 0; d < 64; ++d) acc[d] += p * Vs[kk][d];
        }
    }

    float rl = 1.0f / l;
    size_t ooff = ((size_t)b * S_ + sq) * HID + h * 64;
#pragma unroll
    for (int d = 0; d < 64; d += 4) {
        ushort4 s;
        s.x = f2bf(acc[d]   * rl); s.y = f2bf(acc[d+1] * rl);
        s.z = f2bf(acc[d+2] * rl); s.w = f2bf(acc[d+3] * rl);
        *(ushort4*)(Om + ooff + d) = s;
    }
}

// ---------------------------------------------------------------------------
// x32 = LayerNorm(T16 + x32) * g + b ; optional bf16 mirror store
// ---------------------------------------------------------------------------
__global__ __launch_bounds__(256) void k_addln(const u16* __restrict__ T,
                                               float* __restrict__ X,
                                               u16* __restrict__ X16,
                                               const float* __restrict__ g,
                                               const float* __restrict__ bb) {
    __shared__ float red[8];
    int r = blockIdx.x;
    size_t off = (size_t)r * HID;
    int tid = threadIdx.x;
    float v0 = bf2f(T[off + tid])       + X[off + tid];
    float v1 = bf2f(T[off + tid + 256]) + X[off + tid + 256];
    float s  = v0 + v1;
    float sq = v0 * v0 + v1 * v1;
#pragma unroll
    for (int o = 32; o > 0; o >>= 1) {
        s  += __shfl_down(s,  o, 64);
        sq += __shfl_down(sq, o, 64);
    }
    int wid = tid >> 6;
    if ((tid & 63) == 0) { red[wid] = s; red[4 + wid] = sq; }
    __syncthreads();
    if (tid == 0) {
        red[0] = red[0] + red[1] + red[2] + red[3];
        red[4] = red[4] + red[5] + red[6] + red[7];
    }
    __syncthreads();
    float mean = red[0] * (1.0f / 512.0f);
    float var  = red[4] * (1.0f / 512.0f) - mean * mean;
    float rs   = rsqrtf(var + 1e-6f);
    float o0 = (v0 - mean) * rs * g[tid]       + bb[tid];
    float o1 = (v1 - mean) * rs * g[tid + 256] + bb[tid + 256];
    X[off + tid]       = o0;
    X[off + tid + 256] = o1;
    if (X16) {
        X16[off + tid]       = f2bf(o0);
        X16[off + tid + 256] = f2bf(o1);
    }
}

// ---------------------------------------------------------------------------
// (B,S,NPIX) fp32 logits -> (B,C,H,W,NPIX) fp32 output
// ---------------------------------------------------------------------------
__global__ __launch_bounds__(256) void k_permute(const float* __restrict__ T,
                                                 float* __restrict__ O) {
    int r = blockIdx.x;
    int p = threadIdx.x;
    int b = r / S_, s = r - b * S_;
    int h = s / (W_ * C_);
    int j = s - h * (W_ * C_);
    int w = j / C_;
    int c = j - w * C_;
    O[((((size_t)b * C_ + c) * H_ + h) * W_ + w) * NPIX + p] =
        T[(size_t)r * NPIX + p];
}

// ---------------------------------------------------------------------------
extern "C" void kernel_launch(void* const* d_in, const int* in_sizes, int n_in,
                              void* d_out, int out_size, void* d_ws, size_t ws_size,
                              hipStream_t stream) {
    const float* X    = (const float*)d_in[0];
    const float* emb  = (const float*)d_in[1];
    const float* Wq   = (const float*)d_in[2];
    const float* Wk   = (const float*)d_in[3];
    const float* Wv   = (const float*)d_in[4];
    const float* Wo   = (const float*)d_in[5];
    const float* g1   = (const float*)d_in[6];
    const float* b1l  = (const float*)d_in[7];
    const float* W1   = (const float*)d_in[8];
    const float* bb1  = (const float*)d_in[9];
    const float* W2   = (const float*)d_in[10];
    const float* bb2  = (const float*)d_in[11];
    const float* g2   = (const float*)d_in[12];
    const float* b2l  = (const float*)d_in[13];
    const float* Wout = (const float*)d_in[14];
    const float* bout = (const float*)d_in[15];
    float* out = (float*)d_out;
    (void)in_sizes; (void)n_in; (void)out_size;

    const size_t NB = (size_t)MROWS * HID;
    const size_t BIG_NEED = 189005824ull;

    if (ws_size >= BIG_NEED) {
        // ===== BIG PATH =====
        float* x32  = (float*)d_ws;
        u16* x16    = (u16*)(x32 + NB);
        u16* q16    = x16 + NB;
        u16* k16    = q16 + NB;
        u16* v16    = k16 + NB;
        u16* wqkvT  = v16 + NB;
        u16* woT    = wqkvT + (size_t)6 * 1536 * 512;
        u16* w1T    = woT   + (size_t)6 * 512 * 512;
        u16* w2T    = w1T   + (size_t)6 * 2048 * 512;
        u16* woutT  = w2T   + (size_t)6 * 512 * 2048;
        u16* h16    = q16;
        float* logits = (float*)q16;

        k_trans_g<<<dim3(8, 8, 6),  256, 0, stream>>>(Wq, wqkvT,          512, 512,  262144, 786432);
        k_trans_g<<<dim3(8, 8, 6),  256, 0, stream>>>(Wk, wqkvT + 262144, 512, 512,  262144, 786432);
        k_trans_g<<<dim3(8, 8, 6),  256, 0, stream>>>(Wv, wqkvT + 524288, 512, 512,  262144, 786432);
        k_trans_g<<<dim3(8, 8, 6),  256, 0, stream>>>(Wo, woT,            512, 512,  262144, 262144);
        k_trans_g<<<dim3(32, 8, 6), 256, 0, stream>>>(W1, w1T,  2048, 512, 1048576, 1048576);
        k_trans_g<<<dim3(8, 32, 6), 256, 0, stream>>>(W2, w2T,  512, 2048, 1048576, 1048576);
        k_trans_g<<<dim3(4, 8, 1),  256, 0, stream>>>(Wout, woutT, 256, 512, 131072, 131072);

        k_embed<<<MROWS, 256, 0, stream>>>(X, emb, x32, x16);

        for (int i = 0; i < L_; ++i) {
            g_bf16<1,1,0,0><<<dim3(12, 192), 256, 0, stream>>>(
                x16, wqkvT + (size_t)i * 1536 * 512, nullptr,
                q16, k16, v16, HID, HID);

            k_attn_mfma<<<dim3(S_ / BLEN, B_ * HEADS), 256, 0, stream>>>(
                q16, k16, v16, q16);

            g_bf16<0,1,0,0><<<dim3(4, 192), 256, 0, stream>>>(
                q16, woT + (size_t)i * 512 * 512, nullptr,
                k16, nullptr, nullptr, HID, HID);
            k_addln<<<MROWS, 256, 0, stream>>>(k16, x32, x16,
                                               g1 + i * HID, b1l + i * HID);

            for (int c = 0; c < 2; ++c) {
                const size_t r0 = (size_t)c * (MROWS / 2);
                g_bf16<0,1,1,1><<<dim3(16, 96), 256, 0, stream>>>(
                    x16 + r0 * HID, w1T + (size_t)i * 2048 * 512,
                    bb1 + i * FILT, h16, nullptr, nullptr, FILT, HID);
                g_bf16<0,1,1,0><<<dim3(4, 96), 256, 0, stream>>>(
                    h16, w2T + (size_t)i * 512 * 2048,
                    bb2 + i * HID, v16 + r0 * HID, nullptr, nullptr, HID, FILT);
            }
            k_addln<<<MROWS, 256, 0, stream>>>(v16, x32, x16,
                                               g2 + i * HID, b2l + i * HID);
        }

        g_bf16<0,0,1,0><<<dim3(2, 192), 256, 0, stream>>>(
            x16, woutT, bout, logits, nullptr, nullptr, NPIX, HID);
        k_permute<<<MROWS, 256, 0, stream>>>(logits, out);

    } else {
        // ===== FALLBACK: round-10 proven path =====
        float* x32 = (float*)d_ws;
        u16*   q16 = (u16*)(x32 + NB);
        u16*   k16 = q16 + NB;
        u16*   v16 = k16 + NB;
        u16*   hid16  = q16;
        float* logits = (float*)q16;

        k_embed<<<MROWS, 256, 0, stream>>>(X, emb, x32, nullptr);

        dim3 gQKV(HID / 128, MROWS / 128);
        dim3 gW1(FILT / 128, (MROWS / 2) / 128);
        dim3 gW2(HID / 128, (MROWS / 2) / 128);
        dim3 gOut(NPIX / 128, MROWS / 128);

        for (int i = 0; i < L_; ++i) {
            const float* wq = Wq + (size_t)i * HID * HID;
            const float* wk = Wk + (size_t)i * HID * HID;
            const float* wv = Wv + (size_t)i * HID * HID;
            const float* wo = Wo + (size_t)i * HID * HID;

            g_mfma<0,1,0,0><<<gQKV, 256, 0, stream>>>(x32, wq, nullptr, q16, HID, HID);
            g_mfma<0,1,0,0><<<gQKV, 256, 0, stream>>>(x32, wk, nullptr, k16, HID, HID);
            g_mfma<0,1,0,0><<<gQKV, 256, 0, stream>>>(x32, wv, nullptr, v16, HID, HID);

            k_attn<<<dim3(S_ / BLEN, B_ * HEADS), 256, 0, stream>>>(q16, k16, v16, q16);

            g_mfma<1,1,0,0><<<gQKV, 256, 0, stream>>>(q16, wo, nullptr, k16, HID, HID);
            k_addln<<<MROWS, 256, 0, stream>>>(k16, x32, nullptr,
                                               g1 + i * HID, b1l + i * HID);

            for (int c = 0; c < 2; ++c) {
                const size_t r0 = (size_t)c * (MROWS / 2);
                g_mfma<0,1,1,1><<<gW1, 256, 0, stream>>>(
                    x32 + r0 * HID, W1 + (size_t)i * HID * FILT,
                    bb1 + i * FILT, hid16, FILT, HID);
                g_mfma<1,1,1,0><<<gW2, 256, 0, stream>>>(
                    hid16, W2 + (size_t)i * FILT * HID,
                    bb2 + i * HID, v16 + r0 * HID, HID, FILT);
            }
            k_addln<<<MROWS, 256, 0, stream>>>(v16, x32, nullptr,
                                               g2 + i * HID, b2l + i * HID);
        }

        g_mfma<0,0,1,0><<<gOut, 256, 0, stream>>>(x32, Wout, bout, logits, NPIX, HID);
        k_permute<<<MROWS, 256, 0, stream>>>(logits, out);
    }
}

// Round 13
// 2400.717 us; speedup vs baseline: 18.4957x; 1.0655x over previous
//
#include <hip/hip_runtime.h>
#include <hip/hip_bf16.h>
#include <cstdint>

#define B_    8
#define C_    3
#define H_    32
#define W_    32
#define HID   512
#define HEADS 8
#define FILT  2048
#define L_    6
#define BLEN  256
#define NPIX  256
#define S_    (H_*W_*C_)   /* 3072 */
#define MROWS (B_*S_)      /* 24576 */

typedef unsigned short u16;
typedef short bf16x8 __attribute__((ext_vector_type(8)));
typedef float f32x4  __attribute__((ext_vector_type(4)));

__device__ __forceinline__ float bf2f(u16 u) {
    union { unsigned int i; float f; } x; x.i = ((unsigned int)u) << 16; return x.f;
}
__device__ __forceinline__ u16 f2bf(float f) {
    __hip_bfloat16 h = __float2bfloat16(f);
    return *reinterpret_cast<u16*>(&h);
}

#define GLP(p) ((const __attribute__((address_space(1))) void*)(p))
#define LLP(p) ((__attribute__((address_space(3))) void*)(p))

// ---------------------------------------------------------------------------
// Embedding gather + shift + positional -> x32 (fp32) and optional x16 (bf16)
// ---------------------------------------------------------------------------
__global__ __launch_bounds__(256) void k_embed(const float* __restrict__ X,
                                               const float* __restrict__ emb,
                                               float* __restrict__ xo,
                                               u16* __restrict__ xo16) {
    int r = blockIdx.x;              // b*S + s
    int b = r / S_, s = r - b * S_;
    int h = s / (W_ * C_);
    int j = s - h * (W_ * C_);
    int tid = threadIdx.x;

    float e0 = 0.f, e1 = 0.f;
    if (s > 0) {
        int sp = s - 1;
        int hp = sp / (W_ * C_);
        int jp = sp - hp * (W_ * C_);
        int cp = jp % C_;
        int wp = jp / C_;
        float xv = X[(((size_t)b * C_ + cp) * H_ + hp) * W_ + wp];
        int iv = (int)(xv * 255.0f) + cp * NPIX;
        const float* er = emb + (size_t)iv * HID;
        e0 = er[tid]       * 22.627416997969522f;   // sqrt(512)
        e1 = er[tid + 256] * 22.627416997969522f;
    }
    float invd = expf((float)(tid & 127) * -0.07252236513366287f);
    float p0 = (tid < 128) ? sinf((float)h * invd) : cosf((float)h * invd);
    float p1 = (tid < 128) ? sinf((float)j * invd) : cosf((float)j * invd);

    float v0 = e0 + p0, v1 = e1 + p1;
    xo[(size_t)r * HID + tid]       = v0;
    xo[(size_t)r * HID + tid + 256] = v1;
    if (xo16) {
        xo16[(size_t)r * HID + tid]       = f2bf(v0);
        xo16[(size_t)r * HID + tid + 256] = f2bf(v1);
    }
}

// ---------------------------------------------------------------------------
// 64x64 tile transpose+convert: out[N][K] (bf16) = in[K][N] (fp32).
// ---------------------------------------------------------------------------
__global__ __launch_bounds__(256) void k_trans_g(const float* __restrict__ in,
                                                 u16* __restrict__ out,
                                                 int N, int K,
                                                 size_t inStride, size_t outStride) {
    __shared__ u16 T[64][72];
    in  += (size_t)blockIdx.z * inStride;
    out += (size_t)blockIdx.z * outStride;
    int n0 = blockIdx.x * 64, k0 = blockIdx.y * 64;
    int t = threadIdx.x;
    int r4 = t >> 4;            // 0..15
    int c4 = (t & 15) << 2;     // 0..60
#pragma unroll
    for (int pass = 0; pass < 4; ++pass) {
        int kr = pass * 16 + r4;
        float4 v = *(const float4*)(in + (size_t)(k0 + kr) * N + n0 + c4);
        T[c4 + 0][kr] = f2bf(v.x);
        T[c4 + 1][kr] = f2bf(v.y);
        T[c4 + 2][kr] = f2bf(v.z);
        T[c4 + 3][kr] = f2bf(v.w);
    }
    __syncthreads();
#pragma unroll
    for (int pass = 0; pass < 4; ++pass) {
        int n = pass * 16 + r4;
        ushort4 s = {T[n][c4], T[n][c4 + 1], T[n][c4 + 2], T[n][c4 + 3]};
        *(ushort4*)(out + (size_t)(n0 + n) * K + k0 + c4) = s;
    }
}

// ---------------------------------------------------------------------------
// Pure-bf16 MFMA GEMM (m97-style): C = A(M,K) @ Bt(N,K)^T  [+bias][relu]
// 128x128 tile, 4 waves, BK=64, global_load_lds w16, XOR-swizzled LDS.
// C_BF=1: vectorized LDS-transpose epilogue (b128 stores).
// QKV=1: cols routed to C0/C1/C2 by col>>9. PERM=1 (C_BF=0): fp32 out,
// write directly in (B,C,H,W,NPIX) permuted layout.
// ---------------------------------------------------------------------------
template<int QKV, int C_BF, int BIAS, int RELU, int PERM>
__global__ __launch_bounds__(256) void g_bf16(const u16* __restrict__ A,
                                              const u16* __restrict__ Bt,
                                              const float* __restrict__ bias,
                                              void* __restrict__ C0,
                                              void* __restrict__ C1,
                                              void* __restrict__ C2,
                                              int Nc, int K) {
    // main loop: As = smem[0..8192), Bs = smem[8192..16384)
    // epilogue (C_BF): reused as 128x136 u16 tile
    __shared__ __align__(16) u16 smem[17408];
    u16* As = smem;
    u16* Bs = smem + 8192;
    int tid  = threadIdx.x;
    int lane = tid & 63;
    int w    = tid >> 6;
    int row0 = blockIdx.y * 128, col0 = blockIdx.x * 128;

    int l8 = lane >> 3;                   // 0..7
    int l7 = lane & 7;                    // 0..7
    int scol = (l7 ^ l8) << 3;            // pre-swizzled source col (elems)
    const u16* aP = A  + (size_t)(row0 + w * 32 + l8) * K + scol;
    const u16* bP = Bt + (size_t)(col0 + w * 32 + l8) * K + scol;
    u16* asBase = As + w * 2048;
    u16* bsBase = Bs + w * 2048;

    int wr = (w >> 1) << 6;
    int wc = (w & 1) << 6;
    int lr = lane & 15;
    int kb = lane >> 4;

    f32x4 acc[4][4];
#pragma unroll
    for (int mi = 0; mi < 4; ++mi)
#pragma unroll
        for (int nj = 0; nj < 4; ++nj)
            acc[mi][nj] = (f32x4){0.f, 0.f, 0.f, 0.f};

    for (int k0 = 0; k0 < K; k0 += 64) {
#pragma unroll
        for (int p = 0; p < 4; ++p) {
            __builtin_amdgcn_global_load_lds(GLP(aP + (size_t)p * 8 * K),
                                             LLP(asBase + p * 512), 16, 0, 0);
            __builtin_amdgcn_global_load_lds(GLP(bP + (size_t)p * 8 * K),
                                             LLP(bsBase + p * 512), 16, 0, 0);
        }
        aP += 64; bP += 64;
        __syncthreads();

#pragma unroll
        for (int kh = 0; kh < 2; ++kh) {
            int sl = ((kh << 2) + kb) ^ (lr & 7);
            bf16x8 af[4], bv[4];
#pragma unroll
            for (int mi = 0; mi < 4; ++mi)
                af[mi] = *(const bf16x8*)&As[(wr + lr) * 64 + mi * 1024 + sl * 8];
#pragma unroll
            for (int nj = 0; nj < 4; ++nj)
                bv[nj] = *(const bf16x8*)&Bs[(wc + lr) * 64 + nj * 1024 + sl * 8];
            __builtin_amdgcn_s_setprio(1);
#pragma unroll
            for (int mi = 0; mi < 4; ++mi)
#pragma unroll
                for (int nj = 0; nj < 4; ++nj)
                    acc[mi][nj] = __builtin_amdgcn_mfma_f32_16x16x32_bf16(
                        af[mi], bv[nj], acc[mi][nj], 0, 0, 0);
            __builtin_amdgcn_s_setprio(0);
        }
        __syncthreads();
    }

    if (C_BF) {
        // ---- vectorized epilogue: acc -> smem (stride 136) -> b128 stores ----
        // (last loop iter ended with a barrier; safe to overwrite smem)
#pragma unroll
        for (int nj = 0; nj < 4; ++nj) {
            int colL = wc + (nj << 4) + lr;
            float bsv = BIAS ? bias[col0 + colL] : 0.f;
#pragma unroll
            for (int mi = 0; mi < 4; ++mi)
#pragma unroll
                for (int reg = 0; reg < 4; ++reg) {
                    int rowL = wr + (mi << 4) + (kb << 2) + reg;
                    float v = acc[mi][nj][reg] + bsv;
                    if (RELU) v = fmaxf(v, 0.f);
                    smem[rowL * 136 + colL] = f2bf(v);
                }
        }
        __syncthreads();
        u16* Cp; int cbase;
        if (QKV) {
            int sel = col0 >> 9;
            Cp = (u16*)(sel == 0 ? C0 : sel == 1 ? C1 : C2);
            cbase = col0 & 511;
        } else { Cp = (u16*)C0; cbase = col0; }
#pragma unroll
        for (int it = 0; it < 8; ++it) {
            int job  = tid + (it << 8);
            int rowL = job >> 4;
            int colL = (job & 15) << 3;
            bf16x8 vv = *(const bf16x8*)&smem[rowL * 136 + colL];
            *(bf16x8*)(Cp + (size_t)(row0 + rowL) * Nc + cbase + colL) = vv;
        }
    } else {
        // ---- scalar fp32 epilogue (out-proj), optional fused permute ----
#pragma unroll
        for (int nj = 0; nj < 4; ++nj) {
            int colg = col0 + wc + (nj << 4) + lr;
            float bsv = BIAS ? bias[colg] : 0.f;
#pragma unroll
            for (int mi = 0; mi < 4; ++mi)
#pragma unroll
                for (int reg = 0; reg < 4; ++reg) {
                    int row = row0 + wr + (mi << 4) + (kb << 2) + reg;
                    float v = acc[mi][nj][reg] + bsv;
                    if (RELU) v = fmaxf(v, 0.f);
                    if (PERM) {
                        int bb = row / S_;
                        int ss = row - bb * S_;
                        int hh = ss / (W_ * C_);
                        int jj = ss - hh * (W_ * C_);
                        int ww = jj / C_;
                        int cc = jj - ww * C_;
                        ((float*)C0)[((((size_t)bb * C_ + cc) * H_ + hh) * W_ + ww)
                                     * NPIX + colg] = v;
                    } else {
                        ((float*)C0)[(size_t)row * Nc + colg] = v;
                    }
                }
        }
    }
}

// ---------------------------------------------------------------------------
// LEGACY fp32-staged MFMA GEMM — fallback path only.
// ---------------------------------------------------------------------------
template<int A_BF, int C_BF, int BIAS, int RELU>
__global__ __launch_bounds__(256) void g_mfma(const void* __restrict__ Ap,
                                              const float* __restrict__ Bw,
                                              const float* __restrict__ bias,
                                              void* __restrict__ Cp,
                                              int N, int K) {
    __shared__ __align__(16) u16 As[128][40];
    __shared__ __align__(16) u16 Bs[128][40];
    int tid  = threadIdx.x;
    int row0 = blockIdx.y * 128, col0 = blockIdx.x * 128;

    int ar  = tid >> 1;
    int akq = (tid & 1) << 4;
    int bkk = tid >> 5;
    int bnn = (tid & 31) << 2;

    int lane = tid & 63;
    int wv   = tid >> 6;
    int wr   = (wv >> 1) << 6;
    int wc   = (wv & 1) << 6;
    int lr   = lane & 15;
    int kb   = lane >> 4;

    f32x4 acc[4][4];
#pragma unroll
    for (int mi = 0; mi < 4; ++mi)
#pragma unroll
        for (int nj = 0; nj < 4; ++nj)
            acc[mi][nj] = (f32x4){0.f, 0.f, 0.f, 0.f};

    for (int k0 = 0; k0 < K; k0 += 32) {
        if (A_BF) {
            const u16* ap = (const u16*)Ap + (size_t)(row0 + ar) * K + k0 + akq;
#pragma unroll
            for (int p = 0; p < 4; ++p)
                *(ushort4*)&As[ar][akq + (p << 2)] = *(const ushort4*)(ap + (p << 2));
        } else {
            const float* ap = (const float*)Ap + (size_t)(row0 + ar) * K + k0 + akq;
#pragma unroll
            for (int p = 0; p < 4; ++p) {
                float4 v = *(const float4*)(ap + (p << 2));
                ushort4 wq = {f2bf(v.x), f2bf(v.y), f2bf(v.z), f2bf(v.w)};
                *(ushort4*)&As[ar][akq + (p << 2)] = wq;
            }
        }
#pragma unroll
        for (int p = 0; p < 4; ++p) {
            int kl = bkk + (p << 3);
            float4 wv4 = *(const float4*)(Bw + (size_t)(k0 + kl) * N + col0 + bnn);
            Bs[bnn + 0][kl] = f2bf(wv4.x);
            Bs[bnn + 1][kl] = f2bf(wv4.y);
            Bs[bnn + 2][kl] = f2bf(wv4.z);
            Bs[bnn + 3][kl] = f2bf(wv4.w);
        }
        __syncthreads();

        bf16x8 af[4], bfr[4];
#pragma unroll
        for (int mi = 0; mi < 4; ++mi)
            af[mi] = *(const bf16x8*)&As[wr + (mi << 4) + lr][kb << 3];
#pragma unroll
        for (int nj = 0; nj < 4; ++nj)
            bfr[nj] = *(const bf16x8*)&Bs[wc + (nj << 4) + lr][kb << 3];
#pragma unroll
        for (int mi = 0; mi < 4; ++mi)
#pragma unroll
            for (int nj = 0; nj < 4; ++nj)
                acc[mi][nj] = __builtin_amdgcn_mfma_f32_16x16x32_bf16(
                    af[mi], bfr[nj], acc[mi][nj], 0, 0, 0);
        __syncthreads();
    }

#pragma unroll
    for (int mi = 0; mi < 4; ++mi)
#pragma unroll
        for (int nj = 0; nj < 4; ++nj) {
            int col = col0 + wc + (nj << 4) + lr;
            float bsv = BIAS ? bias[col] : 0.f;
#pragma unroll
            for (int reg = 0; reg < 4; ++reg) {
                int row = row0 + wr + (mi << 4) + (kb << 2) + reg;
                float v = acc[mi][nj][reg] + bsv;
                if (RELU) v = fmaxf(v, 0.f);
                if (C_BF)
                    ((u16*)Cp)[(size_t)row * N + col] = f2bf(v);
                else
                    ((float*)Cp)[(size_t)row * N + col] = v;
            }
        }
}

// ---------------------------------------------------------------------------
// MFMA flash-style block-local causal attention (bf16), swizzled LDS.
// grid=(12, B*HEADS), 256 thr = 4 waves; wave owns 64 queries.
// VT swizzle: col ^= ((d>>3)&7)<<3 (pad 72).  Pl: stride 64,
// col ^= ((row>>1)&7)<<3.  Both applied write+read (involution).
// ---------------------------------------------------------------------------
__global__ __launch_bounds__(256) void k_attn_mfma(const u16* Qm,
                                                   const u16* __restrict__ Km,
                                                   const u16* __restrict__ Vm,
                                                   u16* Om) {
    __shared__ __align__(16) u16 Kl[64][72];      // [key][d]
    __shared__ __align__(16) u16 VT[64][72];      // [d][key^vsw]
    __shared__ __align__(16) u16 Pl[4][64][64];   // per-wave [q][col^psw]

    int qb  = blockIdx.x;            // 0..11
    int bh  = blockIdx.y;
    int b   = bh >> 3, h = bh & 7;
    int tid = threadIdx.x;
    int lane = tid & 63;
    int w    = tid >> 6;
    int lr   = lane & 15;
    int kb   = lane >> 4;            // 0..3
    int qw   = qb * BLEN + w * 64;   // wave query base
    int vsw  = (tid & 7) << 3;       // VT write swizzle (d>>3 == tid&7)
    int prw  = ((lr >> 1) & 7) << 3; // Pl read swizzle

    bf16x8 qf[4][2];
#pragma unroll
    for (int mi = 0; mi < 4; ++mi)
#pragma unroll
        for (int ks = 0; ks < 2; ++ks)
            qf[mi][ks] = *(const bf16x8*)(Qm +
                ((size_t)b * S_ + qw + mi * 16 + lr) * HID + h * 64 + ks * 32 + kb * 8);

    f32x4 oacc[4][4];
    float lacc[4][4];
#pragma unroll
    for (int mi = 0; mi < 4; ++mi)
#pragma unroll
        for (int x = 0; x < 4; ++x) {
            oacc[mi][x] = (f32x4){0.f, 0.f, 0.f, 0.f};
            lacc[mi][x] = 0.f;
        }

    int kstart = (qb == 0) ? 0 : (qb - 1) * BLEN;
    int nch    = (qb == 0) ? 4 : 8;

    for (int ck = 0; ck < nch; ++ck) {
        int ka = kstart + ck * 64;
        __syncthreads();
#pragma unroll
        for (int it = 0; it < 2; ++it) {
            int job = tid + it * 256;
            int key = job >> 3;
            int d8  = (job & 7) << 3;
            size_t goff = ((size_t)b * S_ + ka + key) * HID + h * 64 + d8;
            bf16x8 kv = *(const bf16x8*)(Km + goff);
            bf16x8 vv = *(const bf16x8*)(Vm + goff);
            *(bf16x8*)&Kl[key][d8] = kv;
            const u16* vu = (const u16*)&vv;
            int kcol = key ^ vsw;
#pragma unroll
            for (int e = 0; e < 8; ++e) VT[d8 + e][kcol] = vu[e];
        }
        __syncthreads();

        if (ka <= qw + 63) {
            // ---- S = Q K^T ----
            f32x4 sa[4][4];
#pragma unroll
            for (int mi = 0; mi < 4; ++mi)
#pragma unroll
                for (int nj = 0; nj < 4; ++nj)
                    sa[mi][nj] = (f32x4){0.f, 0.f, 0.f, 0.f};
#pragma unroll
            for (int ks = 0; ks < 2; ++ks) {
                bf16x8 kf[4];
#pragma unroll
                for (int nj = 0; nj < 4; ++nj)
                    kf[nj] = *(const bf16x8*)&Kl[nj * 16 + lr][ks * 32 + kb * 8];
                __builtin_amdgcn_s_setprio(1);
#pragma unroll
                for (int mi = 0; mi < 4; ++mi)
#pragma unroll
                    for (int nj = 0; nj < 4; ++nj)
                        sa[mi][nj] = __builtin_amdgcn_mfma_f32_16x16x32_bf16(
                            qf[mi][ks], kf[nj], sa[mi][nj], 0, 0, 0);
                __builtin_amdgcn_s_setprio(0);
            }
            // ---- mask + exp + l-sum + P -> LDS (swizzled) ----
            bool diag = (ka + 63 > qw);
#pragma unroll
            for (int mi = 0; mi < 4; ++mi) {
#pragma unroll
                for (int reg = 0; reg < 4; ++reg) {
                    int qg  = qw + mi * 16 + kb * 4 + reg;
                    int qlc = mi * 16 + kb * 4 + reg;
                    int psw = ((kb * 2 + (reg >> 1)) & 7) << 3;
                    float t = 0.f;
#pragma unroll
                    for (int nj = 0; nj < 4; ++nj) {
                        float s = sa[mi][nj][reg] * 0.125f;
                        float p = __expf(s);
                        if (diag && (ka + nj * 16 + lr > qg)) p = 0.f;
                        t += p;
                        Pl[w][qlc][(nj * 16 + lr) ^ psw] = f2bf(p);
                    }
                    t += __shfl_xor(t, 1);
                    t += __shfl_xor(t, 2);
                    t += __shfl_xor(t, 4);
                    t += __shfl_xor(t, 8);
                    lacc[mi][reg] += t;
                }
            }
            // ---- PV ----
#pragma unroll
            for (int ks = 0; ks < 2; ++ks) {
                bf16x8 pf[4], vf[4];
#pragma unroll
                for (int mi = 0; mi < 4; ++mi)
                    pf[mi] = *(const bf16x8*)&Pl[w][mi * 16 + lr]
                                                 [(ks * 32 + kb * 8) ^ prw];
#pragma unroll
                for (int dj = 0; dj < 4; ++dj) {
                    int vr = ((dj * 2 + (lr >> 3)) & 7) << 3;
                    vf[dj] = *(const bf16x8*)&VT[dj * 16 + lr]
                                                [(ks * 32 + kb * 8) ^ vr];
                }
                __builtin_amdgcn_s_setprio(1);
#pragma unroll
                for (int mi = 0; mi < 4; ++mi)
#pragma unroll
                    for (int dj = 0; dj < 4; ++dj)
                        oacc[mi][dj] = __builtin_amdgcn_mfma_f32_16x16x32_bf16(
                            pf[mi], vf[dj], oacc[mi][dj], 0, 0, 0);
                __builtin_amdgcn_s_setprio(0);
            }
        }
    }

    // ---- epilogue: O = oacc / l ----
#pragma unroll
    for (int mi = 0; mi < 4; ++mi)
#pragma unroll
        for (int reg = 0; reg < 4; ++reg) {
            float rl = 1.0f / lacc[mi][reg];
            size_t orow = ((size_t)b * S_ + qw + mi * 16 + kb * 4 + reg) * HID + h * 64;
#pragma unroll
            for (int dj = 0; dj < 4; ++dj)
                Om[orow + dj * 16 + lr] = f2bf(oacc[mi][dj][reg] * rl);
        }
}

// ---------------------------------------------------------------------------
// LEGACY scalar attention — fallback path only.
// ---------------------------------------------------------------------------
__global__ __launch_bounds__(256) void k_attn(const u16* Qm,
                                              const u16* __restrict__ Km,
                                              const u16* __restrict__ Vm,
                                              u16* Om) {
    __shared__ float Ks[64][64];
    __shared__ float Vs[64][64];
    int qb  = blockIdx.x;
    int bh  = blockIdx.y;
    int b   = bh >> 3, h = bh & 7;
    int tid = threadIdx.x;
    int sq  = qb * BLEN + tid;

    size_t qoff = ((size_t)b * S_ + sq) * HID + h * 64;
    float q[64];
#pragma unroll
    for (int d = 0; d < 64; d += 4) {
        ushort4 u = *(const ushort4*)(Qm + qoff + d);
        q[d]   = bf2f(u.x) * 0.125f;
        q[d+1] = bf2f(u.y) * 0.125f;
        q[d+2] = bf2f(u.z) * 0.125f;
        q[d+3] = bf2f(u.w) * 0.125f;
    }

    float acc[64];
#pragma unroll
    for (int d = 0; d < 64; ++d) acc[d] = 0.f;
    float l = 0.f;

    int kstart  = (qb == 0) ? 0 : (qb - 1) * BLEN;
    int nchunks = (qb == 0) ? 4 : 8;

    for (int ck = 0; ck < nchunks; ++ck) {
        int ka = kstart + ck * 64;
        __syncthreads();
        int li = tid;
#pragma unroll
        for (int it = 0; it < 4; ++it, li += 256) {
            int key = li >> 4;
            int seg = (li & 15) * 4;
            size_t goff = ((size_t)b * S_ + ka + key) * HID + h * 64 + seg;
            ushort4 ku = *(const ushort4*)(Km + goff);
            ushort4 vu = *(const ushort4*)(Vm + goff);
            Ks[key][seg+0] = bf2f(ku.x); Ks[key][seg+1] = bf2f(ku.y);
            Ks[key][seg+2] = bf2f(ku.z); Ks[key][seg+3] = bf2f(ku.w);
            Vs[key][seg+0] = bf2f(vu.x); Vs[key][seg+1] = bf2f(vu.y);
            Vs[key][seg+2] = bf2f(vu.z); Vs[key][seg+3] = bf2f(vu.w);
        }
        __syncthreads();

        int nk = sq - ka + 1;
        if (nk > 64) nk = 64;
        for (int kk = 0; kk < nk; ++kk) {
            float dot = 0.f;
#pragma unroll
            for (int d = 0; d < 64; ++d) dot += q[d] * Ks[kk][d];
            float p = expf(dot);
            l += p;
#pragma unroll
            for (int d = 0; d < 64; ++d) acc[d] += p * Vs[kk][d];
        }
    }

    float rl = 1.0f / l;
    size_t ooff = ((size_t)b * S_ + sq) * HID + h * 64;
#pragma unroll
    for (int d = 0; d < 64; d += 4) {
        ushort4 s;
        s.x = f2bf(acc[d]   * rl); s.y = f2bf(acc[d+1] * rl);
        s.z = f2bf(acc[d+2] * rl); s.w = f2bf(acc[d+3] * rl);
        *(ushort4*)(Om + ooff + d) = s;
    }
}

// ---------------------------------------------------------------------------
// x32 = LayerNorm(T16 + x32) * g + b ; optional bf16 mirror store
// ---------------------------------------------------------------------------
__global__ __launch_bounds__(256) void k_addln(const u16* __restrict__ T,
                                               float* __restrict__ X,
                                               u16* __restrict__ X16,
                                               const float* __restrict__ g,
                                               const float* __restrict__ bb) {
    __shared__ float red[8];
    int r = blockIdx.x;
    size_t off = (size_t)r * HID;
    int tid = threadIdx.x;
    float v0 = bf2f(T[off + tid])       + X[off + tid];
    float v1 = bf2f(T[off + tid + 256]) + X[off + tid + 256];
    float s  = v0 + v1;
    float sq = v0 * v0 + v1 * v1;
#pragma unroll
    for (int o = 32; o > 0; o >>= 1) {
        s  += __shfl_down(s,  o, 64);
        sq += __shfl_down(sq, o, 64);
    }
    int wid = tid >> 6;
    if ((tid & 63) == 0) { red[wid] = s; red[4 + wid] = sq; }
    __syncthreads();
    if (tid == 0) {
        red[0] = red[0] + red[1] + red[2] + red[3];
        red[4] = red[4] + red[5] + red[6] + red[7];
    }
    __syncthreads();
    float mean = red[0] * (1.0f / 512.0f);
    float var  = red[4] * (1.0f / 512.0f) - mean * mean;
    float rs   = rsqrtf(var + 1e-6f);
    float o0 = (v0 - mean) * rs * g[tid]       + bb[tid];
    float o1 = (v1 - mean) * rs * g[tid + 256] + bb[tid + 256];
    X[off + tid]       = o0;
    X[off + tid + 256] = o1;
    if (X16) {
        X16[off + tid]       = f2bf(o0);
        X16[off + tid + 256] = f2bf(o1);
    }
}

// ---------------------------------------------------------------------------
// (B,S,NPIX) fp32 logits -> (B,C,H,W,NPIX) fp32 output (fallback only)
// ---------------------------------------------------------------------------
__global__ __launch_bounds__(256) void k_permute(const float* __restrict__ T,
                                                 float* __restrict__ O) {
    int r = blockIdx.x;
    int p = threadIdx.x;
    int b = r / S_, s = r - b * S_;
    int h = s / (W_ * C_);
    int j = s - h * (W_ * C_);
    int w = j / C_;
    int c = j - w * C_;
    O[((((size_t)b * C_ + c) * H_ + h) * W_ + w) * NPIX + p] =
        T[(size_t)r * NPIX + p];
}

// ---------------------------------------------------------------------------
extern "C" void kernel_launch(void* const* d_in, const int* in_sizes, int n_in,
                              void* d_out, int out_size, void* d_ws, size_t ws_size,
                              hipStream_t stream) {
    const float* X    = (const float*)d_in[0];
    const float* emb  = (const float*)d_in[1];
    const float* Wq   = (const float*)d_in[2];
    const float* Wk   = (const float*)d_in[3];
    const float* Wv   = (const float*)d_in[4];
    const float* Wo   = (const float*)d_in[5];
    const float* g1   = (const float*)d_in[6];
    const float* b1l  = (const float*)d_in[7];
    const float* W1   = (const float*)d_in[8];
    const float* bb1  = (const float*)d_in[9];
    const float* W2   = (const float*)d_in[10];
    const float* bb2  = (const float*)d_in[11];
    const float* g2   = (const float*)d_in[12];
    const float* b2l  = (const float*)d_in[13];
    const float* Wout = (const float*)d_in[14];
    const float* bout = (const float*)d_in[15];
    float* out = (float*)d_out;
    (void)in_sizes; (void)n_in; (void)out_size;

    const size_t NB = (size_t)MROWS * HID;
    const size_t BIG_NEED = 189005824ull;

    if (ws_size >= BIG_NEED) {
        // ===== BIG PATH =====
        float* x32  = (float*)d_ws;
        u16* x16    = (u16*)(x32 + NB);
        u16* q16    = x16 + NB;
        u16* k16    = q16 + NB;
        u16* v16    = k16 + NB;
        u16* wqkvT  = v16 + NB;
        u16* woT    = wqkvT + (size_t)6 * 1536 * 512;
        u16* w1T    = woT   + (size_t)6 * 512 * 512;
        u16* w2T    = w1T   + (size_t)6 * 2048 * 512;
        u16* woutT  = w2T   + (size_t)6 * 512 * 2048;
        u16* h16    = q16;

        k_trans_g<<<dim3(8, 8, 6),  256, 0, stream>>>(Wq, wqkvT,          512, 512,  262144, 786432);
        k_trans_g<<<dim3(8, 8, 6),  256, 0, stream>>>(Wk, wqkvT + 262144, 512, 512,  262144, 786432);
        k_trans_g<<<dim3(8, 8, 6),  256, 0, stream>>>(Wv, wqkvT + 524288, 512, 512,  262144, 786432);
        k_trans_g<<<dim3(8, 8, 6),  256, 0, stream>>>(Wo, woT,            512, 512,  262144, 262144);
        k_trans_g<<<dim3(32, 8, 6), 256, 0, stream>>>(W1, w1T,  2048, 512, 1048576, 1048576);
        k_trans_g<<<dim3(8, 32, 6), 256, 0, stream>>>(W2, w2T,  512, 2048, 1048576, 1048576);
        k_trans_g<<<dim3(4, 8, 1),  256, 0, stream>>>(Wout, woutT, 256, 512, 131072, 131072);

        k_embed<<<MROWS, 256, 0, stream>>>(X, emb, x32, x16);

        for (int i = 0; i < L_; ++i) {
            g_bf16<1,1,0,0,0><<<dim3(12, 192), 256, 0, stream>>>(
                x16, wqkvT + (size_t)i * 1536 * 512, nullptr,
                q16, k16, v16, HID, HID);

            k_attn_mfma<<<dim3(S_ / BLEN, B_ * HEADS), 256, 0, stream>>>(
                q16, k16, v16, q16);

            g_bf16<0,1,0,0,0><<<dim3(4, 192), 256, 0, stream>>>(
                q16, woT + (size_t)i * 512 * 512, nullptr,
                k16, nullptr, nullptr, HID, HID);
            k_addln<<<MROWS, 256, 0, stream>>>(k16, x32, x16,
                                               g1 + i * HID, b1l + i * HID);

            for (int c = 0; c < 2; ++c) {
                const size_t r0 = (size_t)c * (MROWS / 2);
                g_bf16<0,1,1,1,0><<<dim3(16, 96), 256, 0, stream>>>(
                    x16 + r0 * HID, w1T + (size_t)i * 2048 * 512,
                    bb1 + i * FILT, h16, nullptr, nullptr, FILT, HID);
                g_bf16<0,1,1,0,0><<<dim3(4, 96), 256, 0, stream>>>(
                    h16, w2T + (size_t)i * 512 * 2048,
                    bb2 + i * HID, v16 + r0 * HID, nullptr, nullptr, HID, FILT);
            }
            k_addln<<<MROWS, 256, 0, stream>>>(v16, x32, x16,
                                               g2 + i * HID, b2l + i * HID);
        }

        // out-proj with fused permute: writes d_out directly
        g_bf16<0,0,1,0,1><<<dim3(2, 192), 256, 0, stream>>>(
            x16, woutT, bout, out, nullptr, nullptr, NPIX, HID);

    } else {
        // ===== FALLBACK: round-10 proven path =====
        float* x32 = (float*)d_ws;
        u16*   q16 = (u16*)(x32 + NB);
        u16*   k16 = q16 + NB;
        u16*   v16 = k16 + NB;
        u16*   hid16  = q16;
        float* logits = (float*)q16;

        k_embed<<<MROWS, 256, 0, stream>>>(X, emb, x32, nullptr);

        dim3 gQKV(HID / 128, MROWS / 128);
        dim3 gW1(FILT / 128, (MROWS / 2) / 128);
        dim3 gW2(HID / 128, (MROWS / 2) / 128);
        dim3 gOut(NPIX / 128, MROWS / 128);

        for (int i = 0; i < L_; ++i) {
            const float* wq = Wq + (size_t)i * HID * HID;
            const float* wk = Wk + (size_t)i * HID * HID;
            const float* wv = Wv + (size_t)i * HID * HID;
            const float* wo = Wo + (size_t)i * HID * HID;

            g_mfma<0,1,0,0><<<gQKV, 256, 0, stream>>>(x32, wq, nullptr, q16, HID, HID);
            g_mfma<0,1,0,0><<<gQKV, 256, 0, stream>>>(x32, wk, nullptr, k16, HID, HID);
            g_mfma<0,1,0,0><<<gQKV, 256, 0, stream>>>(x32, wv, nullptr, v16, HID, HID);

            k_attn<<<dim3(S_ / BLEN, B_ * HEADS), 256, 0, stream>>>(q16, k16, v16, q16);

            g_mfma<1,1,0,0><<<gQKV, 256, 0, stream>>>(q16, wo, nullptr, k16, HID, HID);
            k_addln<<<MROWS, 256, 0, stream>>>(k16, x32, nullptr,
                                               g1 + i * HID, b1l + i * HID);

            for (int c = 0; c < 2; ++c) {
                const size_t r0 = (size_t)c * (MROWS / 2);
                g_mfma<0,1,1,1><<<gW1, 256, 0, stream>>>(
                    x32 + r0 * HID, W1 + (size_t)i * HID * FILT,
                    bb1 + i * FILT, hid16, FILT, HID);
                g_mfma<1,1,1,0><<<gW2, 256, 0, stream>>>(
                    hid16, W2 + (size_t)i * FILT * HID,
                    bb2 + i * HID, v16 + r0 * HID, HID, FILT);
            }
            k_addln<<<MROWS, 256, 0, stream>>>(v16, x32, nullptr,
                                               g2 + i * HID, b2l + i * HID);
        }

        g_mfma<0,0,1,0><<<gOut, 256, 0, stream>>>(x32, Wout, bout, logits, NPIX, HID);
        k_permute<<<MROWS, 256, 0, stream>>>(logits, out);
    }
}

// Round 14
// 2360.101 us; speedup vs baseline: 18.8140x; 1.0172x over previous
//
#include <hip/hip_runtime.h>
#include <hip/hip_bf16.h>
#include <cstdint>

#define B_    8
#define C_    3
#define H_    32
#define W_    32
#define HID   512
#define HEADS 8
#define FILT  2048
#define L_    6
#define BLEN  256
#define NPIX  256
#define S_    (H_*W_*C_)   /* 3072 */
#define MROWS (B_*S_)      /* 24576 */

typedef unsigned short u16;
typedef short bf16x8 __attribute__((ext_vector_type(8)));
typedef float f32x4  __attribute__((ext_vector_type(4)));

__device__ __forceinline__ float bf2f(u16 u) {
    union { unsigned int i; float f; } x; x.i = ((unsigned int)u) << 16; return x.f;
}
__device__ __forceinline__ u16 f2bf(float f) {
    __hip_bfloat16 h = __float2bfloat16(f);
    return *reinterpret_cast<u16*>(&h);
}

#define GLP(p) ((const __attribute__((address_space(1))) void*)(p))
#define LLP(p) ((__attribute__((address_space(3))) void*)(p))

// ---------------------------------------------------------------------------
// Embedding gather + shift + positional -> x32 (fp32) and optional x16 (bf16)
// ---------------------------------------------------------------------------
__global__ __launch_bounds__(256) void k_embed(const float* __restrict__ X,
                                               const float* __restrict__ emb,
                                               float* __restrict__ xo,
                                               u16* __restrict__ xo16) {
    int r = blockIdx.x;              // b*S + s
    int b = r / S_, s = r - b * S_;
    int h = s / (W_ * C_);
    int j = s - h * (W_ * C_);
    int tid = threadIdx.x;

    float e0 = 0.f, e1 = 0.f;
    if (s > 0) {
        int sp = s - 1;
        int hp = sp / (W_ * C_);
        int jp = sp - hp * (W_ * C_);
        int cp = jp % C_;
        int wp = jp / C_;
        float xv = X[(((size_t)b * C_ + cp) * H_ + hp) * W_ + wp];
        int iv = (int)(xv * 255.0f) + cp * NPIX;
        const float* er = emb + (size_t)iv * HID;
        e0 = er[tid]       * 22.627416997969522f;   // sqrt(512)
        e1 = er[tid + 256] * 22.627416997969522f;
    }
    float invd = expf((float)(tid & 127) * -0.07252236513366287f);
    float p0 = (tid < 128) ? sinf((float)h * invd) : cosf((float)h * invd);
    float p1 = (tid < 128) ? sinf((float)j * invd) : cosf((float)j * invd);

    float v0 = e0 + p0, v1 = e1 + p1;
    xo[(size_t)r * HID + tid]       = v0;
    xo[(size_t)r * HID + tid + 256] = v1;
    if (xo16) {
        xo16[(size_t)r * HID + tid]       = f2bf(v0);
        xo16[(size_t)r * HID + tid + 256] = f2bf(v1);
    }
}

// ---------------------------------------------------------------------------
// 64x64 tile transpose+convert: out[N][K] (bf16) = in[K][N] (fp32).
// ---------------------------------------------------------------------------
__global__ __launch_bounds__(256) void k_trans_g(const float* __restrict__ in,
                                                 u16* __restrict__ out,
                                                 int N, int K,
                                                 size_t inStride, size_t outStride) {
    __shared__ u16 T[64][72];
    in  += (size_t)blockIdx.z * inStride;
    out += (size_t)blockIdx.z * outStride;
    int n0 = blockIdx.x * 64, k0 = blockIdx.y * 64;
    int t = threadIdx.x;
    int r4 = t >> 4;            // 0..15
    int c4 = (t & 15) << 2;     // 0..60
#pragma unroll
    for (int pass = 0; pass < 4; ++pass) {
        int kr = pass * 16 + r4;
        float4 v = *(const float4*)(in + (size_t)(k0 + kr) * N + n0 + c4);
        T[c4 + 0][kr] = f2bf(v.x);
        T[c4 + 1][kr] = f2bf(v.y);
        T[c4 + 2][kr] = f2bf(v.z);
        T[c4 + 3][kr] = f2bf(v.w);
    }
    __syncthreads();
#pragma unroll
    for (int pass = 0; pass < 4; ++pass) {
        int n = pass * 16 + r4;
        ushort4 s = {T[n][c4], T[n][c4 + 1], T[n][c4 + 2], T[n][c4 + 3]};
        *(ushort4*)(out + (size_t)(n0 + n) * K + k0 + c4) = s;
    }
}

// ---------------------------------------------------------------------------
// Pure-bf16 MFMA GEMM (m97-style): C = A(M,K) @ Bt(N,K)^T  [+bias][relu]
// ---------------------------------------------------------------------------
template<int QKV, int C_BF, int BIAS, int RELU, int PERM>
__global__ __launch_bounds__(256) void g_bf16(const u16* __restrict__ A,
                                              const u16* __restrict__ Bt,
                                              const float* __restrict__ bias,
                                              void* __restrict__ C0,
                                              void* __restrict__ C1,
                                              void* __restrict__ C2,
                                              int Nc, int K) {
    __shared__ __align__(16) u16 smem[17408];
    u16* As = smem;
    u16* Bs = smem + 8192;
    int tid  = threadIdx.x;
    int lane = tid & 63;
    int w    = tid >> 6;
    int row0 = blockIdx.y * 128, col0 = blockIdx.x * 128;

    int l8 = lane >> 3;                   // 0..7
    int l7 = lane & 7;                    // 0..7
    int scol = (l7 ^ l8) << 3;            // pre-swizzled source col (elems)
    const u16* aP = A  + (size_t)(row0 + w * 32 + l8) * K + scol;
    const u16* bP = Bt + (size_t)(col0 + w * 32 + l8) * K + scol;
    u16* asBase = As + w * 2048;
    u16* bsBase = Bs + w * 2048;

    int wr = (w >> 1) << 6;
    int wc = (w & 1) << 6;
    int lr = lane & 15;
    int kb = lane >> 4;

    f32x4 acc[4][4];
#pragma unroll
    for (int mi = 0; mi < 4; ++mi)
#pragma unroll
        for (int nj = 0; nj < 4; ++nj)
            acc[mi][nj] = (f32x4){0.f, 0.f, 0.f, 0.f};

    for (int k0 = 0; k0 < K; k0 += 64) {
#pragma unroll
        for (int p = 0; p < 4; ++p) {
            __builtin_amdgcn_global_load_lds(GLP(aP + (size_t)p * 8 * K),
                                             LLP(asBase + p * 512), 16, 0, 0);
            __builtin_amdgcn_global_load_lds(GLP(bP + (size_t)p * 8 * K),
                                             LLP(bsBase + p * 512), 16, 0, 0);
        }
        aP += 64; bP += 64;
        __syncthreads();

#pragma unroll
        for (int kh = 0; kh < 2; ++kh) {
            int sl = ((kh << 2) + kb) ^ (lr & 7);
            bf16x8 af[4], bv[4];
#pragma unroll
            for (int mi = 0; mi < 4; ++mi)
                af[mi] = *(const bf16x8*)&As[(wr + lr) * 64 + mi * 1024 + sl * 8];
#pragma unroll
            for (int nj = 0; nj < 4; ++nj)
                bv[nj] = *(const bf16x8*)&Bs[(wc + lr) * 64 + nj * 1024 + sl * 8];
            __builtin_amdgcn_s_setprio(1);
#pragma unroll
            for (int mi = 0; mi < 4; ++mi)
#pragma unroll
                for (int nj = 0; nj < 4; ++nj)
                    acc[mi][nj] = __builtin_amdgcn_mfma_f32_16x16x32_bf16(
                        af[mi], bv[nj], acc[mi][nj], 0, 0, 0);
            __builtin_amdgcn_s_setprio(0);
        }
        __syncthreads();
    }

    if (C_BF) {
#pragma unroll
        for (int nj = 0; nj < 4; ++nj) {
            int colL = wc + (nj << 4) + lr;
            float bsv = BIAS ? bias[col0 + colL] : 0.f;
#pragma unroll
            for (int mi = 0; mi < 4; ++mi)
#pragma unroll
                for (int reg = 0; reg < 4; ++reg) {
                    int rowL = wr + (mi << 4) + (kb << 2) + reg;
                    float v = acc[mi][nj][reg] + bsv;
                    if (RELU) v = fmaxf(v, 0.f);
                    smem[rowL * 136 + colL] = f2bf(v);
                }
        }
        __syncthreads();
        u16* Cp; int cbase;
        if (QKV) {
            int sel = col0 >> 9;
            Cp = (u16*)(sel == 0 ? C0 : sel == 1 ? C1 : C2);
            cbase = col0 & 511;
        } else { Cp = (u16*)C0; cbase = col0; }
#pragma unroll
        for (int it = 0; it < 8; ++it) {
            int job  = tid + (it << 8);
            int rowL = job >> 4;
            int colL = (job & 15) << 3;
            bf16x8 vv = *(const bf16x8*)&smem[rowL * 136 + colL];
            *(bf16x8*)(Cp + (size_t)(row0 + rowL) * Nc + cbase + colL) = vv;
        }
    } else {
#pragma unroll
        for (int nj = 0; nj < 4; ++nj) {
            int colg = col0 + wc + (nj << 4) + lr;
            float bsv = BIAS ? bias[colg] : 0.f;
#pragma unroll
            for (int mi = 0; mi < 4; ++mi)
#pragma unroll
                for (int reg = 0; reg < 4; ++reg) {
                    int row = row0 + wr + (mi << 4) + (kb << 2) + reg;
                    float v = acc[mi][nj][reg] + bsv;
                    if (RELU) v = fmaxf(v, 0.f);
                    if (PERM) {
                        int bb = row / S_;
                        int ss = row - bb * S_;
                        int hh = ss / (W_ * C_);
                        int jj = ss - hh * (W_ * C_);
                        int ww = jj / C_;
                        int cc = jj - ww * C_;
                        ((float*)C0)[((((size_t)bb * C_ + cc) * H_ + hh) * W_ + ww)
                                     * NPIX + colg] = v;
                    } else {
                        ((float*)C0)[(size_t)row * Nc + colg] = v;
                    }
                }
        }
    }
}

// ---------------------------------------------------------------------------
// LEGACY fp32-staged MFMA GEMM — fallback path only.
// ---------------------------------------------------------------------------
template<int A_BF, int C_BF, int BIAS, int RELU>
__global__ __launch_bounds__(256) void g_mfma(const void* __restrict__ Ap,
                                              const float* __restrict__ Bw,
                                              const float* __restrict__ bias,
                                              void* __restrict__ Cp,
                                              int N, int K) {
    __shared__ __align__(16) u16 As[128][40];
    __shared__ __align__(16) u16 Bs[128][40];
    int tid  = threadIdx.x;
    int row0 = blockIdx.y * 128, col0 = blockIdx.x * 128;

    int ar  = tid >> 1;
    int akq = (tid & 1) << 4;
    int bkk = tid >> 5;
    int bnn = (tid & 31) << 2;

    int lane = tid & 63;
    int wv   = tid >> 6;
    int wr   = (wv >> 1) << 6;
    int wc   = (wv & 1) << 6;
    int lr   = lane & 15;
    int kb   = lane >> 4;

    f32x4 acc[4][4];
#pragma unroll
    for (int mi = 0; mi < 4; ++mi)
#pragma unroll
        for (int nj = 0; nj < 4; ++nj)
            acc[mi][nj] = (f32x4){0.f, 0.f, 0.f, 0.f};

    for (int k0 = 0; k0 < K; k0 += 32) {
        if (A_BF) {
            const u16* ap = (const u16*)Ap + (size_t)(row0 + ar) * K + k0 + akq;
#pragma unroll
            for (int p = 0; p < 4; ++p)
                *(ushort4*)&As[ar][akq + (p << 2)] = *(const ushort4*)(ap + (p << 2));
        } else {
            const float* ap = (const float*)Ap + (size_t)(row0 + ar) * K + k0 + akq;
#pragma unroll
            for (int p = 0; p < 4; ++p) {
                float4 v = *(const float4*)(ap + (p << 2));
                ushort4 wq = {f2bf(v.x), f2bf(v.y), f2bf(v.z), f2bf(v.w)};
                *(ushort4*)&As[ar][akq + (p << 2)] = wq;
            }
        }
#pragma unroll
        for (int p = 0; p < 4; ++p) {
            int kl = bkk + (p << 3);
            float4 wv4 = *(const float4*)(Bw + (size_t)(k0 + kl) * N + col0 + bnn);
            Bs[bnn + 0][kl] = f2bf(wv4.x);
            Bs[bnn + 1][kl] = f2bf(wv4.y);
            Bs[bnn + 2][kl] = f2bf(wv4.z);
            Bs[bnn + 3][kl] = f2bf(wv4.w);
        }
        __syncthreads();

        bf16x8 af[4], bfr[4];
#pragma unroll
        for (int mi = 0; mi < 4; ++mi)
            af[mi] = *(const bf16x8*)&As[wr + (mi << 4) + lr][kb << 3];
#pragma unroll
        for (int nj = 0; nj < 4; ++nj)
            bfr[nj] = *(const bf16x8*)&Bs[wc + (nj << 4) + lr][kb << 3];
#pragma unroll
        for (int mi = 0; mi < 4; ++mi)
#pragma unroll
            for (int nj = 0; nj < 4; ++nj)
                acc[mi][nj] = __builtin_amdgcn_mfma_f32_16x16x32_bf16(
                    af[mi], bfr[nj], acc[mi][nj], 0, 0, 0);
        __syncthreads();
    }

#pragma unroll
    for (int mi = 0; mi < 4; ++mi)
#pragma unroll
        for (int nj = 0; nj < 4; ++nj) {
            int col = col0 + wc + (nj << 4) + lr;
            float bsv = BIAS ? bias[col] : 0.f;
#pragma unroll
            for (int reg = 0; reg < 4; ++reg) {
                int row = row0 + wr + (mi << 4) + (kb << 2) + reg;
                float v = acc[mi][nj][reg] + bsv;
                if (RELU) v = fmaxf(v, 0.f);
                if (C_BF)
                    ((u16*)Cp)[(size_t)row * N + col] = f2bf(v);
                else
                    ((float*)Cp)[(size_t)row * N + col] = v;
            }
        }
}

// ---------------------------------------------------------------------------
// MFMA flash-style block-local causal attention (bf16), swizzled LDS,
// XCD-aware 1D grid (768 blocks), K/V register prefetch (async-stage split).
// Decode: f = xcd + 8*(qb + 12*grp); bh = grp*8 + xcd  ->  all 12 q-blocks
// of one (b,h) land on the same XCD (f%8 invariant) for L2 K/V locality.
// ---------------------------------------------------------------------------
__global__ __launch_bounds__(256) void k_attn_mfma(const u16* Qm,
                                                   const u16* __restrict__ Km,
                                                   const u16* __restrict__ Vm,
                                                   u16* Om) {
    __shared__ __align__(16) u16 Kl[64][72];      // [key][d]
    __shared__ __align__(16) u16 VT[64][72];      // [d][key^vsw]
    __shared__ __align__(16) u16 Pl[4][64][64];   // per-wave [q][col^psw]

    int f   = blockIdx.x;            // 0..767
    int xcd = f & 7;
    int t2  = f >> 3;
    int qb  = t2 % 12;
    int grp = t2 / 12;               // 0..7
    int bh  = (grp << 3) | xcd;
    int b   = bh >> 3, h = bh & 7;

    int tid = threadIdx.x;
    int lane = tid & 63;
    int w    = tid >> 6;
    int lr   = lane & 15;
    int kb   = lane >> 4;            // 0..3
    int qw   = qb * BLEN + w * 64;   // wave query base
    int vsw  = (tid & 7) << 3;       // VT write swizzle (d>>3 == tid&7)
    int prw  = ((lr >> 1) & 7) << 3; // Pl read swizzle

    bf16x8 qf[4][2];
#pragma unroll
    for (int mi = 0; mi < 4; ++mi)
#pragma unroll
        for (int ks = 0; ks < 2; ++ks)
            qf[mi][ks] = *(const bf16x8*)(Qm +
                ((size_t)b * S_ + qw + mi * 16 + lr) * HID + h * 64 + ks * 32 + kb * 8);

    f32x4 oacc[4][4];
    float lacc[4][4];
#pragma unroll
    for (int mi = 0; mi < 4; ++mi)
#pragma unroll
        for (int x = 0; x < 4; ++x) {
            oacc[mi][x] = (f32x4){0.f, 0.f, 0.f, 0.f};
            lacc[mi][x] = 0.f;
        }

    int kstart = (qb == 0) ? 0 : (qb - 1) * BLEN;
    int nch    = (qb == 0) ? 4 : 8;

    // staging job geometry (fixed per thread; 2 jobs of 8 dims)
    int key0 = tid >> 3;              // job0 key (tid)
    int key1 = (tid + 256) >> 3;      // job1 key
    int d8   = (tid & 7) << 3;        // same for both jobs (256 % 8 == 0)

    // ---- preload chunk 0 into registers ----
    bf16x8 kvr0, kvr1, vvr0, vvr1;
    {
        size_t g0 = ((size_t)b * S_ + kstart + key0) * HID + h * 64 + d8;
        size_t g1 = ((size_t)b * S_ + kstart + key1) * HID + h * 64 + d8;
        kvr0 = *(const bf16x8*)(Km + g0);
        vvr0 = *(const bf16x8*)(Vm + g0);
        kvr1 = *(const bf16x8*)(Km + g1);
        vvr1 = *(const bf16x8*)(Vm + g1);
    }

    for (int ck = 0; ck < nch; ++ck) {
        int ka = kstart + ck * 64;
        __syncthreads();                      // all waves done reading LDS
        // ---- regs -> LDS ----
        *(bf16x8*)&Kl[key0][d8] = kvr0;
        *(bf16x8*)&Kl[key1][d8] = kvr1;
        {
            const u16* vu0 = (const u16*)&vvr0;
            const u16* vu1 = (const u16*)&vvr1;
            int kc0 = key0 ^ vsw, kc1 = key1 ^ vsw;
#pragma unroll
            for (int e = 0; e < 8; ++e) VT[d8 + e][kc0] = vu0[e];
#pragma unroll
            for (int e = 0; e < 8; ++e) VT[d8 + e][kc1] = vu1[e];
        }
        // ---- issue next chunk's loads (hide latency under compute) ----
        if (ck + 1 < nch) {
            int kan = ka + 64;
            size_t g0 = ((size_t)b * S_ + kan + key0) * HID + h * 64 + d8;
            size_t g1 = ((size_t)b * S_ + kan + key1) * HID + h * 64 + d8;
            kvr0 = *(const bf16x8*)(Km + g0);
            vvr0 = *(const bf16x8*)(Vm + g0);
            kvr1 = *(const bf16x8*)(Km + g1);
            vvr1 = *(const bf16x8*)(Vm + g1);
        }
        __syncthreads();

        if (ka <= qw + 63) {
            // ---- S = Q K^T ----
            f32x4 sa[4][4];
#pragma unroll
            for (int mi = 0; mi < 4; ++mi)
#pragma unroll
                for (int nj = 0; nj < 4; ++nj)
                    sa[mi][nj] = (f32x4){0.f, 0.f, 0.f, 0.f};
#pragma unroll
            for (int ks = 0; ks < 2; ++ks) {
                bf16x8 kf[4];
#pragma unroll
                for (int nj = 0; nj < 4; ++nj)
                    kf[nj] = *(const bf16x8*)&Kl[nj * 16 + lr][ks * 32 + kb * 8];
                __builtin_amdgcn_s_setprio(1);
#pragma unroll
                for (int mi = 0; mi < 4; ++mi)
#pragma unroll
                    for (int nj = 0; nj < 4; ++nj)
                        sa[mi][nj] = __builtin_amdgcn_mfma_f32_16x16x32_bf16(
                            qf[mi][ks], kf[nj], sa[mi][nj], 0, 0, 0);
                __builtin_amdgcn_s_setprio(0);
            }
            // ---- mask + exp + l-sum + P -> LDS (swizzled) ----
            bool diag = (ka + 63 > qw);
#pragma unroll
            for (int mi = 0; mi < 4; ++mi) {
#pragma unroll
                for (int reg = 0; reg < 4; ++reg) {
                    int qg  = qw + mi * 16 + kb * 4 + reg;
                    int qlc = mi * 16 + kb * 4 + reg;
                    int psw = ((kb * 2 + (reg >> 1)) & 7) << 3;
                    float t = 0.f;
#pragma unroll
                    for (int nj = 0; nj < 4; ++nj) {
                        float s = sa[mi][nj][reg] * 0.125f;
                        float p = __expf(s);
                        if (diag && (ka + nj * 16 + lr > qg)) p = 0.f;
                        t += p;
                        Pl[w][qlc][(nj * 16 + lr) ^ psw] = f2bf(p);
                    }
                    t += __shfl_xor(t, 1);
                    t += __shfl_xor(t, 2);
                    t += __shfl_xor(t, 4);
                    t += __shfl_xor(t, 8);
                    lacc[mi][reg] += t;
                }
            }
            // ---- PV ----
#pragma unroll
            for (int ks = 0; ks < 2; ++ks) {
                bf16x8 pf[4], vf[4];
#pragma unroll
                for (int mi = 0; mi < 4; ++mi)
                    pf[mi] = *(const bf16x8*)&Pl[w][mi * 16 + lr]
                                                 [(ks * 32 + kb * 8) ^ prw];
#pragma unroll
                for (int dj = 0; dj < 4; ++dj) {
                    int vr = ((dj * 2 + (lr >> 3)) & 7) << 3;
                    vf[dj] = *(const bf16x8*)&VT[dj * 16 + lr]
                                                [(ks * 32 + kb * 8) ^ vr];
                }
                __builtin_amdgcn_s_setprio(1);
#pragma unroll
                for (int mi = 0; mi < 4; ++mi)
#pragma unroll
                    for (int dj = 0; dj < 4; ++dj)
                        oacc[mi][dj] = __builtin_amdgcn_mfma_f32_16x16x32_bf16(
                            pf[mi], vf[dj], oacc[mi][dj], 0, 0, 0);
                __builtin_amdgcn_s_setprio(0);
            }
        }
    }

    // ---- epilogue: O = oacc / l ----
#pragma unroll
    for (int mi = 0; mi < 4; ++mi)
#pragma unroll
        for (int reg = 0; reg < 4; ++reg) {
            float rl = 1.0f / lacc[mi][reg];
            size_t orow = ((size_t)b * S_ + qw + mi * 16 + kb * 4 + reg) * HID + h * 64;
#pragma unroll
            for (int dj = 0; dj < 4; ++dj)
                Om[orow + dj * 16 + lr] = f2bf(oacc[mi][dj][reg] * rl);
        }
}

// ---------------------------------------------------------------------------
// LEGACY scalar attention — fallback path only.
// ---------------------------------------------------------------------------
__global__ __launch_bounds__(256) void k_attn(const u16* Qm,
                                              const u16* __restrict__ Km,
                                              const u16* __restrict__ Vm,
                                              u16* Om) {
    __shared__ float Ks[64][64];
    __shared__ float Vs[64][64];
    int qb  = blockIdx.x;
    int bh  = blockIdx.y;
    int b   = bh >> 3, h = bh & 7;
    int tid = threadIdx.x;
    int sq  = qb * BLEN + tid;

    size_t qoff = ((size_t)b * S_ + sq) * HID + h * 64;
    float q[64];
#pragma unroll
    for (int d = 0; d < 64; d += 4) {
        ushort4 u = *(const ushort4*)(Qm + qoff + d);
        q[d]   = bf2f(u.x) * 0.125f;
        q[d+1] = bf2f(u.y) * 0.125f;
        q[d+2] = bf2f(u.z) * 0.125f;
        q[d+3] = bf2f(u.w) * 0.125f;
    }

    float acc[64];
#pragma unroll
    for (int d = 0; d < 64; ++d) acc[d] = 0.f;
    float l = 0.f;

    int kstart  = (qb == 0) ? 0 : (qb - 1) * BLEN;
    int nchunks = (qb == 0) ? 4 : 8;

    for (int ck = 0; ck < nchunks; ++ck) {
        int ka = kstart + ck * 64;
        __syncthreads();
        int li = tid;
#pragma unroll
        for (int it = 0; it < 4; ++it, li += 256) {
            int key = li >> 4;
            int seg = (li & 15) * 4;
            size_t goff = ((size_t)b * S_ + ka + key) * HID + h * 64 + seg;
            ushort4 ku = *(const ushort4*)(Km + goff);
            ushort4 vu = *(const ushort4*)(Vm + goff);
            Ks[key][seg+0] = bf2f(ku.x); Ks[key][seg+1] = bf2f(ku.y);
            Ks[key][seg+2] = bf2f(ku.z); Ks[key][seg+3] = bf2f(ku.w);
            Vs[key][seg+0] = bf2f(vu.x); Vs[key][seg+1] = bf2f(vu.y);
            Vs[key][seg+2] = bf2f(vu.z); Vs[key][seg+3] = bf2f(vu.w);
        }
        __syncthreads();

        int nk = sq - ka + 1;
        if (nk > 64) nk = 64;
        for (int kk = 0; kk < nk; ++kk) {
            float dot = 0.f;
#pragma unroll
            for (int d = 0; d < 64; ++d) dot += q[d] * Ks[kk][d];
            float p = expf(dot);
            l += p;
#pragma unroll
            for (int d = 0; d < 64; ++d) acc[d] += p * Vs[kk][d];
        }
    }

    float rl = 1.0f / l;
    size_t ooff = ((size_t)b * S_ + sq) * HID + h * 64;
#pragma unroll
    for (int d = 0; d < 64; d += 4) {
        ushort4 s;
        s.x = f2bf(acc[d]   * rl); s.y = f2bf(acc[d+1] * rl);
        s.z = f2bf(acc[d+2] * rl); s.w = f2bf(acc[d+3] * rl);
        *(ushort4*)(Om + ooff + d) = s;
    }
}

// ---------------------------------------------------------------------------
// x32 = LayerNorm(T16 + x32) * g + b ; optional bf16 mirror store
// ---------------------------------------------------------------------------
__global__ __launch_bounds__(256) void k_addln(const u16* __restrict__ T,
                                               float* __restrict__ X,
                                               u16* __restrict__ X16,
                                               const float* __restrict__ g,
                                               const float* __restrict__ bb) {
    __shared__ float red[8];
    int r = blockIdx.x;
    size_t off = (size_t)r * HID;
    int tid = threadIdx.x;
    float v0 = bf2f(T[off + tid])       + X[off + tid];
    float v1 = bf2f(T[off + tid + 256]) + X[off + tid + 256];
    float s  = v0 + v1;
    float sq = v0 * v0 + v1 * v1;
#pragma unroll
    for (int o = 32; o > 0; o >>= 1) {
        s  += __shfl_down(s,  o, 64);
        sq += __shfl_down(sq, o, 64);
    }
    int wid = tid >> 6;
    if ((tid & 63) == 0) { red[wid] = s; red[4 + wid] = sq; }
    __syncthreads();
    if (tid == 0) {
        red[0] = red[0] + red[1] + red[2] + red[3];
        red[4] = red[4] + red[5] + red[6] + red[7];
    }
    __syncthreads();
    float mean = red[0] * (1.0f / 512.0f);
    float var  = red[4] * (1.0f / 512.0f) - mean * mean;
    float rs   = rsqrtf(var + 1e-6f);
    float o0 = (v0 - mean) * rs * g[tid]       + bb[tid];
    float o1 = (v1 - mean) * rs * g[tid + 256] + bb[tid + 256];
    X[off + tid]       = o0;
    X[off + tid + 256] = o1;
    if (X16) {
        X16[off + tid]       = f2bf(o0);
        X16[off + tid + 256] = f2bf(o1);
    }
}

// ---------------------------------------------------------------------------
// (B,S,NPIX) fp32 logits -> (B,C,H,W,NPIX) fp32 output (fallback only)
// ---------------------------------------------------------------------------
__global__ __launch_bounds__(256) void k_permute(const float* __restrict__ T,
                                                 float* __restrict__ O) {
    int r = blockIdx.x;
    int p = threadIdx.x;
    int b = r / S_, s = r - b * S_;
    int h = s / (W_ * C_);
    int j = s - h * (W_ * C_);
    int w = j / C_;
    int c = j - w * C_;
    O[((((size_t)b * C_ + c) * H_ + h) * W_ + w) * NPIX + p] =
        T[(size_t)r * NPIX + p];
}

// ---------------------------------------------------------------------------
extern "C" void kernel_launch(void* const* d_in, const int* in_sizes, int n_in,
                              void* d_out, int out_size, void* d_ws, size_t ws_size,
                              hipStream_t stream) {
    const float* X    = (const float*)d_in[0];
    const float* emb  = (const float*)d_in[1];
    const float* Wq   = (const float*)d_in[2];
    const float* Wk   = (const float*)d_in[3];
    const float* Wv   = (const float*)d_in[4];
    const float* Wo   = (const float*)d_in[5];
    const float* g1   = (const float*)d_in[6];
    const float* b1l  = (const float*)d_in[7];
    const float* W1   = (const float*)d_in[8];
    const float* bb1  = (const float*)d_in[9];
    const float* W2   = (const float*)d_in[10];
    const float* bb2  = (const float*)d_in[11];
    const float* g2   = (const float*)d_in[12];
    const float* b2l  = (const float*)d_in[13];
    const float* Wout = (const float*)d_in[14];
    const float* bout = (const float*)d_in[15];
    float* out = (float*)d_out;
    (void)in_sizes; (void)n_in; (void)out_size;

    const size_t NB = (size_t)MROWS * HID;
    const size_t BIG_NEED = 189005824ull;

    if (ws_size >= BIG_NEED) {
        // ===== BIG PATH =====
        float* x32  = (float*)d_ws;
        u16* x16    = (u16*)(x32 + NB);
        u16* q16    = x16 + NB;
        u16* k16    = q16 + NB;
        u16* v16    = k16 + NB;
        u16* wqkvT  = v16 + NB;
        u16* woT    = wqkvT + (size_t)6 * 1536 * 512;
        u16* w1T    = woT   + (size_t)6 * 512 * 512;
        u16* w2T    = w1T   + (size_t)6 * 2048 * 512;
        u16* woutT  = w2T   + (size_t)6 * 512 * 2048;
        u16* h16    = q16;

        k_trans_g<<<dim3(8, 8, 6),  256, 0, stream>>>(Wq, wqkvT,          512, 512,  262144, 786432);
        k_trans_g<<<dim3(8, 8, 6),  256, 0, stream>>>(Wk, wqkvT + 262144, 512, 512,  262144, 786432);
        k_trans_g<<<dim3(8, 8, 6),  256, 0, stream>>>(Wv, wqkvT + 524288, 512, 512,  262144, 786432);
        k_trans_g<<<dim3(8, 8, 6),  256, 0, stream>>>(Wo, woT,            512, 512,  262144, 262144);
        k_trans_g<<<dim3(32, 8, 6), 256, 0, stream>>>(W1, w1T,  2048, 512, 1048576, 1048576);
        k_trans_g<<<dim3(8, 32, 6), 256, 0, stream>>>(W2, w2T,  512, 2048, 1048576, 1048576);
        k_trans_g<<<dim3(4, 8, 1),  256, 0, stream>>>(Wout, woutT, 256, 512, 131072, 131072);

        k_embed<<<MROWS, 256, 0, stream>>>(X, emb, x32, x16);

        for (int i = 0; i < L_; ++i) {
            g_bf16<1,1,0,0,0><<<dim3(12, 192), 256, 0, stream>>>(
                x16, wqkvT + (size_t)i * 1536 * 512, nullptr,
                q16, k16, v16, HID, HID);

            k_attn_mfma<<<768, 256, 0, stream>>>(q16, k16, v16, q16);

            g_bf16<0,1,0,0,0><<<dim3(4, 192), 256, 0, stream>>>(
                q16, woT + (size_t)i * 512 * 512, nullptr,
                k16, nullptr, nullptr, HID, HID);
            k_addln<<<MROWS, 256, 0, stream>>>(k16, x32, x16,
                                               g1 + i * HID, b1l + i * HID);

            for (int c = 0; c < 2; ++c) {
                const size_t r0 = (size_t)c * (MROWS / 2);
                g_bf16<0,1,1,1,0><<<dim3(16, 96), 256, 0, stream>>>(
                    x16 + r0 * HID, w1T + (size_t)i * 2048 * 512,
                    bb1 + i * FILT, h16, nullptr, nullptr, FILT, HID);
                g_bf16<0,1,1,0,0><<<dim3(4, 96), 256, 0, stream>>>(
                    h16, w2T + (size_t)i * 512 * 2048,
                    bb2 + i * HID, v16 + r0 * HID, nullptr, nullptr, HID, FILT);
            }
            k_addln<<<MROWS, 256, 0, stream>>>(v16, x32, x16,
                                               g2 + i * HID, b2l + i * HID);
        }

        // out-proj with fused permute: writes d_out directly
        g_bf16<0,0,1,0,1><<<dim3(2, 192), 256, 0, stream>>>(
            x16, woutT, bout, out, nullptr, nullptr, NPIX, HID);

    } else {
        // ===== FALLBACK: round-10 proven path =====
        float* x32 = (float*)d_ws;
        u16*   q16 = (u16*)(x32 + NB);
        u16*   k16 = q16 + NB;
        u16*   v16 = k16 + NB;
        u16*   hid16  = q16;
        float* logits = (float*)q16;

        k_embed<<<MROWS, 256, 0, stream>>>(X, emb, x32, nullptr);

        dim3 gQKV(HID / 128, MROWS / 128);
        dim3 gW1(FILT / 128, (MROWS / 2) / 128);
        dim3 gW2(HID / 128, (MROWS / 2) / 128);
        dim3 gOut(NPIX / 128, MROWS / 128);

        for (int i = 0; i < L_; ++i) {
            const float* wq = Wq + (size_t)i * HID * HID;
            const float* wk = Wk + (size_t)i * HID * HID;
            const float* wv = Wv + (size_t)i * HID * HID;
            const float* wo = Wo + (size_t)i * HID * HID;

            g_mfma<0,1,0,0><<<gQKV, 256, 0, stream>>>(x32, wq, nullptr, q16, HID, HID);
            g_mfma<0,1,0,0><<<gQKV, 256, 0, stream>>>(x32, wk, nullptr, k16, HID, HID);
            g_mfma<0,1,0,0><<<gQKV, 256, 0, stream>>>(x32, wv, nullptr, v16, HID, HID);

            k_attn<<<dim3(S_ / BLEN, B_ * HEADS), 256, 0, stream>>>(q16, k16, v16, q16);

            g_mfma<1,1,0,0><<<gQKV, 256, 0, stream>>>(q16, wo, nullptr, k16, HID, HID);
            k_addln<<<MROWS, 256, 0, stream>>>(k16, x32, nullptr,
                                               g1 + i * HID, b1l + i * HID);

            for (int c = 0; c < 2; ++c) {
                const size_t r0 = (size_t)c * (MROWS / 2);
                g_mfma<0,1,1,1><<<gW1, 256, 0, stream>>>(
                    x32 + r0 * HID, W1 + (size_t)i * HID * FILT,
                    bb1 + i * FILT, hid16, FILT, HID);
                g_mfma<1,1,1,0><<<gW2, 256, 0, stream>>>(
                    hid16, W2 + (size_t)i * FILT * HID,
                    bb2 + i * HID, v16 + r0 * HID, HID, FILT);
            }
            k_addln<<<MROWS, 256, 0, stream>>>(v16, x32, nullptr,
                                               g2 + i * HID, b2l + i * HID);
        }

        g_mfma<0,0,1,0><<<gOut, 256, 0, stream>>>(x32, Wout, bout, logits, NPIX, HID);
        k_permute<<<MROWS, 256, 0, stream>>>(logits, out);
    }
}

// Round 15
// 2261.292 us; speedup vs baseline: 19.6361x; 1.0437x over previous
//
#include <hip/hip_runtime.h>
#include <hip/hip_bf16.h>
#include <cstdint>

#define B_    8
#define C_    3
#define H_    32
#define W_    32
#define HID   512
#define HEADS 8
#define FILT  2048
#define L_    6
#define BLEN  256
#define NPIX  256
#define S_    (H_*W_*C_)   /* 3072 */
#define MROWS (B_*S_)      /* 24576 */

typedef unsigned short u16;
typedef short bf16x8 __attribute__((ext_vector_type(8)));
typedef float f32x4  __attribute__((ext_vector_type(4)));

__device__ __forceinline__ float bf2f(u16 u) {
    union { unsigned int i; float f; } x; x.i = ((unsigned int)u) << 16; return x.f;
}
__device__ __forceinline__ u16 f2bf(float f) {
    __hip_bfloat16 h = __float2bfloat16(f);
    return *reinterpret_cast<u16*>(&h);
}

#define GLP(p) ((const __attribute__((address_space(1))) void*)(p))
#define LLP(p) ((__attribute__((address_space(3))) void*)(p))

// ---------------------------------------------------------------------------
// Embedding gather + shift + positional -> x32 (fp32) and optional x16 (bf16)
// ---------------------------------------------------------------------------
__global__ __launch_bounds__(256) void k_embed(const float* __restrict__ X,
                                               const float* __restrict__ emb,
                                               float* __restrict__ xo,
                                               u16* __restrict__ xo16) {
    int r = blockIdx.x;              // b*S + s
    int b = r / S_, s = r - b * S_;
    int h = s / (W_ * C_);
    int j = s - h * (W_ * C_);
    int tid = threadIdx.x;

    float e0 = 0.f, e1 = 0.f;
    if (s > 0) {
        int sp = s - 1;
        int hp = sp / (W_ * C_);
        int jp = sp - hp * (W_ * C_);
        int cp = jp % C_;
        int wp = jp / C_;
        float xv = X[(((size_t)b * C_ + cp) * H_ + hp) * W_ + wp];
        int iv = (int)(xv * 255.0f) + cp * NPIX;
        const float* er = emb + (size_t)iv * HID;
        e0 = er[tid]       * 22.627416997969522f;   // sqrt(512)
        e1 = er[tid + 256] * 22.627416997969522f;
    }
    float invd = expf((float)(tid & 127) * -0.07252236513366287f);
    float p0 = (tid < 128) ? sinf((float)h * invd) : cosf((float)h * invd);
    float p1 = (tid < 128) ? sinf((float)j * invd) : cosf((float)j * invd);

    float v0 = e0 + p0, v1 = e1 + p1;
    xo[(size_t)r * HID + tid]       = v0;
    xo[(size_t)r * HID + tid + 256] = v1;
    if (xo16) {
        xo16[(size_t)r * HID + tid]       = f2bf(v0);
        xo16[(size_t)r * HID + tid + 256] = f2bf(v1);
    }
}

// ---------------------------------------------------------------------------
// 64x64 tile transpose+convert: out[N][K] (bf16) = in[K][N] (fp32).
// ---------------------------------------------------------------------------
__global__ __launch_bounds__(256) void k_trans_g(const float* __restrict__ in,
                                                 u16* __restrict__ out,
                                                 int N, int K,
                                                 size_t inStride, size_t outStride) {
    __shared__ u16 T[64][72];
    in  += (size_t)blockIdx.z * inStride;
    out += (size_t)blockIdx.z * outStride;
    int n0 = blockIdx.x * 64, k0 = blockIdx.y * 64;
    int t = threadIdx.x;
    int r4 = t >> 4;            // 0..15
    int c4 = (t & 15) << 2;     // 0..60
#pragma unroll
    for (int pass = 0; pass < 4; ++pass) {
        int kr = pass * 16 + r4;
        float4 v = *(const float4*)(in + (size_t)(k0 + kr) * N + n0 + c4);
        T[c4 + 0][kr] = f2bf(v.x);
        T[c4 + 1][kr] = f2bf(v.y);
        T[c4 + 2][kr] = f2bf(v.z);
        T[c4 + 3][kr] = f2bf(v.w);
    }
    __syncthreads();
#pragma unroll
    for (int pass = 0; pass < 4; ++pass) {
        int n = pass * 16 + r4;
        ushort4 s = {T[n][c4], T[n][c4 + 1], T[n][c4 + 2], T[n][c4 + 3]};
        *(ushort4*)(out + (size_t)(n0 + n) * K + k0 + c4) = s;
    }
}

// ---------------------------------------------------------------------------
// Pure-bf16 MFMA GEMM (m97-style): C = A(M,K) @ Bt(N,K)^T  [+bias][relu]
// ---------------------------------------------------------------------------
template<int QKV, int C_BF, int BIAS, int RELU, int PERM>
__global__ __launch_bounds__(256) void g_bf16(const u16* __restrict__ A,
                                              const u16* __restrict__ Bt,
                                              const float* __restrict__ bias,
                                              void* __restrict__ C0,
                                              void* __restrict__ C1,
                                              void* __restrict__ C2,
                                              int Nc, int K) {
    __shared__ __align__(16) u16 smem[17408];
    u16* As = smem;
    u16* Bs = smem + 8192;
    int tid  = threadIdx.x;
    int lane = tid & 63;
    int w    = tid >> 6;
    int row0 = blockIdx.y * 128, col0 = blockIdx.x * 128;

    int l8 = lane >> 3;                   // 0..7
    int l7 = lane & 7;                    // 0..7
    int scol = (l7 ^ l8) << 3;            // pre-swizzled source col (elems)
    const u16* aP = A  + (size_t)(row0 + w * 32 + l8) * K + scol;
    const u16* bP = Bt + (size_t)(col0 + w * 32 + l8) * K + scol;
    u16* asBase = As + w * 2048;
    u16* bsBase = Bs + w * 2048;

    int wr = (w >> 1) << 6;
    int wc = (w & 1) << 6;
    int lr = lane & 15;
    int kb = lane >> 4;

    f32x4 acc[4][4];
#pragma unroll
    for (int mi = 0; mi < 4; ++mi)
#pragma unroll
        for (int nj = 0; nj < 4; ++nj)
            acc[mi][nj] = (f32x4){0.f, 0.f, 0.f, 0.f};

    for (int k0 = 0; k0 < K; k0 += 64) {
#pragma unroll
        for (int p = 0; p < 4; ++p) {
            __builtin_amdgcn_global_load_lds(GLP(aP + (size_t)p * 8 * K),
                                             LLP(asBase + p * 512), 16, 0, 0);
            __builtin_amdgcn_global_load_lds(GLP(bP + (size_t)p * 8 * K),
                                             LLP(bsBase + p * 512), 16, 0, 0);
        }
        aP += 64; bP += 64;
        __syncthreads();

#pragma unroll
        for (int kh = 0; kh < 2; ++kh) {
            int sl = ((kh << 2) + kb) ^ (lr & 7);
            bf16x8 af[4], bv[4];
#pragma unroll
            for (int mi = 0; mi < 4; ++mi)
                af[mi] = *(const bf16x8*)&As[(wr + lr) * 64 + mi * 1024 + sl * 8];
#pragma unroll
            for (int nj = 0; nj < 4; ++nj)
                bv[nj] = *(const bf16x8*)&Bs[(wc + lr) * 64 + nj * 1024 + sl * 8];
            __builtin_amdgcn_s_setprio(1);
#pragma unroll
            for (int mi = 0; mi < 4; ++mi)
#pragma unroll
                for (int nj = 0; nj < 4; ++nj)
                    acc[mi][nj] = __builtin_amdgcn_mfma_f32_16x16x32_bf16(
                        af[mi], bv[nj], acc[mi][nj], 0, 0, 0);
            __builtin_amdgcn_s_setprio(0);
        }
        __syncthreads();
    }

    if (C_BF) {
#pragma unroll
        for (int nj = 0; nj < 4; ++nj) {
            int colL = wc + (nj << 4) + lr;
            float bsv = BIAS ? bias[col0 + colL] : 0.f;
#pragma unroll
            for (int mi = 0; mi < 4; ++mi)
#pragma unroll
                for (int reg = 0; reg < 4; ++reg) {
                    int rowL = wr + (mi << 4) + (kb << 2) + reg;
                    float v = acc[mi][nj][reg] + bsv;
                    if (RELU) v = fmaxf(v, 0.f);
                    smem[rowL * 136 + colL] = f2bf(v);
                }
        }
        __syncthreads();
        u16* Cp; int cbase;
        if (QKV) {
            int sel = col0 >> 9;
            Cp = (u16*)(sel == 0 ? C0 : sel == 1 ? C1 : C2);
            cbase = col0 & 511;
        } else { Cp = (u16*)C0; cbase = col0; }
#pragma unroll
        for (int it = 0; it < 8; ++it) {
            int job  = tid + (it << 8);
            int rowL = job >> 4;
            int colL = (job & 15) << 3;
            bf16x8 vv = *(const bf16x8*)&smem[rowL * 136 + colL];
            *(bf16x8*)(Cp + (size_t)(row0 + rowL) * Nc + cbase + colL) = vv;
        }
    } else {
#pragma unroll
        for (int nj = 0; nj < 4; ++nj) {
            int colg = col0 + wc + (nj << 4) + lr;
            float bsv = BIAS ? bias[colg] : 0.f;
#pragma unroll
            for (int mi = 0; mi < 4; ++mi)
#pragma unroll
                for (int reg = 0; reg < 4; ++reg) {
                    int row = row0 + wr + (mi << 4) + (kb << 2) + reg;
                    float v = acc[mi][nj][reg] + bsv;
                    if (RELU) v = fmaxf(v, 0.f);
                    if (PERM) {
                        int bb = row / S_;
                        int ss = row - bb * S_;
                        int hh = ss / (W_ * C_);
                        int jj = ss - hh * (W_ * C_);
                        int ww = jj / C_;
                        int cc = jj - ww * C_;
                        ((float*)C0)[((((size_t)bb * C_ + cc) * H_ + hh) * W_ + ww)
                                     * NPIX + colg] = v;
                    } else {
                        ((float*)C0)[(size_t)row * Nc + colg] = v;
                    }
                }
        }
    }
}

// ---------------------------------------------------------------------------
// LEGACY fp32-staged MFMA GEMM — fallback path only.
// ---------------------------------------------------------------------------
template<int A_BF, int C_BF, int BIAS, int RELU>
__global__ __launch_bounds__(256) void g_mfma(const void* __restrict__ Ap,
                                              const float* __restrict__ Bw,
                                              const float* __restrict__ bias,
                                              void* __restrict__ Cp,
                                              int N, int K) {
    __shared__ __align__(16) u16 As[128][40];
    __shared__ __align__(16) u16 Bs[128][40];
    int tid  = threadIdx.x;
    int row0 = blockIdx.y * 128, col0 = blockIdx.x * 128;

    int ar  = tid >> 1;
    int akq = (tid & 1) << 4;
    int bkk = tid >> 5;
    int bnn = (tid & 31) << 2;

    int lane = tid & 63;
    int wv   = tid >> 6;
    int wr   = (wv >> 1) << 6;
    int wc   = (wv & 1) << 6;
    int lr   = lane & 15;
    int kb   = lane >> 4;

    f32x4 acc[4][4];
#pragma unroll
    for (int mi = 0; mi < 4; ++mi)
#pragma unroll
        for (int nj = 0; nj < 4; ++nj)
            acc[mi][nj] = (f32x4){0.f, 0.f, 0.f, 0.f};

    for (int k0 = 0; k0 < K; k0 += 32) {
        if (A_BF) {
            const u16* ap = (const u16*)Ap + (size_t)(row0 + ar) * K + k0 + akq;
#pragma unroll
            for (int p = 0; p < 4; ++p)
                *(ushort4*)&As[ar][akq + (p << 2)] = *(const ushort4*)(ap + (p << 2));
        } else {
            const float* ap = (const float*)Ap + (size_t)(row0 + ar) * K + k0 + akq;
#pragma unroll
            for (int p = 0; p < 4; ++p) {
                float4 v = *(const float4*)(ap + (p << 2));
                ushort4 wq = {f2bf(v.x), f2bf(v.y), f2bf(v.z), f2bf(v.w)};
                *(ushort4*)&As[ar][akq + (p << 2)] = wq;
            }
        }
#pragma unroll
        for (int p = 0; p < 4; ++p) {
            int kl = bkk + (p << 3);
            float4 wv4 = *(const float4*)(Bw + (size_t)(k0 + kl) * N + col0 + bnn);
            Bs[bnn + 0][kl] = f2bf(wv4.x);
            Bs[bnn + 1][kl] = f2bf(wv4.y);
            Bs[bnn + 2][kl] = f2bf(wv4.z);
            Bs[bnn + 3][kl] = f2bf(wv4.w);
        }
        __syncthreads();

        bf16x8 af[4], bfr[4];
#pragma unroll
        for (int mi = 0; mi < 4; ++mi)
            af[mi] = *(const bf16x8*)&As[wr + (mi << 4) + lr][kb << 3];
#pragma unroll
        for (int nj = 0; nj < 4; ++nj)
            bfr[nj] = *(const bf16x8*)&Bs[wc + (nj << 4) + lr][kb << 3];
#pragma unroll
        for (int mi = 0; mi < 4; ++mi)
#pragma unroll
            for (int nj = 0; nj < 4; ++nj)
                acc[mi][nj] = __builtin_amdgcn_mfma_f32_16x16x32_bf16(
                    af[mi], bfr[nj], acc[mi][nj], 0, 0, 0);
        __syncthreads();
    }

#pragma unroll
    for (int mi = 0; mi < 4; ++mi)
#pragma unroll
        for (int nj = 0; nj < 4; ++nj) {
            int col = col0 + wc + (nj << 4) + lr;
            float bsv = BIAS ? bias[col] : 0.f;
#pragma unroll
            for (int reg = 0; reg < 4; ++reg) {
                int row = row0 + wr + (mi << 4) + (kb << 2) + reg;
                float v = acc[mi][nj][reg] + bsv;
                if (RELU) v = fmaxf(v, 0.f);
                if (C_BF)
                    ((u16*)Cp)[(size_t)row * N + col] = f2bf(v);
                else
                    ((float*)Cp)[(size_t)row * N + col] = v;
            }
        }
}

// ---------------------------------------------------------------------------
// MFMA flash-style block-local causal attention (bf16), SWAPPED QK^T:
// S^T = mfma(A=K, B=Q)  ->  lane holds P[key=kb*4+reg (+16nj)][q=lr (+16mi)],
// making keys in-lane contiguous: Pl writes are b64 (was 64x scalar b16),
// l-sum is in-lane + 2 shfl_xor (was 64 shfl). Pl swizzle: k ^= (q&7)<<3
// (bijective, preserves b64/b128 runs). PV unchanged: O row=q => same
// epilogue. XCD-aware 1D grid + K/V register prefetch as round 14.
// ---------------------------------------------------------------------------
__global__ __launch_bounds__(256) void k_attn_mfma(const u16* Qm,
                                                   const u16* __restrict__ Km,
                                                   const u16* __restrict__ Vm,
                                                   u16* Om) {
    __shared__ __align__(16) u16 Kl[64][72];      // [key][d]
    __shared__ __align__(16) u16 VT[64][72];      // [d][key^vsw]
    __shared__ __align__(16) u16 Pl[4][64][64];   // per-wave [q][k^((q&7)<<3)]

    int f   = blockIdx.x;            // 0..767
    int xcd = f & 7;
    int t2  = f >> 3;
    int qb  = t2 % 12;
    int grp = t2 / 12;               // 0..7
    int bh  = (grp << 3) | xcd;
    int b   = bh >> 3, h = bh & 7;

    int tid = threadIdx.x;
    int lane = tid & 63;
    int w    = tid >> 6;
    int lr   = lane & 15;
    int kb   = lane >> 4;            // 0..3
    int qw   = qb * BLEN + w * 64;   // wave query base
    int vsw  = (tid & 7) << 3;       // VT write swizzle (d>>3 == tid&7)
    int psw  = (lr & 7) << 3;        // Pl swizzle for this lane's rows (q&7)

    // Q as the B-operand: qf[mi][ks] = Q[qw+mi*16+lr][ks*32+kb*8 ..+7]
    bf16x8 qf[4][2];
#pragma unroll
    for (int mi = 0; mi < 4; ++mi)
#pragma unroll
        for (int ks = 0; ks < 2; ++ks)
            qf[mi][ks] = *(const bf16x8*)(Qm +
                ((size_t)b * S_ + qw + mi * 16 + lr) * HID + h * 64 + ks * 32 + kb * 8);

    f32x4 oacc[4][4];                 // [mi][dj]
    float lacc[4];                    // l for q = qw + mi*16 + lr
#pragma unroll
    for (int mi = 0; mi < 4; ++mi) {
        lacc[mi] = 0.f;
#pragma unroll
        for (int dj = 0; dj < 4; ++dj)
            oacc[mi][dj] = (f32x4){0.f, 0.f, 0.f, 0.f};
    }

    int kstart = (qb == 0) ? 0 : (qb - 1) * BLEN;
    int nch    = (qb == 0) ? 4 : 8;

    // staging job geometry (fixed per thread; 2 jobs of 8 dims)
    int key0 = tid >> 3;              // job0 key
    int key1 = (tid + 256) >> 3;      // job1 key
    int d8   = (tid & 7) << 3;        // same for both jobs

    // ---- preload chunk 0 into registers ----
    bf16x8 kvr0, kvr1, vvr0, vvr1;
    {
        size_t g0 = ((size_t)b * S_ + kstart + key0) * HID + h * 64 + d8;
        size_t g1 = ((size_t)b * S_ + kstart + key1) * HID + h * 64 + d8;
        kvr0 = *(const bf16x8*)(Km + g0);
        vvr0 = *(const bf16x8*)(Vm + g0);
        kvr1 = *(const bf16x8*)(Km + g1);
        vvr1 = *(const bf16x8*)(Vm + g1);
    }

    for (int ck = 0; ck < nch; ++ck) {
        int ka = kstart + ck * 64;
        __syncthreads();                      // all waves done reading LDS
        // ---- regs -> LDS ----
        *(bf16x8*)&Kl[key0][d8] = kvr0;
        *(bf16x8*)&Kl[key1][d8] = kvr1;
        {
            const u16* vu0 = (const u16*)&vvr0;
            const u16* vu1 = (const u16*)&vvr1;
            int kc0 = key0 ^ vsw, kc1 = key1 ^ vsw;
#pragma unroll
            for (int e = 0; e < 8; ++e) VT[d8 + e][kc0] = vu0[e];
#pragma unroll
            for (int e = 0; e < 8; ++e) VT[d8 + e][kc1] = vu1[e];
        }
        // ---- issue next chunk's loads (hide latency under compute) ----
        if (ck + 1 < nch) {
            int kan = ka + 64;
            size_t g0 = ((size_t)b * S_ + kan + key0) * HID + h * 64 + d8;
            size_t g1 = ((size_t)b * S_ + kan + key1) * HID + h * 64 + d8;
            kvr0 = *(const bf16x8*)(Km + g0);
            vvr0 = *(const bf16x8*)(Vm + g0);
            kvr1 = *(const bf16x8*)(Km + g1);
            vvr1 = *(const bf16x8*)(Vm + g1);
        }
        __syncthreads();

        if (ka <= qw + 63) {
            // ---- S^T = K Q^T :  sa[nj][mi], D row=key, col=q ----
            f32x4 sa[4][4];
#pragma unroll
            for (int nj = 0; nj < 4; ++nj)
#pragma unroll
                for (int mi = 0; mi < 4; ++mi)
                    sa[nj][mi] = (f32x4){0.f, 0.f, 0.f, 0.f};
#pragma unroll
            for (int ks = 0; ks < 2; ++ks) {
                bf16x8 kf[4];
#pragma unroll
                for (int nj = 0; nj < 4; ++nj)
                    kf[nj] = *(const bf16x8*)&Kl[nj * 16 + lr][ks * 32 + kb * 8];
                __builtin_amdgcn_s_setprio(1);
#pragma unroll
                for (int nj = 0; nj < 4; ++nj)
#pragma unroll
                    for (int mi = 0; mi < 4; ++mi)
                        sa[nj][mi] = __builtin_amdgcn_mfma_f32_16x16x32_bf16(
                            kf[nj], qf[mi][ks], sa[nj][mi], 0, 0, 0);
                __builtin_amdgcn_s_setprio(0);
            }
            // ---- mask + exp + in-lane l + P -> LDS (b64, swizzled) ----
            bool diag = (ka + 63 > qw);
#pragma unroll
            for (int mi = 0; mi < 4; ++mi) {
                int qg = qw + mi * 16 + lr;       // this lane's query (global)
                float tsum = 0.f;
#pragma unroll
                for (int nj = 0; nj < 4; ++nj) {
                    ushort4 pk;
                    u16* pp = (u16*)&pk;
#pragma unroll
                    for (int reg = 0; reg < 4; ++reg) {
                        float s = sa[nj][mi][reg] * 0.125f;
                        float p = __expf(s);
                        if (diag && (ka + nj * 16 + kb * 4 + reg > qg)) p = 0.f;
                        tsum += p;
                        pp[reg] = f2bf(p);
                    }
                    *(ushort4*)&Pl[w][mi * 16 + lr][(nj * 16 + kb * 4) ^ psw] = pk;
                }
                tsum += __shfl_xor(tsum, 16);
                tsum += __shfl_xor(tsum, 32);
                lacc[mi] += tsum;
            }
            // ---- PV:  O = P V,  A=P (row=q), B=V^T (row=d) ----
#pragma unroll
            for (int ks = 0; ks < 2; ++ks) {
                bf16x8 pf[4], vf[4];
#pragma unroll
                for (int mi = 0; mi < 4; ++mi)
                    pf[mi] = *(const bf16x8*)&Pl[w][mi * 16 + lr]
                                                 [(ks * 32 + kb * 8) ^ psw];
#pragma unroll
                for (int dj = 0; dj < 4; ++dj) {
                    int vr = ((dj * 2 + (lr >> 3)) & 7) << 3;
                    vf[dj] = *(const bf16x8*)&VT[dj * 16 + lr]
                                                [(ks * 32 + kb * 8) ^ vr];
                }
                __builtin_amdgcn_s_setprio(1);
#pragma unroll
                for (int mi = 0; mi < 4; ++mi)
#pragma unroll
                    for (int dj = 0; dj < 4; ++dj)
                        oacc[mi][dj] = __builtin_amdgcn_mfma_f32_16x16x32_bf16(
                            pf[mi], vf[dj], oacc[mi][dj], 0, 0, 0);
                __builtin_amdgcn_s_setprio(0);
            }
        }
    }

    // ---- epilogue: O = oacc / l.  l lives at lanes lr == q_local;
    //      redistribute to (kb,reg) rows via 4 shfls per mi. ----
#pragma unroll
    for (int mi = 0; mi < 4; ++mi) {
        float lr4[4];
#pragma unroll
        for (int reg = 0; reg < 4; ++reg)
            lr4[reg] = __shfl(lacc[mi], kb * 4 + reg);   // lane (0, kb*4+reg)
#pragma unroll
        for (int reg = 0; reg < 4; ++reg) {
            float rl = 1.0f / lr4[reg];
            size_t orow = ((size_t)b * S_ + qw + mi * 16 + kb * 4 + reg) * HID + h * 64;
#pragma unroll
            for (int dj = 0; dj < 4; ++dj)
                Om[orow + dj * 16 + lr] = f2bf(oacc[mi][dj][reg] * rl);
        }
    }
}

// ---------------------------------------------------------------------------
// LEGACY scalar attention — fallback path only.
// ---------------------------------------------------------------------------
__global__ __launch_bounds__(256) void k_attn(const u16* Qm,
                                              const u16* __restrict__ Km,
                                              const u16* __restrict__ Vm,
                                              u16* Om) {
    __shared__ float Ks[64][64];
    __shared__ float Vs[64][64];
    int qb  = blockIdx.x;
    int bh  = blockIdx.y;
    int b   = bh >> 3, h = bh & 7;
    int tid = threadIdx.x;
    int sq  = qb * BLEN + tid;

    size_t qoff = ((size_t)b * S_ + sq) * HID + h * 64;
    float q[64];
#pragma unroll
    for (int d = 0; d < 64; d += 4) {
        ushort4 u = *(const ushort4*)(Qm + qoff + d);
        q[d]   = bf2f(u.x) * 0.125f;
        q[d+1] = bf2f(u.y) * 0.125f;
        q[d+2] = bf2f(u.z) * 0.125f;
        q[d+3] = bf2f(u.w) * 0.125f;
    }

    float acc[64];
#pragma unroll
    for (int d = 0; d < 64; ++d) acc[d] = 0.f;
    float l = 0.f;

    int kstart  = (qb == 0) ? 0 : (qb - 1) * BLEN;
    int nchunks = (qb == 0) ? 4 : 8;

    for (int ck = 0; ck < nchunks; ++ck) {
        int ka = kstart + ck * 64;
        __syncthreads();
        int li = tid;
#pragma unroll
        for (int it = 0; it < 4; ++it, li += 256) {
            int key = li >> 4;
            int seg = (li & 15) * 4;
            size_t goff = ((size_t)b * S_ + ka + key) * HID + h * 64 + seg;
            ushort4 ku = *(const ushort4*)(Km + goff);
            ushort4 vu = *(const ushort4*)(Vm + goff);
            Ks[key][seg+0] = bf2f(ku.x); Ks[key][seg+1] = bf2f(ku.y);
            Ks[key][seg+2] = bf2f(ku.z); Ks[key][seg+3] = bf2f(ku.w);
            Vs[key][seg+0] = bf2f(vu.x); Vs[key][seg+1] = bf2f(vu.y);
            Vs[key][seg+2] = bf2f(vu.z); Vs[key][seg+3] = bf2f(vu.w);
        }
        __syncthreads();

        int nk = sq - ka + 1;
        if (nk > 64) nk = 64;
        for (int kk = 0; kk < nk; ++kk) {
            float dot = 0.f;
#pragma unroll
            for (int d = 0; d < 64; ++d) dot += q[d] * Ks[kk][d];
            float p = expf(dot);
            l += p;
#pragma unroll
            for (int d = 0; d < 64; ++d) acc[d] += p * Vs[kk][d];
        }
    }

    float rl = 1.0f / l;
    size_t ooff = ((size_t)b * S_ + sq) * HID + h * 64;
#pragma unroll
    for (int d = 0; d < 64; d += 4) {
        ushort4 s;
        s.x = f2bf(acc[d]   * rl); s.y = f2bf(acc[d+1] * rl);
        s.z = f2bf(acc[d+2] * rl); s.w = f2bf(acc[d+3] * rl);
        *(ushort4*)(Om + ooff + d) = s;
    }
}

// ---------------------------------------------------------------------------
// x32 = LayerNorm(T16 + x32) * g + b ; optional bf16 mirror store
// ---------------------------------------------------------------------------
__global__ __launch_bounds__(256) void k_addln(const u16* __restrict__ T,
                                               float* __restrict__ X,
                                               u16* __restrict__ X16,
                                               const float* __restrict__ g,
                                               const float* __restrict__ bb) {
    __shared__ float red[8];
    int r = blockIdx.x;
    size_t off = (size_t)r * HID;
    int tid = threadIdx.x;
    float v0 = bf2f(T[off + tid])       + X[off + tid];
    float v1 = bf2f(T[off + tid + 256]) + X[off + tid + 256];
    float s  = v0 + v1;
    float sq = v0 * v0 + v1 * v1;
#pragma unroll
    for (int o = 32; o > 0; o >>= 1) {
        s  += __shfl_down(s,  o, 64);
        sq += __shfl_down(sq, o, 64);
    }
    int wid = tid >> 6;
    if ((tid & 63) == 0) { red[wid] = s; red[4 + wid] = sq; }
    __syncthreads();
    if (tid == 0) {
        red[0] = red[0] + red[1] + red[2] + red[3];
        red[4] = red[4] + red[5] + red[6] + red[7];
    }
    __syncthreads();
    float mean = red[0] * (1.0f / 512.0f);
    float var  = red[4] * (1.0f / 512.0f) - mean * mean;
    float rs   = rsqrtf(var + 1e-6f);
    float o0 = (v0 - mean) * rs * g[tid]       + bb[tid];
    float o1 = (v1 - mean) * rs * g[tid + 256] + bb[tid + 256];
    X[off + tid]       = o0;
    X[off + tid + 256] = o1;
    if (X16) {
        X16[off + tid]       = f2bf(o0);
        X16[off + tid + 256] = f2bf(o1);
    }
}

// ---------------------------------------------------------------------------
// (B,S,NPIX) fp32 logits -> (B,C,H,W,NPIX) fp32 output (fallback only)
// ---------------------------------------------------------------------------
__global__ __launch_bounds__(256) void k_permute(const float* __restrict__ T,
                                                 float* __restrict__ O) {
    int r = blockIdx.x;
    int p = threadIdx.x;
    int b = r / S_, s = r - b * S_;
    int h = s / (W_ * C_);
    int j = s - h * (W_ * C_);
    int w = j / C_;
    int c = j - w * C_;
    O[((((size_t)b * C_ + c) * H_ + h) * W_ + w) * NPIX + p] =
        T[(size_t)r * NPIX + p];
}

// ---------------------------------------------------------------------------
extern "C" void kernel_launch(void* const* d_in, const int* in_sizes, int n_in,
                              void* d_out, int out_size, void* d_ws, size_t ws_size,
                              hipStream_t stream) {
    const float* X    = (const float*)d_in[0];
    const float* emb  = (const float*)d_in[1];
    const float* Wq   = (const float*)d_in[2];
    const float* Wk   = (const float*)d_in[3];
    const float* Wv   = (const float*)d_in[4];
    const float* Wo   = (const float*)d_in[5];
    const float* g1   = (const float*)d_in[6];
    const float* b1l  = (const float*)d_in[7];
    const float* W1   = (const float*)d_in[8];
    const float* bb1  = (const float*)d_in[9];
    const float* W2   = (const float*)d_in[10];
    const float* bb2  = (const float*)d_in[11];
    const float* g2   = (const float*)d_in[12];
    const float* b2l  = (const float*)d_in[13];
    const float* Wout = (const float*)d_in[14];
    const float* bout = (const float*)d_in[15];
    float* out = (float*)d_out;
    (void)in_sizes; (void)n_in; (void)out_size;

    const size_t NB = (size_t)MROWS * HID;
    const size_t BIG_NEED = 189005824ull;

    if (ws_size >= BIG_NEED) {
        // ===== BIG PATH =====
        float* x32  = (float*)d_ws;
        u16* x16    = (u16*)(x32 + NB);
        u16* q16    = x16 + NB;
        u16* k16    = q16 + NB;
        u16* v16    = k16 + NB;
        u16* wqkvT  = v16 + NB;
        u16* woT    = wqkvT + (size_t)6 * 1536 * 512;
        u16* w1T    = woT   + (size_t)6 * 512 * 512;
        u16* w2T    = w1T   + (size_t)6 * 2048 * 512;
        u16* woutT  = w2T   + (size_t)6 * 512 * 2048;
        u16* h16    = q16;

        k_trans_g<<<dim3(8, 8, 6),  256, 0, stream>>>(Wq, wqkvT,          512, 512,  262144, 786432);
        k_trans_g<<<dim3(8, 8, 6),  256, 0, stream>>>(Wk, wqkvT + 262144, 512, 512,  262144, 786432);
        k_trans_g<<<dim3(8, 8, 6),  256, 0, stream>>>(Wv, wqkvT + 524288, 512, 512,  262144, 786432);
        k_trans_g<<<dim3(8, 8, 6),  256, 0, stream>>>(Wo, woT,            512, 512,  262144, 262144);
        k_trans_g<<<dim3(32, 8, 6), 256, 0, stream>>>(W1, w1T,  2048, 512, 1048576, 1048576);
        k_trans_g<<<dim3(8, 32, 6), 256, 0, stream>>>(W2, w2T,  512, 2048, 1048576, 1048576);
        k_trans_g<<<dim3(4, 8, 1),  256, 0, stream>>>(Wout, woutT, 256, 512, 131072, 131072);

        k_embed<<<MROWS, 256, 0, stream>>>(X, emb, x32, x16);

        for (int i = 0; i < L_; ++i) {
            g_bf16<1,1,0,0,0><<<dim3(12, 192), 256, 0, stream>>>(
                x16, wqkvT + (size_t)i * 1536 * 512, nullptr,
                q16, k16, v16, HID, HID);

            k_attn_mfma<<<768, 256, 0, stream>>>(q16, k16, v16, q16);

            g_bf16<0,1,0,0,0><<<dim3(4, 192), 256, 0, stream>>>(
                q16, woT + (size_t)i * 512 * 512, nullptr,
                k16, nullptr, nullptr, HID, HID);
            k_addln<<<MROWS, 256, 0, stream>>>(k16, x32, x16,
                                               g1 + i * HID, b1l + i * HID);

            for (int c = 0; c < 2; ++c) {
                const size_t r0 = (size_t)c * (MROWS / 2);
                g_bf16<0,1,1,1,0><<<dim3(16, 96), 256, 0, stream>>>(
                    x16 + r0 * HID, w1T + (size_t)i * 2048 * 512,
                    bb1 + i * FILT, h16, nullptr, nullptr, FILT, HID);
                g_bf16<0,1,1,0,0><<<dim3(4, 96), 256, 0, stream>>>(
                    h16, w2T + (size_t)i * 512 * 2048,
                    bb2 + i * HID, v16 + r0 * HID, nullptr, nullptr, HID, FILT);
            }
            k_addln<<<MROWS, 256, 0, stream>>>(v16, x32, x16,
                                               g2 + i * HID, b2l + i * HID);
        }

        // out-proj with fused permute: writes d_out directly
        g_bf16<0,0,1,0,1><<<dim3(2, 192), 256, 0, stream>>>(
            x16, woutT, bout, out, nullptr, nullptr, NPIX, HID);

    } else {
        // ===== FALLBACK: round-10 proven path =====
        float* x32 = (float*)d_ws;
        u16*   q16 = (u16*)(x32 + NB);
        u16*   k16 = q16 + NB;
        u16*   v16 = k16 + NB;
        u16*   hid16  = q16;
        float* logits = (float*)q16;

        k_embed<<<MROWS, 256, 0, stream>>>(X, emb, x32, nullptr);

        dim3 gQKV(HID / 128, MROWS / 128);
        dim3 gW1(FILT / 128, (MROWS / 2) / 128);
        dim3 gW2(HID / 128, (MROWS / 2) / 128);
        dim3 gOut(NPIX / 128, MROWS / 128);

        for (int i = 0; i < L_; ++i) {
            const float* wq = Wq + (size_t)i * HID * HID;
            const float* wk = Wk + (size_t)i * HID * HID;
            const float* wv = Wv + (size_t)i * HID * HID;
            const float* wo = Wo + (size_t)i * HID * HID;

            g_mfma<0,1,0,0><<<gQKV, 256, 0, stream>>>(x32, wq, nullptr, q16, HID, HID);
            g_mfma<0,1,0,0><<<gQKV, 256, 0, stream>>>(x32, wk, nullptr, k16, HID, HID);
            g_mfma<0,1,0,0><<<gQKV, 256, 0, stream>>>(x32, wv, nullptr, v16, HID, HID);

            k_attn<<<dim3(S_ / BLEN, B_ * HEADS), 256, 0, stream>>>(q16, k16, v16, q16);

            g_mfma<1,1,0,0><<<gQKV, 256, 0, stream>>>(q16, wo, nullptr, k16, HID, HID);
            k_addln<<<MROWS, 256, 0, stream>>>(k16, x32, nullptr,
                                               g1 + i * HID, b1l + i * HID);

            for (int c = 0; c < 2; ++c) {
                const size_t r0 = (size_t)c * (MROWS / 2);
                g_mfma<0,1,1,1><<<gW1, 256, 0, stream>>>(
                    x32 + r0 * HID, W1 + (size_t)i * HID * FILT,
                    bb1 + i * FILT, hid16, FILT, HID);
                g_mfma<1,1,1,0><<<gW2, 256, 0, stream>>>(
                    hid16, W2 + (size_t)i * FILT * HID,
                    bb2 + i * HID, v16 + r0 * HID, HID, FILT);
            }
            k_addln<<<MROWS, 256, 0, stream>>>(v16, x32, nullptr,
                                               g2 + i * HID, b2l + i * HID);
        }

        g_mfma<0,0,1,0><<<gOut, 256, 0, stream>>>(x32, Wout, bout, logits, NPIX, HID);
        k_permute<<<MROWS, 256, 0, stream>>>(logits, out);
    }
}

// Round 16
// 2192.176 us; speedup vs baseline: 20.2552x; 1.0315x over previous
//
#include <hip/hip_runtime.h>
#include <hip/hip_bf16.h>
#include <cstdint>

#define B_    8
#define C_    3
#define H_    32
#define W_    32
#define HID   512
#define HEADS 8
#define FILT  2048
#define L_    6
#define BLEN  256
#define NPIX  256
#define S_    (H_*W_*C_)   /* 3072 */
#define MROWS (B_*S_)      /* 24576 */

typedef unsigned short u16;
typedef short bf16x8 __attribute__((ext_vector_type(8)));
typedef float f32x4  __attribute__((ext_vector_type(4)));

__device__ __forceinline__ float bf2f(u16 u) {
    union { unsigned int i; float f; } x; x.i = ((unsigned int)u) << 16; return x.f;
}
__device__ __forceinline__ u16 f2bf(float f) {
    __hip_bfloat16 h = __float2bfloat16(f);
    return *reinterpret_cast<u16*>(&h);
}

#define GLP(p) ((const __attribute__((address_space(1))) void*)(p))
#define LLP(p) ((__attribute__((address_space(3))) void*)(p))

// ---------------------------------------------------------------------------
// Embedding gather + shift + positional -> x16 (bf16 residual stream).
// Thread handles dims d0=2*tid, d0+1 (vectorized float2 gather, ushort2 store).
// ---------------------------------------------------------------------------
__global__ __launch_bounds__(256) void k_embed(const float* __restrict__ X,
                                               const float* __restrict__ emb,
                                               u16* __restrict__ xo16) {
    int r = blockIdx.x;              // b*S + s
    int b = r / S_, s = r - b * S_;
    int h = s / (W_ * C_);
    int j = s - h * (W_ * C_);
    int tid = threadIdx.x;
    int d0 = tid << 1;               // 0,2,..,510

    float e0 = 0.f, e1 = 0.f;
    if (s > 0) {
        int sp = s - 1;
        int hp = sp / (W_ * C_);
        int jp = sp - hp * (W_ * C_);
        int cp = jp % C_;
        int wp = jp / C_;
        float xv = X[(((size_t)b * C_ + cp) * H_ + hp) * W_ + wp];
        int iv = (int)(xv * 255.0f) + cp * NPIX;
        float2 ev = *(const float2*)(emb + (size_t)iv * HID + d0);
        e0 = ev.x * 22.627416997969522f;   // sqrt(512)
        e1 = ev.y * 22.627416997969522f;
    }
    float p01[2];
#pragma unroll
    for (int q = 0; q < 2; ++q) {
        int d = d0 + q;
        float invd = expf((float)(d & 127) * -0.07252236513366287f);
        p01[q] = (d < 128) ? sinf((float)h * invd)
               : (d < 256) ? cosf((float)h * invd)
               : (d < 384) ? sinf((float)j * invd)
                           : cosf((float)j * invd);
    }
    ushort2 o;
    o.x = f2bf(e0 + p01[0]);
    o.y = f2bf(e1 + p01[1]);
    *(ushort2*)(xo16 + (size_t)r * HID + d0) = o;
}

// ---------------------------------------------------------------------------
// 64x64 tile transpose+convert: out[N][K] (bf16) = in[K][N] (fp32).
// ---------------------------------------------------------------------------
__global__ __launch_bounds__(256) void k_trans_g(const float* __restrict__ in,
                                                 u16* __restrict__ out,
                                                 int N, int K,
                                                 size_t inStride, size_t outStride) {
    __shared__ u16 T[64][72];
    in  += (size_t)blockIdx.z * inStride;
    out += (size_t)blockIdx.z * outStride;
    int n0 = blockIdx.x * 64, k0 = blockIdx.y * 64;
    int t = threadIdx.x;
    int r4 = t >> 4;            // 0..15
    int c4 = (t & 15) << 2;     // 0..60
#pragma unroll
    for (int pass = 0; pass < 4; ++pass) {
        int kr = pass * 16 + r4;
        float4 v = *(const float4*)(in + (size_t)(k0 + kr) * N + n0 + c4);
        T[c4 + 0][kr] = f2bf(v.x);
        T[c4 + 1][kr] = f2bf(v.y);
        T[c4 + 2][kr] = f2bf(v.z);
        T[c4 + 3][kr] = f2bf(v.w);
    }
    __syncthreads();
#pragma unroll
    for (int pass = 0; pass < 4; ++pass) {
        int n = pass * 16 + r4;
        ushort4 s = {T[n][c4], T[n][c4 + 1], T[n][c4 + 2], T[n][c4 + 3]};
        *(ushort4*)(out + (size_t)(n0 + n) * K + k0 + c4) = s;
    }
}

// ---------------------------------------------------------------------------
// Pure-bf16 MFMA GEMM (m97-style): C = A(M,K) @ Bt(N,K)^T  [+bias][relu]
// ---------------------------------------------------------------------------
template<int QKV, int C_BF, int BIAS, int RELU, int PERM>
__global__ __launch_bounds__(256) void g_bf16(const u16* __restrict__ A,
                                              const u16* __restrict__ Bt,
                                              const float* __restrict__ bias,
                                              void* __restrict__ C0,
                                              void* __restrict__ C1,
                                              void* __restrict__ C2,
                                              int Nc, int K) {
    __shared__ __align__(16) u16 smem[17408];
    u16* As = smem;
    u16* Bs = smem + 8192;
    int tid  = threadIdx.x;
    int lane = tid & 63;
    int w    = tid >> 6;
    int row0 = blockIdx.y * 128, col0 = blockIdx.x * 128;

    int l8 = lane >> 3;                   // 0..7
    int l7 = lane & 7;                    // 0..7
    int scol = (l7 ^ l8) << 3;            // pre-swizzled source col (elems)
    const u16* aP = A  + (size_t)(row0 + w * 32 + l8) * K + scol;
    const u16* bP = Bt + (size_t)(col0 + w * 32 + l8) * K + scol;
    u16* asBase = As + w * 2048;
    u16* bsBase = Bs + w * 2048;

    int wr = (w >> 1) << 6;
    int wc = (w & 1) << 6;
    int lr = lane & 15;
    int kb = lane >> 4;

    f32x4 acc[4][4];
#pragma unroll
    for (int mi = 0; mi < 4; ++mi)
#pragma unroll
        for (int nj = 0; nj < 4; ++nj)
            acc[mi][nj] = (f32x4){0.f, 0.f, 0.f, 0.f};

    for (int k0 = 0; k0 < K; k0 += 64) {
#pragma unroll
        for (int p = 0; p < 4; ++p) {
            __builtin_amdgcn_global_load_lds(GLP(aP + (size_t)p * 8 * K),
                                             LLP(asBase + p * 512), 16, 0, 0);
            __builtin_amdgcn_global_load_lds(GLP(bP + (size_t)p * 8 * K),
                                             LLP(bsBase + p * 512), 16, 0, 0);
        }
        aP += 64; bP += 64;
        __syncthreads();

#pragma unroll
        for (int kh = 0; kh < 2; ++kh) {
            int sl = ((kh << 2) + kb) ^ (lr & 7);
            bf16x8 af[4], bv[4];
#pragma unroll
            for (int mi = 0; mi < 4; ++mi)
                af[mi] = *(const bf16x8*)&As[(wr + lr) * 64 + mi * 1024 + sl * 8];
#pragma unroll
            for (int nj = 0; nj < 4; ++nj)
                bv[nj] = *(const bf16x8*)&Bs[(wc + lr) * 64 + nj * 1024 + sl * 8];
            __builtin_amdgcn_s_setprio(1);
#pragma unroll
            for (int mi = 0; mi < 4; ++mi)
#pragma unroll
                for (int nj = 0; nj < 4; ++nj)
                    acc[mi][nj] = __builtin_amdgcn_mfma_f32_16x16x32_bf16(
                        af[mi], bv[nj], acc[mi][nj], 0, 0, 0);
            __builtin_amdgcn_s_setprio(0);
        }
        __syncthreads();
    }

    if (C_BF) {
#pragma unroll
        for (int nj = 0; nj < 4; ++nj) {
            int colL = wc + (nj << 4) + lr;
            float bsv = BIAS ? bias[col0 + colL] : 0.f;
#pragma unroll
            for (int mi = 0; mi < 4; ++mi)
#pragma unroll
                for (int reg = 0; reg < 4; ++reg) {
                    int rowL = wr + (mi << 4) + (kb << 2) + reg;
                    float v = acc[mi][nj][reg] + bsv;
                    if (RELU) v = fmaxf(v, 0.f);
                    smem[rowL * 136 + colL] = f2bf(v);
                }
        }
        __syncthreads();
        u16* Cp; int cbase;
        if (QKV) {
            int sel = col0 >> 9;
            Cp = (u16*)(sel == 0 ? C0 : sel == 1 ? C1 : C2);
            cbase = col0 & 511;
        } else { Cp = (u16*)C0; cbase = col0; }
#pragma unroll
        for (int it = 0; it < 8; ++it) {
            int job  = tid + (it << 8);
            int rowL = job >> 4;
            int colL = (job & 15) << 3;
            bf16x8 vv = *(const bf16x8*)&smem[rowL * 136 + colL];
            *(bf16x8*)(Cp + (size_t)(row0 + rowL) * Nc + cbase + colL) = vv;
        }
    } else {
#pragma unroll
        for (int nj = 0; nj < 4; ++nj) {
            int colg = col0 + wc + (nj << 4) + lr;
            float bsv = BIAS ? bias[colg] : 0.f;
#pragma unroll
            for (int mi = 0; mi < 4; ++mi)
#pragma unroll
                for (int reg = 0; reg < 4; ++reg) {
                    int row = row0 + wr + (mi << 4) + (kb << 2) + reg;
                    float v = acc[mi][nj][reg] + bsv;
                    if (RELU) v = fmaxf(v, 0.f);
                    if (PERM) {
                        int bb = row / S_;
                        int ss = row - bb * S_;
                        int hh = ss / (W_ * C_);
                        int jj = ss - hh * (W_ * C_);
                        int ww = jj / C_;
                        int cc = jj - ww * C_;
                        ((float*)C0)[((((size_t)bb * C_ + cc) * H_ + hh) * W_ + ww)
                                     * NPIX + colg] = v;
                    } else {
                        ((float*)C0)[(size_t)row * Nc + colg] = v;
                    }
                }
        }
    }
}

// ---------------------------------------------------------------------------
// LEGACY fp32-staged MFMA GEMM — fallback path only.
// ---------------------------------------------------------------------------
template<int A_BF, int C_BF, int BIAS, int RELU>
__global__ __launch_bounds__(256) void g_mfma(const void* __restrict__ Ap,
                                              const float* __restrict__ Bw,
                                              const float* __restrict__ bias,
                                              void* __restrict__ Cp,
                                              int N, int K) {
    __shared__ __align__(16) u16 As[128][40];
    __shared__ __align__(16) u16 Bs[128][40];
    int tid  = threadIdx.x;
    int row0 = blockIdx.y * 128, col0 = blockIdx.x * 128;

    int ar  = tid >> 1;
    int akq = (tid & 1) << 4;
    int bkk = tid >> 5;
    int bnn = (tid & 31) << 2;

    int lane = tid & 63;
    int wv   = tid >> 6;
    int wr   = (wv >> 1) << 6;
    int wc   = (wv & 1) << 6;
    int lr   = lane & 15;
    int kb   = lane >> 4;

    f32x4 acc[4][4];
#pragma unroll
    for (int mi = 0; mi < 4; ++mi)
#pragma unroll
        for (int nj = 0; nj < 4; ++nj)
            acc[mi][nj] = (f32x4){0.f, 0.f, 0.f, 0.f};

    for (int k0 = 0; k0 < K; k0 += 32) {
        if (A_BF) {
            const u16* ap = (const u16*)Ap + (size_t)(row0 + ar) * K + k0 + akq;
#pragma unroll
            for (int p = 0; p < 4; ++p)
                *(ushort4*)&As[ar][akq + (p << 2)] = *(const ushort4*)(ap + (p << 2));
        } else {
            const float* ap = (const float*)Ap + (size_t)(row0 + ar) * K + k0 + akq;
#pragma unroll
            for (int p = 0; p < 4; ++p) {
                float4 v = *(const float4*)(ap + (p << 2));
                ushort4 wq = {f2bf(v.x), f2bf(v.y), f2bf(v.z), f2bf(v.w)};
                *(ushort4*)&As[ar][akq + (p << 2)] = wq;
            }
        }
#pragma unroll
        for (int p = 0; p < 4; ++p) {
            int kl = bkk + (p << 3);
            float4 wv4 = *(const float4*)(Bw + (size_t)(k0 + kl) * N + col0 + bnn);
            Bs[bnn + 0][kl] = f2bf(wv4.x);
            Bs[bnn + 1][kl] = f2bf(wv4.y);
            Bs[bnn + 2][kl] = f2bf(wv4.z);
            Bs[bnn + 3][kl] = f2bf(wv4.w);
        }
        __syncthreads();

        bf16x8 af[4], bfr[4];
#pragma unroll
        for (int mi = 0; mi < 4; ++mi)
            af[mi] = *(const bf16x8*)&As[wr + (mi << 4) + lr][kb << 3];
#pragma unroll
        for (int nj = 0; nj < 4; ++nj)
            bfr[nj] = *(const bf16x8*)&Bs[wc + (nj << 4) + lr][kb << 3];
#pragma unroll
        for (int mi = 0; mi < 4; ++mi)
#pragma unroll
            for (int nj = 0; nj < 4; ++nj)
                acc[mi][nj] = __builtin_amdgcn_mfma_f32_16x16x32_bf16(
                    af[mi], bfr[nj], acc[mi][nj], 0, 0, 0);
        __syncthreads();
    }

#pragma unroll
    for (int mi = 0; mi < 4; ++mi)
#pragma unroll
        for (int nj = 0; nj < 4; ++nj) {
            int col = col0 + wc + (nj << 4) + lr;
            float bsv = BIAS ? bias[col] : 0.f;
#pragma unroll
            for (int reg = 0; reg < 4; ++reg) {
                int row = row0 + wr + (mi << 4) + (kb << 2) + reg;
                float v = acc[mi][nj][reg] + bsv;
                if (RELU) v = fmaxf(v, 0.f);
                if (C_BF)
                    ((u16*)Cp)[(size_t)row * N + col] = f2bf(v);
                else
                    ((float*)Cp)[(size_t)row * N + col] = v;
            }
        }
}

// ---------------------------------------------------------------------------
// MFMA flash-style block-local causal attention (bf16), SWAPPED QK^T,
// XCD-aware 1D grid + K/V register prefetch. (unchanged from round 15)
// ---------------------------------------------------------------------------
__global__ __launch_bounds__(256) void k_attn_mfma(const u16* Qm,
                                                   const u16* __restrict__ Km,
                                                   const u16* __restrict__ Vm,
                                                   u16* Om) {
    __shared__ __align__(16) u16 Kl[64][72];      // [key][d]
    __shared__ __align__(16) u16 VT[64][72];      // [d][key^vsw]
    __shared__ __align__(16) u16 Pl[4][64][64];   // per-wave [q][k^((q&7)<<3)]

    int f   = blockIdx.x;            // 0..767
    int xcd = f & 7;
    int t2  = f >> 3;
    int qb  = t2 % 12;
    int grp = t2 / 12;               // 0..7
    int bh  = (grp << 3) | xcd;
    int b   = bh >> 3, h = bh & 7;

    int tid = threadIdx.x;
    int lane = tid & 63;
    int w    = tid >> 6;
    int lr   = lane & 15;
    int kb   = lane >> 4;            // 0..3
    int qw   = qb * BLEN + w * 64;   // wave query base
    int vsw  = (tid & 7) << 3;       // VT write swizzle
    int psw  = (lr & 7) << 3;        // Pl swizzle for this lane's rows (q&7)

    bf16x8 qf[4][2];
#pragma unroll
    for (int mi = 0; mi < 4; ++mi)
#pragma unroll
        for (int ks = 0; ks < 2; ++ks)
            qf[mi][ks] = *(const bf16x8*)(Qm +
                ((size_t)b * S_ + qw + mi * 16 + lr) * HID + h * 64 + ks * 32 + kb * 8);

    f32x4 oacc[4][4];                 // [mi][dj]
    float lacc[4];
#pragma unroll
    for (int mi = 0; mi < 4; ++mi) {
        lacc[mi] = 0.f;
#pragma unroll
        for (int dj = 0; dj < 4; ++dj)
            oacc[mi][dj] = (f32x4){0.f, 0.f, 0.f, 0.f};
    }

    int kstart = (qb == 0) ? 0 : (qb - 1) * BLEN;
    int nch    = (qb == 0) ? 4 : 8;

    int key0 = tid >> 3;
    int key1 = (tid + 256) >> 3;
    int d8   = (tid & 7) << 3;

    bf16x8 kvr0, kvr1, vvr0, vvr1;
    {
        size_t g0 = ((size_t)b * S_ + kstart + key0) * HID + h * 64 + d8;
        size_t g1 = ((size_t)b * S_ + kstart + key1) * HID + h * 64 + d8;
        kvr0 = *(const bf16x8*)(Km + g0);
        vvr0 = *(const bf16x8*)(Vm + g0);
        kvr1 = *(const bf16x8*)(Km + g1);
        vvr1 = *(const bf16x8*)(Vm + g1);
    }

    for (int ck = 0; ck < nch; ++ck) {
        int ka = kstart + ck * 64;
        __syncthreads();
        *(bf16x8*)&Kl[key0][d8] = kvr0;
        *(bf16x8*)&Kl[key1][d8] = kvr1;
        {
            const u16* vu0 = (const u16*)&vvr0;
            const u16* vu1 = (const u16*)&vvr1;
            int kc0 = key0 ^ vsw, kc1 = key1 ^ vsw;
#pragma unroll
            for (int e = 0; e < 8; ++e) VT[d8 + e][kc0] = vu0[e];
#pragma unroll
            for (int e = 0; e < 8; ++e) VT[d8 + e][kc1] = vu1[e];
        }
        if (ck + 1 < nch) {
            int kan = ka + 64;
            size_t g0 = ((size_t)b * S_ + kan + key0) * HID + h * 64 + d8;
            size_t g1 = ((size_t)b * S_ + kan + key1) * HID + h * 64 + d8;
            kvr0 = *(const bf16x8*)(Km + g0);
            vvr0 = *(const bf16x8*)(Vm + g0);
            kvr1 = *(const bf16x8*)(Km + g1);
            vvr1 = *(const bf16x8*)(Vm + g1);
        }
        __syncthreads();

        if (ka <= qw + 63) {
            f32x4 sa[4][4];
#pragma unroll
            for (int nj = 0; nj < 4; ++nj)
#pragma unroll
                for (int mi = 0; mi < 4; ++mi)
                    sa[nj][mi] = (f32x4){0.f, 0.f, 0.f, 0.f};
#pragma unroll
            for (int ks = 0; ks < 2; ++ks) {
                bf16x8 kf[4];
#pragma unroll
                for (int nj = 0; nj < 4; ++nj)
                    kf[nj] = *(const bf16x8*)&Kl[nj * 16 + lr][ks * 32 + kb * 8];
                __builtin_amdgcn_s_setprio(1);
#pragma unroll
                for (int nj = 0; nj < 4; ++nj)
#pragma unroll
                    for (int mi = 0; mi < 4; ++mi)
                        sa[nj][mi] = __builtin_amdgcn_mfma_f32_16x16x32_bf16(
                            kf[nj], qf[mi][ks], sa[nj][mi], 0, 0, 0);
                __builtin_amdgcn_s_setprio(0);
            }
            bool diag = (ka + 63 > qw);
#pragma unroll
            for (int mi = 0; mi < 4; ++mi) {
                int qg = qw + mi * 16 + lr;
                float tsum = 0.f;
#pragma unroll
                for (int nj = 0; nj < 4; ++nj) {
                    ushort4 pk;
                    u16* pp = (u16*)&pk;
#pragma unroll
                    for (int reg = 0; reg < 4; ++reg) {
                        float s = sa[nj][mi][reg] * 0.125f;
                        float p = __expf(s);
                        if (diag && (ka + nj * 16 + kb * 4 + reg > qg)) p = 0.f;
                        tsum += p;
                        pp[reg] = f2bf(p);
                    }
                    *(ushort4*)&Pl[w][mi * 16 + lr][(nj * 16 + kb * 4) ^ psw] = pk;
                }
                tsum += __shfl_xor(tsum, 16);
                tsum += __shfl_xor(tsum, 32);
                lacc[mi] += tsum;
            }
#pragma unroll
            for (int ks = 0; ks < 2; ++ks) {
                bf16x8 pf[4], vf[4];
#pragma unroll
                for (int mi = 0; mi < 4; ++mi)
                    pf[mi] = *(const bf16x8*)&Pl[w][mi * 16 + lr]
                                                 [(ks * 32 + kb * 8) ^ psw];
#pragma unroll
                for (int dj = 0; dj < 4; ++dj) {
                    int vr = ((dj * 2 + (lr >> 3)) & 7) << 3;
                    vf[dj] = *(const bf16x8*)&VT[dj * 16 + lr]
                                                [(ks * 32 + kb * 8) ^ vr];
                }
                __builtin_amdgcn_s_setprio(1);
#pragma unroll
                for (int mi = 0; mi < 4; ++mi)
#pragma unroll
                    for (int dj = 0; dj < 4; ++dj)
                        oacc[mi][dj] = __builtin_amdgcn_mfma_f32_16x16x32_bf16(
                            pf[mi], vf[dj], oacc[mi][dj], 0, 0, 0);
                __builtin_amdgcn_s_setprio(0);
            }
        }
    }

#pragma unroll
    for (int mi = 0; mi < 4; ++mi) {
        float lr4[4];
#pragma unroll
        for (int reg = 0; reg < 4; ++reg)
            lr4[reg] = __shfl(lacc[mi], kb * 4 + reg);
#pragma unroll
        for (int reg = 0; reg < 4; ++reg) {
            float rl = 1.0f / lr4[reg];
            size_t orow = ((size_t)b * S_ + qw + mi * 16 + kb * 4 + reg) * HID + h * 64;
#pragma unroll
            for (int dj = 0; dj < 4; ++dj)
                Om[orow + dj * 16 + lr] = f2bf(oacc[mi][dj][reg] * rl);
        }
    }
}

// ---------------------------------------------------------------------------
// LEGACY scalar attention — fallback path only.
// ---------------------------------------------------------------------------
__global__ __launch_bounds__(256) void k_attn(const u16* Qm,
                                              const u16* __restrict__ Km,
                                              const u16* __restrict__ Vm,
                                              u16* Om) {
    __shared__ float Ks[64][64];
    __shared__ float Vs[64][64];
    int qb  = blockIdx.x;
    int bh  = blockIdx.y;
    int b   = bh >> 3, h = bh & 7;
    int tid = threadIdx.x;
    int sq  = qb * BLEN + tid;

    size_t qoff = ((size_t)b * S_ + sq) * HID + h * 64;
    float q[64];
#pragma unroll
    for (int d = 0; d < 64; d += 4) {
        ushort4 u = *(const ushort4*)(Qm + qoff + d);
        q[d]   = bf2f(u.x) * 0.125f;
        q[d+1] = bf2f(u.y) * 0.125f;
        q[d+2] = bf2f(u.z) * 0.125f;
        q[d+3] = bf2f(u.w) * 0.125f;
    }

    float acc[64];
#pragma unroll
    for (int d = 0; d < 64; ++d) acc[d] = 0.f;
    float l = 0.f;

    int kstart  = (qb == 0) ? 0 : (qb - 1) * BLEN;
    int nchunks = (qb == 0) ? 4 : 8;

    for (int ck = 0; ck < nchunks; ++ck) {
        int ka = kstart + ck * 64;
        __syncthreads();
        int li = tid;
#pragma unroll
        for (int it = 0; it < 4; ++it, li += 256) {
            int key = li >> 4;
            int seg = (li & 15) * 4;
            size_t goff = ((size_t)b * S_ + ka + key) * HID + h * 64 + seg;
            ushort4 ku = *(const ushort4*)(Km + goff);
            ushort4 vu = *(const ushort4*)(Vm + goff);
            Ks[key][seg+0] = bf2f(ku.x); Ks[key][seg+1] = bf2f(ku.y);
            Ks[key][seg+2] = bf2f(ku.z); Ks[key][seg+3] = bf2f(ku.w);
            Vs[key][seg+0] = bf2f(vu.x); Vs[key][seg+1] = bf2f(vu.y);
            Vs[key][seg+2] = bf2f(vu.z); Vs[key][seg+3] = bf2f(vu.w);
        }
        __syncthreads();

        int nk = sq - ka + 1;
        if (nk > 64) nk = 64;
        for (int kk = 0; kk < nk; ++kk) {
            float dot = 0.f;
#pragma unroll
            for (int d = 0; d < 64; ++d) dot += q[d] * Ks[kk][d];
            float p = expf(dot);
            l += p;
#pragma unroll
            for (int d = 0; d < 64; ++d) acc[d] += p * Vs[kk][d];
        }
    }

    float rl = 1.0f / l;
    size_t ooff = ((size_t)b * S_ + sq) * HID + h * 64;
#pragma unroll
    for (int d = 0; d < 64; d += 4) {
        ushort4 s;
        s.x = f2bf(acc[d]   * rl); s.y = f2bf(acc[d+1] * rl);
        s.z = f2bf(acc[d+2] * rl); s.w = f2bf(acc[d+3] * rl);
        *(ushort4*)(Om + ooff + d) = s;
    }
}

// ---------------------------------------------------------------------------
// X16 = LayerNorm(T16 + X16) * g + b   (bf16 residual stream, fp32 math)
// Vectorized: thread handles cols 2*tid, 2*tid+1 (ushort2/float2).
// ---------------------------------------------------------------------------
__global__ __launch_bounds__(256) void k_addln(const u16* __restrict__ T,
                                               u16* __restrict__ X16,
                                               const float* __restrict__ g,
                                               const float* __restrict__ bb) {
    __shared__ float red[8];
    int r = blockIdx.x;
    size_t off = (size_t)r * HID;
    int tid = threadIdx.x;
    int c0 = tid << 1;
    ushort2 tv = *(const ushort2*)(T + off + c0);
    ushort2 xv = *(const ushort2*)(X16 + off + c0);
    float v0 = bf2f(tv.x) + bf2f(xv.x);
    float v1 = bf2f(tv.y) + bf2f(xv.y);
    float s  = v0 + v1;
    float sq = v0 * v0 + v1 * v1;
#pragma unroll
    for (int o = 32; o > 0; o >>= 1) {
        s  += __shfl_down(s,  o, 64);
        sq += __shfl_down(sq, o, 64);
    }
    int wid = tid >> 6;
    if ((tid & 63) == 0) { red[wid] = s; red[4 + wid] = sq; }
    __syncthreads();
    if (tid == 0) {
        red[0] = red[0] + red[1] + red[2] + red[3];
        red[4] = red[4] + red[5] + red[6] + red[7];
    }
    __syncthreads();
    float mean = red[0] * (1.0f / 512.0f);
    float var  = red[4] * (1.0f / 512.0f) - mean * mean;
    float rs   = rsqrtf(var + 1e-6f);
    float2 gv = *(const float2*)(g + c0);
    float2 bv = *(const float2*)(bb + c0);
    ushort2 o;
    o.x = f2bf((v0 - mean) * rs * gv.x + bv.x);
    o.y = f2bf((v1 - mean) * rs * gv.y + bv.y);
    *(ushort2*)(X16 + off + c0) = o;
}

// ---------------------------------------------------------------------------
// Fallback-path add+LN (fp32 residual) — unchanged round-10 logic.
// ---------------------------------------------------------------------------
__global__ __launch_bounds__(256) void k_addln_fb(const u16* __restrict__ T,
                                                  float* __restrict__ X,
                                                  const float* __restrict__ g,
                                                  const float* __restrict__ bb) {
    __shared__ float red[8];
    int r = blockIdx.x;
    size_t off = (size_t)r * HID;
    int tid = threadIdx.x;
    float v0 = bf2f(T[off + tid])       + X[off + tid];
    float v1 = bf2f(T[off + tid + 256]) + X[off + tid + 256];
    float s  = v0 + v1;
    float sq = v0 * v0 + v1 * v1;
#pragma unroll
    for (int o = 32; o > 0; o >>= 1) {
        s  += __shfl_down(s,  o, 64);
        sq += __shfl_down(sq, o, 64);
    }
    int wid = tid >> 6;
    if ((tid & 63) == 0) { red[wid] = s; red[4 + wid] = sq; }
    __syncthreads();
    if (tid == 0) {
        red[0] = red[0] + red[1] + red[2] + red[3];
        red[4] = red[4] + red[5] + red[6] + red[7];
    }
    __syncthreads();
    float mean = red[0] * (1.0f / 512.0f);
    float var  = red[4] * (1.0f / 512.0f) - mean * mean;
    float rs   = rsqrtf(var + 1e-6f);
    X[off + tid]       = (v0 - mean) * rs * g[tid]       + bb[tid];
    X[off + tid + 256] = (v1 - mean) * rs * g[tid + 256] + bb[tid + 256];
}

// ---------------------------------------------------------------------------
// Fallback embed (fp32 out) — round-10 logic.
// ---------------------------------------------------------------------------
__global__ __launch_bounds__(256) void k_embed_fb(const float* __restrict__ X,
                                                  const float* __restrict__ emb,
                                                  float* __restrict__ xo) {
    int r = blockIdx.x;
    int b = r / S_, s = r - b * S_;
    int h = s / (W_ * C_);
    int j = s - h * (W_ * C_);
    int tid = threadIdx.x;

    float e0 = 0.f, e1 = 0.f;
    if (s > 0) {
        int sp = s - 1;
        int hp = sp / (W_ * C_);
        int jp = sp - hp * (W_ * C_);
        int cp = jp % C_;
        int wp = jp / C_;
        float xv = X[(((size_t)b * C_ + cp) * H_ + hp) * W_ + wp];
        int iv = (int)(xv * 255.0f) + cp * NPIX;
        const float* er = emb + (size_t)iv * HID;
        e0 = er[tid]       * 22.627416997969522f;
        e1 = er[tid + 256] * 22.627416997969522f;
    }
    float invd = expf((float)(tid & 127) * -0.07252236513366287f);
    float p0 = (tid < 128) ? sinf((float)h * invd) : cosf((float)h * invd);
    float p1 = (tid < 128) ? sinf((float)j * invd) : cosf((float)j * invd);

    xo[(size_t)r * HID + tid]       = e0 + p0;
    xo[(size_t)r * HID + tid + 256] = e1 + p1;
}

// ---------------------------------------------------------------------------
// (B,S,NPIX) fp32 logits -> (B,C,H,W,NPIX) fp32 output (fallback only)
// ---------------------------------------------------------------------------
__global__ __launch_bounds__(256) void k_permute(const float* __restrict__ T,
                                                 float* __restrict__ O) {
    int r = blockIdx.x;
    int p = threadIdx.x;
    int b = r / S_, s = r - b * S_;
    int h = s / (W_ * C_);
    int j = s - h * (W_ * C_);
    int w = j / C_;
    int c = j - w * C_;
    O[((((size_t)b * C_ + c) * H_ + h) * W_ + w) * NPIX + p] =
        T[(size_t)r * NPIX + p];
}

// ---------------------------------------------------------------------------
extern "C" void kernel_launch(void* const* d_in, const int* in_sizes, int n_in,
                              void* d_out, int out_size, void* d_ws, size_t ws_size,
                              hipStream_t stream) {
    const float* X    = (const float*)d_in[0];
    const float* emb  = (const float*)d_in[1];
    const float* Wq   = (const float*)d_in[2];
    const float* Wk   = (const float*)d_in[3];
    const float* Wv   = (const float*)d_in[4];
    const float* Wo   = (const float*)d_in[5];
    const float* g1   = (const float*)d_in[6];
    const float* b1l  = (const float*)d_in[7];
    const float* W1   = (const float*)d_in[8];
    const float* bb1  = (const float*)d_in[9];
    const float* W2   = (const float*)d_in[10];
    const float* bb2  = (const float*)d_in[11];
    const float* g2   = (const float*)d_in[12];
    const float* b2l  = (const float*)d_in[13];
    const float* Wout = (const float*)d_in[14];
    const float* bout = (const float*)d_in[15];
    float* out = (float*)d_out;
    (void)in_sizes; (void)n_in; (void)out_size;

    const size_t NB = (size_t)MROWS * HID;
    // bf16-only layout: x16|q16|k16|v16 (4*NB*2B) + transposed weights (38MB)
    const size_t BIG_NEED = 138674176ull;

    if (ws_size >= BIG_NEED) {
        // ===== BIG PATH (bf16 residual stream, no x32) =====
        u16* x16    = (u16*)d_ws;
        u16* q16    = x16 + NB;
        u16* k16    = q16 + NB;
        u16* v16    = k16 + NB;
        u16* wqkvT  = v16 + NB;
        u16* woT    = wqkvT + (size_t)6 * 1536 * 512;
        u16* w1T    = woT   + (size_t)6 * 512 * 512;
        u16* w2T    = w1T   + (size_t)6 * 2048 * 512;
        u16* woutT  = w2T   + (size_t)6 * 512 * 2048;
        u16* h16    = q16;                 // FFN hidden chunk = q16..k16 span

        k_trans_g<<<dim3(8, 8, 6),  256, 0, stream>>>(Wq, wqkvT,          512, 512,  262144, 786432);
        k_trans_g<<<dim3(8, 8, 6),  256, 0, stream>>>(Wk, wqkvT + 262144, 512, 512,  262144, 786432);
        k_trans_g<<<dim3(8, 8, 6),  256, 0, stream>>>(Wv, wqkvT + 524288, 512, 512,  262144, 786432);
        k_trans_g<<<dim3(8, 8, 6),  256, 0, stream>>>(Wo, woT,            512, 512,  262144, 262144);
        k_trans_g<<<dim3(32, 8, 6), 256, 0, stream>>>(W1, w1T,  2048, 512, 1048576, 1048576);
        k_trans_g<<<dim3(8, 32, 6), 256, 0, stream>>>(W2, w2T,  512, 2048, 1048576, 1048576);
        k_trans_g<<<dim3(4, 8, 1),  256, 0, stream>>>(Wout, woutT, 256, 512, 131072, 131072);

        k_embed<<<MROWS, 256, 0, stream>>>(X, emb, x16);

        for (int i = 0; i < L_; ++i) {
            g_bf16<1,1,0,0,0><<<dim3(12, 192), 256, 0, stream>>>(
                x16, wqkvT + (size_t)i * 1536 * 512, nullptr,
                q16, k16, v16, HID, HID);

            k_attn_mfma<<<768, 256, 0, stream>>>(q16, k16, v16, q16);

            g_bf16<0,1,0,0,0><<<dim3(4, 192), 256, 0, stream>>>(
                q16, woT + (size_t)i * 512 * 512, nullptr,
                k16, nullptr, nullptr, HID, HID);
            k_addln<<<MROWS, 256, 0, stream>>>(k16, x16,
                                               g1 + i * HID, b1l + i * HID);

            for (int c = 0; c < 2; ++c) {
                const size_t r0 = (size_t)c * (MROWS / 2);
                g_bf16<0,1,1,1,0><<<dim3(16, 96), 256, 0, stream>>>(
                    x16 + r0 * HID, w1T + (size_t)i * 2048 * 512,
                    bb1 + i * FILT, h16, nullptr, nullptr, FILT, HID);
                g_bf16<0,1,1,0,0><<<dim3(4, 96), 256, 0, stream>>>(
                    h16, w2T + (size_t)i * 512 * 2048,
                    bb2 + i * HID, v16 + r0 * HID, nullptr, nullptr, HID, FILT);
            }
            k_addln<<<MROWS, 256, 0, stream>>>(v16, x16,
                                               g2 + i * HID, b2l + i * HID);
        }

        // out-proj with fused permute: writes d_out directly
        g_bf16<0,0,1,0,1><<<dim3(2, 192), 256, 0, stream>>>(
            x16, woutT, bout, out, nullptr, nullptr, NPIX, HID);

    } else {
        // ===== FALLBACK: round-10 proven path (fp32 residual) =====
        float* x32 = (float*)d_ws;
        u16*   q16 = (u16*)(x32 + NB);
        u16*   k16 = q16 + NB;
        u16*   v16 = k16 + NB;
        u16*   hid16  = q16;
        float* logits = (float*)q16;

        k_embed_fb<<<MROWS, 256, 0, stream>>>(X, emb, x32);

        dim3 gQKV(HID / 128, MROWS / 128);
        dim3 gW1(FILT / 128, (MROWS / 2) / 128);
        dim3 gW2(HID / 128, (MROWS / 2) / 128);
        dim3 gOut(NPIX / 128, MROWS / 128);

        for (int i = 0; i < L_; ++i) {
            const float* wq = Wq + (size_t)i * HID * HID;
            const float* wk = Wk + (size_t)i * HID * HID;
            const float* wv = Wv + (size_t)i * HID * HID;
            const float* wo = Wo + (size_t)i * HID * HID;

            g_mfma<0,1,0,0><<<gQKV, 256, 0, stream>>>(x32, wq, nullptr, q16, HID, HID);
            g_mfma<0,1,0,0><<<gQKV, 256, 0, stream>>>(x32, wk, nullptr, k16, HID, HID);
            g_mfma<0,1,0,0><<<gQKV, 256, 0, stream>>>(x32, wv, nullptr, v16, HID, HID);

            k_attn<<<dim3(S_ / BLEN, B_ * HEADS), 256, 0, stream>>>(q16, k16, v16, q16);

            g_mfma<1,1,0,0><<<gQKV, 256, 0, stream>>>(q16, wo, nullptr, k16, HID, HID);
            k_addln_fb<<<MROWS, 256, 0, stream>>>(k16, x32,
                                                  g1 + i * HID, b1l + i * HID);

            for (int c = 0; c < 2; ++c) {
                const size_t r0 = (size_t)c * (MROWS / 2);
                g_mfma<0,1,1,1><<<gW1, 256, 0, stream>>>(
                    x32 + r0 * HID, W1 + (size_t)i * HID * FILT,
                    bb1 + i * FILT, hid16, FILT, HID);
                g_mfma<1,1,1,0><<<gW2, 256, 0, stream>>>(
                    hid16, W2 + (size_t)i * FILT * HID,
                    bb2 + i * HID, v16 + r0 * HID, HID, FILT);
            }
            k_addln_fb<<<MROWS, 256, 0, stream>>>(v16, x32,
                                                  g2 + i * HID, b2l + i * HID);
        }

        g_mfma<0,0,1,0><<<gOut, 256, 0, stream>>>(x32, Wout, bout, logits, NPIX, HID);
        k_permute<<<MROWS, 256, 0, stream>>>(logits, out);
    }
}